// Round 1
// baseline (2761.137 us; speedup 1.0000x reference)
//
#include <hip/hip_runtime.h>
#include <math.h>

// ---- problem constants ----
#define D_      1024
#define DH_     64
#define H_      8
#define INNER_  512
#define L_      6
#define NL_     64
#define FF_     4096
#define B_      4
#define T_      8
#define FV_     1024          // F*V
#define BT_     32            // B*T
#define MROWS_  32768         // BT*FV
#define NKV_    1088          // FV + NL
#define KVROWS_ 34816         // BT*NKV
#define ZB_     256           // BT*H

typedef __bf16 bf16;
typedef __bf16 bf16x8 __attribute__((ext_vector_type(8)));
typedef __bf16 bf16x4 __attribute__((ext_vector_type(4)));
typedef float  f32x4  __attribute__((ext_vector_type(4)));

// ---- helpers ----
__device__ __forceinline__ void gload_lds16(const bf16* g, bf16* l) {
    __builtin_amdgcn_global_load_lds(
        (const __attribute__((address_space(1))) unsigned int*)g,
        (__attribute__((address_space(3))) unsigned int*)l, 16, 0, 0);
}

__device__ __forceinline__ float wred_sum(float v) {
#pragma unroll
    for (int o = 32; o > 0; o >>= 1) v += __shfl_xor(v, o, 64);
    return v;
}
__device__ __forceinline__ float wred_max(float v) {
#pragma unroll
    for (int o = 32; o > 0; o >>= 1) v = fmaxf(v, __shfl_xor(v, o, 64));
    return v;
}

__device__ __forceinline__ float gelu_f(float x) {
    return 0.5f * x * (1.0f + erff(x * 0.70710678118654752440f));
}

// ---- xhat: LN-normalize (x + frame_embs[t]) once, no affine, bf16 out ----
__global__ __launch_bounds__(256) void xhat_k(const float* __restrict__ x,
                                              const float* __restrict__ fe,
                                              bf16* __restrict__ xhat) {
    __shared__ float red[8];
    int row = blockIdx.x;                // bt*FV + fv
    int t = (row >> 10) & 7;             // bt = row>>10 (FV=1024), t = bt % T
    const float* xr = x + (size_t)row * D_;
    const float* fr_ = fe + (size_t)t * D_;
    int tid = threadIdx.x, c = tid * 4;
    float4 v = *(const float4*)(xr + c);
    float4 f = *(const float4*)(fr_ + c);
    v.x += f.x; v.y += f.y; v.z += f.z; v.w += f.w;
    float s = v.x + v.y + v.z + v.w;
    float ss = v.x * v.x + v.y * v.y + v.z * v.z + v.w * v.w;
    s = wred_sum(s); ss = wred_sum(ss);
    if ((tid & 63) == 0) { red[tid >> 6] = s; red[4 + (tid >> 6)] = ss; }
    __syncthreads();
    s = red[0] + red[1] + red[2] + red[3];
    ss = red[4] + red[5] + red[6] + red[7];
    float mean = s * (1.0f / D_);
    float rstd = rsqrtf(ss * (1.0f / D_) - mean * mean + 1e-5f);
    bf16x4 o;
    o[0] = (bf16)((v.x - mean) * rstd);
    o[1] = (bf16)((v.y - mean) * rstd);
    o[2] = (bf16)((v.z - mean) * rstd);
    o[3] = (bf16)((v.w - mean) * rstd);
    *(bf16x4*)(xhat + (size_t)row * D_ + c) = o;
}

// ---- lat init: broadcast latents ----
__global__ __launch_bounds__(256) void latinit_k(const float* __restrict__ latents,
                                                 float* __restrict__ lat) {
    int row = blockIdx.x;                // 0..2047 = bt*NL + i
    int i = row & 63;
    int c = threadIdx.x * 4;
    float4 v = *(const float4*)(latents + (size_t)i * D_ + c);
    *(float4*)(lat + (size_t)row * D_ + c) = v;
}

// ---- row LayerNorm with affine: fp32 in, bf16 or fp32 out ----
template<int OUTF>
__global__ __launch_bounds__(256) void ln_k(const float* __restrict__ in,
                                            const float* __restrict__ g,
                                            const float* __restrict__ b,
                                            void* __restrict__ out) {
    __shared__ float red[8];
    int row = blockIdx.x;
    const float* x = in + (size_t)row * D_;
    int tid = threadIdx.x, c = tid * 4;
    float4 v = *(const float4*)(x + c);
    float s = v.x + v.y + v.z + v.w;
    float ss = v.x * v.x + v.y * v.y + v.z * v.z + v.w * v.w;
    s = wred_sum(s); ss = wred_sum(ss);
    if ((tid & 63) == 0) { red[tid >> 6] = s; red[4 + (tid >> 6)] = ss; }
    __syncthreads();
    s = red[0] + red[1] + red[2] + red[3];
    ss = red[4] + red[5] + red[6] + red[7];
    float mean = s * (1.0f / D_);
    float rstd = rsqrtf(ss * (1.0f / D_) - mean * mean + 1e-5f);
    float4 gv = *(const float4*)(g + c);
    float4 bv = *(const float4*)(b + c);
    float o0 = (v.x - mean) * rstd * gv.x + bv.x;
    float o1 = (v.y - mean) * rstd * gv.y + bv.y;
    float o2 = (v.z - mean) * rstd * gv.z + bv.z;
    float o3 = (v.w - mean) * rstd * gv.w + bv.w;
    if (OUTF) {
        float4 o = make_float4(o0, o1, o2, o3);
        *(float4*)((float*)out + (size_t)row * D_ + c) = o;
    } else {
        bf16x4 o; o[0] = (bf16)o0; o[1] = (bf16)o1; o[2] = (bf16)o2; o[3] = (bf16)o3;
        *(bf16x4*)((bf16*)out + (size_t)row * D_ + c) = o;
    }
}

// ---- build concat input rows: [xhat*gm+bm ; lnl] ----
__global__ __launch_bounds__(256) void build_in_k(const bf16* __restrict__ xhat,
                                                  const bf16* __restrict__ lnl,
                                                  const float* __restrict__ gm,
                                                  const float* __restrict__ bm,
                                                  bf16* __restrict__ IN) {
    int row = blockIdx.x;                 // 0..KVROWS-1
    int bt = row / NKV_;
    int j = row - bt * NKV_;
    int c = threadIdx.x * 4;
    bf16* dst = IN + (size_t)row * D_;
    if (j < FV_) {
        const bf16* src = xhat + ((size_t)bt * FV_ + j) * D_;
        bf16x4 sv = *(const bf16x4*)(src + c);
        float4 gv = *(const float4*)(gm + c);
        float4 bv = *(const float4*)(bm + c);
        bf16x4 o;
        o[0] = (bf16)((float)sv[0] * gv.x + bv.x);
        o[1] = (bf16)((float)sv[1] * gv.y + bv.y);
        o[2] = (bf16)((float)sv[2] * gv.z + bv.z);
        o[3] = (bf16)((float)sv[3] * gv.w + bv.w);
        *(bf16x4*)(dst + c) = o;
    } else {
        const bf16* src = lnl + ((size_t)bt * NL_ + (j - FV_)) * D_;
        *(bf16x4*)(dst + c) = *(const bf16x4*)(src + c);
    }
}

// ---- weight transpose + fp32->bf16: in (R x C) -> out (C x R) ----
__global__ __launch_bounds__(256) void wtrans_k(const float* __restrict__ in,
                                                int R, int C, bf16* __restrict__ out) {
    __shared__ float t[32][33];
    int c0 = blockIdx.x * 32, r0 = blockIdx.y * 32;
    int tx = threadIdx.x & 31, ty = threadIdx.x >> 5;
#pragma unroll
    for (int i = 0; i < 4; i++)
        t[ty + i * 8][tx] = in[(size_t)(r0 + ty + i * 8) * C + c0 + tx];
    __syncthreads();
#pragma unroll
    for (int i = 0; i < 4; i++)
        out[(size_t)(c0 + ty + i * 8) * R + r0 + tx] = (bf16)t[tx][ty + i * 8];
}

// ---- V transpose per (bt,h): KV v-part (1088 x 64) -> vt (64 x 1088) ----
__global__ __launch_bounds__(256) void vtrans_k(const bf16* __restrict__ KV,
                                                bf16* __restrict__ vt) {
    __shared__ float t[32][33];
    int z = blockIdx.z, bt = z >> 3, h = z & 7;
    const bf16* src = KV + (size_t)bt * NKV_ * D_ + INNER_ + h * DH_;
    int j0 = blockIdx.x * 32, d0 = blockIdx.y * 32;
    int tx = threadIdx.x & 31, ty = threadIdx.x >> 5;
#pragma unroll
    for (int i = 0; i < 4; i++)
        t[ty + i * 8][tx] = (float)src[(size_t)(j0 + ty + i * 8) * D_ + d0 + tx];
    __syncthreads();
    bf16* dst = vt + (size_t)z * (DH_ * NKV_);
#pragma unroll
    for (int i = 0; i < 4; i++)
        dst[(size_t)(d0 + ty + i * 8) * NKV_ + j0 + tx] = (bf16)t[tx][ty + i * 8];
}

// ---- big NT GEMM: C[m,n] = sum_k A[m,k]*B[n,k]; 128x128 tile, BK=32 ----
// MODE 0: bf16 out.  1: bf16 out * scale.  2: fp32 out += acc.  3: bf16 gelu(acc).
template<int MODE>
__global__ __launch_bounds__(256) void gemm128(const bf16* __restrict__ A, int lda,
                                               const bf16* __restrict__ Bw, int ldb,
                                               void* __restrict__ C, int ldc,
                                               int K, float scale) {
    __shared__ bf16 As[128 * 32];
    __shared__ bf16 Bs[128 * 32];
    const int tid = threadIdx.x;
    const int wave = tid >> 6;
    const int lane = tid & 63;
    const size_t m0 = (size_t)blockIdx.x * 128;
    const size_t n0 = (size_t)blockIdx.y * 128;
    const int wm = (wave >> 1) * 64;
    const int wn = (wave & 1) * 64;

    // staging: chunk e covers elements [e*8, e*8+8); row=e>>2, koff=(e&3)*8
    const int r0 = tid >> 2, c0 = (tid & 3) * 8;
    const bf16* ga0 = A + (m0 + r0) * lda + c0;
    const bf16* ga1 = A + (m0 + r0 + 64) * lda + c0;
    const bf16* gb0 = Bw + (n0 + r0) * ldb + c0;
    const bf16* gb1 = Bw + (n0 + r0 + 64) * ldb + c0;
    bf16* la0 = As + wave * 512;
    bf16* la1 = As + 2048 + wave * 512;
    bf16* lb0 = Bs + wave * 512;
    bf16* lb1 = Bs + 2048 + wave * 512;

    f32x4 acc[4][4];
#pragma unroll
    for (int i = 0; i < 4; i++)
#pragma unroll
        for (int j = 0; j < 4; j++)
#pragma unroll
            for (int r = 0; r < 4; r++) acc[i][j][r] = 0.0f;

    const int fr = lane & 15;
    const int kq = (lane >> 4) * 8;

    for (int kt = 0; kt < K; kt += 32) {
        gload_lds16(ga0 + kt, la0);
        gload_lds16(ga1 + kt, la1);
        gload_lds16(gb0 + kt, lb0);
        gload_lds16(gb1 + kt, lb1);
        __syncthreads();
        bf16x8 af[4], bfv[4];
#pragma unroll
        for (int i = 0; i < 4; i++) {
            af[i]  = *(const bf16x8*)(As + (wm + i * 16 + fr) * 32 + kq);
            bfv[i] = *(const bf16x8*)(Bs + (wn + i * 16 + fr) * 32 + kq);
        }
#pragma unroll
        for (int i = 0; i < 4; i++)
#pragma unroll
            for (int j = 0; j < 4; j++)
                acc[i][j] = __builtin_amdgcn_mfma_f32_16x16x32_bf16(af[i], bfv[j], acc[i][j], 0, 0, 0);
        __syncthreads();
    }

    const int fq = (lane >> 4) * 4;
    if (MODE == 2) {
        float* Cf = (float*)C;
#pragma unroll
        for (int i = 0; i < 4; i++)
#pragma unroll
            for (int j = 0; j < 4; j++) {
                size_t rb = m0 + wm + i * 16 + fq;
                size_t cb = n0 + wn + j * 16 + fr;
#pragma unroll
                for (int r = 0; r < 4; r++)
                    Cf[(rb + r) * ldc + cb] += acc[i][j][r];
            }
    } else {
        bf16* Cb = (bf16*)C;
#pragma unroll
        for (int i = 0; i < 4; i++)
#pragma unroll
            for (int j = 0; j < 4; j++) {
                size_t rb = m0 + wm + i * 16 + fq;
                size_t cb = n0 + wn + j * 16 + fr;
#pragma unroll
                for (int r = 0; r < 4; r++) {
                    float v = acc[i][j][r];
                    if (MODE == 1) v *= scale;
                    if (MODE == 3) v = gelu_f(v);
                    Cb[(rb + r) * ldc + cb] = (bf16)v;
                }
            }
    }
}

// ---- small batched NT GEMM (1 wave, 64x64 tile, direct global frags) ----
// z = blockIdx.y; offsets = (z>>3)*so + (z&7)*si. MODE 0: fp32 store; 1: bf16 store.
template<int MODE>
__global__ __launch_bounds__(64) void gemm_attn(const bf16* __restrict__ A, int lda,
                                                long long sAo, long long sAi,
                                                const bf16* __restrict__ Bm, int ldb,
                                                long long sBo, long long sBi,
                                                void* __restrict__ C, int ldc,
                                                long long sCo, long long sCi,
                                                int K) {
    int z = blockIdx.y;
    int n0 = blockIdx.x * 64;
    long long zo = z >> 3, zi = z & 7;
    const bf16* Ap = A + zo * sAo + zi * sAi;
    const bf16* Bp = Bm + zo * sBo + zi * sBi + (size_t)n0 * ldb;
    int lane = threadIdx.x;
    int fr = lane & 15, kq = (lane >> 4) * 8;

    f32x4 acc[4][4];
#pragma unroll
    for (int i = 0; i < 4; i++)
#pragma unroll
        for (int j = 0; j < 4; j++)
#pragma unroll
            for (int r = 0; r < 4; r++) acc[i][j][r] = 0.0f;

    for (int kt = 0; kt < K; kt += 32) {
        bf16x8 af[4], bfv[4];
#pragma unroll
        for (int i = 0; i < 4; i++)
            af[i] = *(const bf16x8*)(Ap + (size_t)(i * 16 + fr) * lda + kt + kq);
#pragma unroll
        for (int j = 0; j < 4; j++)
            bfv[j] = *(const bf16x8*)(Bp + (size_t)(j * 16 + fr) * ldb + kt + kq);
#pragma unroll
        for (int i = 0; i < 4; i++)
#pragma unroll
            for (int j = 0; j < 4; j++)
                acc[i][j] = __builtin_amdgcn_mfma_f32_16x16x32_bf16(af[i], bfv[j], acc[i][j], 0, 0, 0);
    }

    int fq = (lane >> 4) * 4;
    if (MODE == 0) {
        float* Cf = (float*)C + zo * sCo + zi * sCi;
#pragma unroll
        for (int i = 0; i < 4; i++)
#pragma unroll
            for (int j = 0; j < 4; j++)
#pragma unroll
                for (int r = 0; r < 4; r++)
                    Cf[(size_t)(i * 16 + fq + r) * ldc + n0 + j * 16 + fr] = acc[i][j][r];
    } else {
        bf16* Cb = (bf16*)C + zo * sCo + zi * sCi;
#pragma unroll
        for (int i = 0; i < 4; i++)
#pragma unroll
            for (int j = 0; j < 4; j++)
#pragma unroll
                for (int r = 0; r < 4; r++)
                    Cb[(size_t)(i * 16 + fq + r) * ldc + n0 + j * 16 + fr] = (bf16)acc[i][j][r];
    }
}

// ---- softmax over 1088, in-place: fp32 scores -> bf16 probs at row start ----
__global__ __launch_bounds__(256) void softmax_k(float* __restrict__ simattn) {
    __shared__ float buf[NKV_];
    __shared__ float red[4];
    __shared__ float red2[4];
    float* s = simattn + (size_t)blockIdx.x * NKV_;
    int tid = threadIdx.x;
    float mx = -1e30f;
    for (int c = tid; c < NKV_; c += 256) { float v = s[c]; buf[c] = v; mx = fmaxf(mx, v); }
    mx = wred_max(mx);
    if ((tid & 63) == 0) red[tid >> 6] = mx;
    __syncthreads();
    mx = fmaxf(fmaxf(red[0], red[1]), fmaxf(red[2], red[3]));
    float sum = 0.0f;
    for (int c = tid; c < NKV_; c += 256) { float e = __expf(buf[c] - mx); buf[c] = e; sum += e; }
    sum = wred_sum(sum);
    if ((tid & 63) == 0) red2[tid >> 6] = sum;
    __syncthreads();
    sum = red2[0] + red2[1] + red2[2] + red2[3];
    float inv = 1.0f / sum;
    bf16* a = (bf16*)s;     // row stride stays 2176 bf16 elements (4352 B)
    for (int c = tid; c < NKV_; c += 256) a[c] = (bf16)(buf[c] * inv);
}

// ---- host side ----
extern "C" void kernel_launch(void* const* d_in, const int* in_sizes, int n_in,
                              void* d_out, int out_size, void* d_ws, size_t ws_size,
                              hipStream_t stream) {
    const float* x       = (const float*)d_in[0];
    const float* latents = (const float*)d_in[1];
    const float* fe      = (const float*)d_in[2];
    const float* g_media = (const float*)d_in[3];
    const float* b_media = (const float*)d_in[4];
    const float* g_lat   = (const float*)d_in[5];
    const float* b_lat   = (const float*)d_in[6];
    const float* Wq      = (const float*)d_in[7];
    const float* Wkv     = (const float*)d_in[8];
    const float* Wo      = (const float*)d_in[9];
    const float* g_ff    = (const float*)d_in[10];
    const float* b_ff    = (const float*)d_in[11];
    const float* W1      = (const float*)d_in[12];
    const float* W2      = (const float*)d_in[13];
    const float* g_out   = (const float*)d_in[14];
    const float* b_out   = (const float*)d_in[15];

    char* p = (char*)d_ws;
    auto alloc = [&](size_t bytes) { char* r = p; p += (bytes + 255) & ~(size_t)255; return r; };
    bf16*  xhat = (bf16*)alloc((size_t)MROWS_ * D_ * 2);          // 67 MB
    float* lat  = (float*)alloc((size_t)2048 * D_ * 4);           // 8 MB
    bf16*  lnl  = (bf16*)alloc((size_t)2048 * D_ * 2);            // 4 MB
    bf16*  qb   = (bf16*)alloc((size_t)2048 * INNER_ * 2);        // 2 MB
    bf16*  INb  = (bf16*)alloc((size_t)KVROWS_ * D_ * 2);         // 71 MB (aliases sim)
    bf16*  KVb  = (bf16*)alloc((size_t)KVROWS_ * D_ * 2);         // 71 MB
    bf16*  vt   = (bf16*)alloc((size_t)ZB_ * DH_ * NKV_ * 2);     // 36 MB (aliases ffh)
    bf16*  ob   = (bf16*)alloc((size_t)2048 * INNER_ * 2);        // 2 MB
    bf16*  WqT  = (bf16*)alloc((size_t)INNER_ * D_ * 2);
    bf16*  WkvT = (bf16*)alloc((size_t)D_ * D_ * 2);
    bf16*  WoT  = (bf16*)alloc((size_t)D_ * INNER_ * 2);
    bf16*  W1T  = (bf16*)alloc((size_t)FF_ * D_ * 2);
    bf16*  W2T  = (bf16*)alloc((size_t)D_ * FF_ * 2);
    float* sim  = (float*)INb;   // alias: IN dead once KV GEMM done
    bf16*  ffh  = vt;            // alias: vt dead once PV done

    // setup (once per call)
    xhat_k<<<MROWS_, 256, 0, stream>>>(x, fe, xhat);
    latinit_k<<<2048, 256, 0, stream>>>(latents, lat);

    for (int l = 0; l < L_; l++) {
        const float* gm = g_media + (size_t)l * D_;
        const float* bm = b_media + (size_t)l * D_;
        const float* gl = g_lat + (size_t)l * D_;
        const float* bl = b_lat + (size_t)l * D_;
        const float* gf = g_ff + (size_t)l * D_;
        const float* bf_ = b_ff + (size_t)l * D_;
        const float* wq = Wq + (size_t)l * D_ * INNER_;
        const float* wkv = Wkv + (size_t)l * D_ * 2 * INNER_;
        const float* wo = Wo + (size_t)l * INNER_ * D_;
        const float* w1 = W1 + (size_t)l * D_ * FF_;
        const float* w2 = W2 + (size_t)l * FF_ * D_;

        // LN(latents) for this layer
        ln_k<0><<<2048, 256, 0, stream>>>(lat, gl, bl, lnl);

        // transpose-convert weights to bf16 (C x R layouts for NT GEMM)
        wtrans_k<<<dim3(16, 32), 256, 0, stream>>>(wq, D_, INNER_, WqT);       // 512x1024
        wtrans_k<<<dim3(32, 32), 256, 0, stream>>>(wkv, D_, 2 * INNER_, WkvT); // 1024x1024
        wtrans_k<<<dim3(32, 16), 256, 0, stream>>>(wo, INNER_, D_, WoT);       // 1024x512
        wtrans_k<<<dim3(128, 32), 256, 0, stream>>>(w1, D_, FF_, W1T);         // 4096x1024
        wtrans_k<<<dim3(32, 128), 256, 0, stream>>>(w2, FF_, D_, W2T);         // 1024x4096

        // IN = [xhat*gm+bm ; lnl]  (KVROWS x D)
        build_in_k<<<KVROWS_, 256, 0, stream>>>(xhat, lnl, gm, bm, INb);

        // KV = IN @ WkvT   (KVROWS x 1024)
        gemm128<0><<<dim3(KVROWS_ / 128, 8), 256, 0, stream>>>(INb, D_, WkvT, D_, KVb, 2 * INNER_, D_, 1.0f);

        // vt: per (bt,h) transpose of V
        vtrans_k<<<dim3(34, 2, ZB_), 256, 0, stream>>>(KVb, vt);

        // q = (lnl @ WqT) * scale
        gemm128<1><<<dim3(16, 4), 256, 0, stream>>>(lnl, D_, WqT, D_, qb, INNER_, D_, 0.125f);

        // sim[z] = q_z @ k_z^T  (64 x 1088 fp32), z = bt*8+h
        gemm_attn<0><<<dim3(17, ZB_), 64, 0, stream>>>(
            qb, INNER_, (long long)NL_ * INNER_, DH_,
            KVb, D_, (long long)NKV_ * D_, DH_,
            sim, NKV_, (long long)8 * NL_ * NKV_, (long long)NL_ * NKV_, DH_);

        // softmax in-place (fp32 -> bf16 at row starts, stride 2176 elems)
        softmax_k<<<ZB_ * NL_, 256, 0, stream>>>(sim);

        // o[z] = attn_z @ v_z  -> (bt, i, h*64+dh)
        gemm_attn<1><<<dim3(1, ZB_), 64, 0, stream>>>(
            (const bf16*)sim, 2 * NKV_, (long long)8 * NL_ * 2 * NKV_, (long long)NL_ * 2 * NKV_,
            vt, NKV_, (long long)8 * DH_ * NKV_, (long long)DH_ * NKV_,
            ob, INNER_, (long long)NL_ * INNER_, DH_, NKV_);

        // lat += o @ WoT
        gemm128<2><<<dim3(16, 8), 256, 0, stream>>>(ob, INNER_, WoT, INNER_, lat, D_, INNER_, 1.0f);

        // FF: lnl2 = LN(lat); ffh = gelu(lnl2 @ W1T); lat += ffh @ W2T
        ln_k<0><<<2048, 256, 0, stream>>>(lat, gf, bf_, lnl);
        gemm128<3><<<dim3(16, 32), 256, 0, stream>>>(lnl, D_, W1T, D_, ffh, FF_, D_, 1.0f);
        gemm128<2><<<dim3(16, 8), 256, 0, stream>>>(ffh, FF_, W2T, FF_, lat, D_, FF_, 1.0f);
    }

    // final LN -> fp32 output
    ln_k<1><<<2048, 256, 0, stream>>>(lat, g_out, b_out, (float*)d_out);
}

// Round 2
// 2404.370 us; speedup vs baseline: 1.1484x; 1.1484x over previous
//
#include <hip/hip_runtime.h>
#include <math.h>

// ---- problem constants ----
#define D_      1024
#define DH_     64
#define H_      8
#define INNER_  512
#define L_      6
#define NL_     64
#define FF_     4096
#define B_      4
#define T_      8
#define FV_     1024          // F*V
#define BT_     32            // B*T
#define MROWS_  32768         // BT*FV
#define NKV_    1088          // FV + NL
#define KVROWS_ 34816         // BT*NKV
#define ZB_     256           // BT*H

typedef __bf16 bf16;
typedef __bf16 bf16x8 __attribute__((ext_vector_type(8)));
typedef __bf16 bf16x4 __attribute__((ext_vector_type(4)));
typedef float  f32x4  __attribute__((ext_vector_type(4)));

// ---- helpers ----
__device__ __forceinline__ void gload_lds16(const bf16* g, bf16* l) {
    __builtin_amdgcn_global_load_lds(
        (const __attribute__((address_space(1))) unsigned int*)g,
        (__attribute__((address_space(3))) unsigned int*)l, 16, 0, 0);
}

__device__ __forceinline__ float wred_sum(float v) {
#pragma unroll
    for (int o = 32; o > 0; o >>= 1) v += __shfl_xor(v, o, 64);
    return v;
}
__device__ __forceinline__ float wred_max(float v) {
#pragma unroll
    for (int o = 32; o > 0; o >>= 1) v = fmaxf(v, __shfl_xor(v, o, 64));
    return v;
}

__device__ __forceinline__ float gelu_f(float x) {
    return 0.5f * x * (1.0f + erff(x * 0.70710678118654752440f));
}

// ---- xhat: LN-normalize (x + frame_embs[t]) once, no affine, bf16 out ----
__global__ __launch_bounds__(256) void xhat_k(const float* __restrict__ x,
                                              const float* __restrict__ fe,
                                              bf16* __restrict__ xhat) {
    __shared__ float red[8];
    int row = blockIdx.x;                // bt*FV + fv
    int t = (row >> 10) & 7;
    const float* xr = x + (size_t)row * D_;
    const float* fr_ = fe + (size_t)t * D_;
    int tid = threadIdx.x, c = tid * 4;
    float4 v = *(const float4*)(xr + c);
    float4 f = *(const float4*)(fr_ + c);
    v.x += f.x; v.y += f.y; v.z += f.z; v.w += f.w;
    float s = v.x + v.y + v.z + v.w;
    float ss = v.x * v.x + v.y * v.y + v.z * v.z + v.w * v.w;
    s = wred_sum(s); ss = wred_sum(ss);
    if ((tid & 63) == 0) { red[tid >> 6] = s; red[4 + (tid >> 6)] = ss; }
    __syncthreads();
    s = red[0] + red[1] + red[2] + red[3];
    ss = red[4] + red[5] + red[6] + red[7];
    float mean = s * (1.0f / D_);
    float rstd = rsqrtf(ss * (1.0f / D_) - mean * mean + 1e-5f);
    bf16x4 o;
    o[0] = (bf16)((v.x - mean) * rstd);
    o[1] = (bf16)((v.y - mean) * rstd);
    o[2] = (bf16)((v.z - mean) * rstd);
    o[3] = (bf16)((v.w - mean) * rstd);
    *(bf16x4*)(xhat + (size_t)row * D_ + c) = o;
}

// ---- lat init ----
__global__ __launch_bounds__(256) void latinit_k(const float* __restrict__ latents,
                                                 float* __restrict__ lat) {
    int row = blockIdx.x;
    int i = row & 63;
    int c = threadIdx.x * 4;
    float4 v = *(const float4*)(latents + (size_t)i * D_ + c);
    *(float4*)(lat + (size_t)row * D_ + c) = v;
}

// ---- row LayerNorm with affine: fp32 in, bf16 (OUTF=0) or fp32 (OUTF=1) out ----
template<int OUTF>
__global__ __launch_bounds__(256) void ln_k(const float* __restrict__ in,
                                            const float* __restrict__ g,
                                            const float* __restrict__ b,
                                            void* __restrict__ out) {
    __shared__ float red[8];
    int row = blockIdx.x;
    const float* x = in + (size_t)row * D_;
    int tid = threadIdx.x, c = tid * 4;
    float4 v = *(const float4*)(x + c);
    float s = v.x + v.y + v.z + v.w;
    float ss = v.x * v.x + v.y * v.y + v.z * v.z + v.w * v.w;
    s = wred_sum(s); ss = wred_sum(ss);
    if ((tid & 63) == 0) { red[tid >> 6] = s; red[4 + (tid >> 6)] = ss; }
    __syncthreads();
    s = red[0] + red[1] + red[2] + red[3];
    ss = red[4] + red[5] + red[6] + red[7];
    float mean = s * (1.0f / D_);
    float rstd = rsqrtf(ss * (1.0f / D_) - mean * mean + 1e-5f);
    float4 gv = *(const float4*)(g + c);
    float4 bv = *(const float4*)(b + c);
    float o0 = (v.x - mean) * rstd * gv.x + bv.x;
    float o1 = (v.y - mean) * rstd * gv.y + bv.y;
    float o2 = (v.z - mean) * rstd * gv.z + bv.z;
    float o3 = (v.w - mean) * rstd * gv.w + bv.w;
    if (OUTF) {
        *(float4*)((float*)out + (size_t)row * D_ + c) = make_float4(o0, o1, o2, o3);
    } else {
        bf16x4 o; o[0] = (bf16)o0; o[1] = (bf16)o1; o[2] = (bf16)o2; o[3] = (bf16)o3;
        *(bf16x4*)((bf16*)out + (size_t)row * D_ + c) = o;
    }
}

// ---- fused weight prep: transpose fp32->bf16, one launch per layer ----
// segments (tile=32x32):  [0,512) Wq | [512,1536) WkvT | [1536,2560) WkvTg(gm)
//                         [2560,3072) Wo | [3072,7168) W1 | [7168,11264) W2
__device__ __forceinline__ void wt_tile(const float* __restrict__ in, int R, int C,
                                        bf16* __restrict__ out, int bx, int by,
                                        const float* __restrict__ sc) {
    __shared__ float t[32][33];
    int c0 = bx * 32, r0 = by * 32;
    int tx = threadIdx.x & 31, ty = threadIdx.x >> 5;
#pragma unroll
    for (int i = 0; i < 4; i++)
        t[ty + i * 8][tx] = in[(size_t)(r0 + ty + i * 8) * C + c0 + tx];
    __syncthreads();
    float scale = sc ? sc[r0 + tx] : 1.0f;
#pragma unroll
    for (int i = 0; i < 4; i++)
        out[(size_t)(c0 + ty + i * 8) * R + r0 + tx] = (bf16)(t[tx][ty + i * 8] * scale);
}

__global__ __launch_bounds__(256) void wprep_k(const float* __restrict__ wq,
                                               const float* __restrict__ wkv,
                                               const float* __restrict__ wo,
                                               const float* __restrict__ w1,
                                               const float* __restrict__ w2,
                                               const float* __restrict__ gm,
                                               bf16* __restrict__ WqT,
                                               bf16* __restrict__ WkvT,
                                               bf16* __restrict__ WkvTg,
                                               bf16* __restrict__ WoT,
                                               bf16* __restrict__ W1T,
                                               bf16* __restrict__ W2T) {
    int id = blockIdx.x;
    if (id < 512)            wt_tile(wq, D_, INNER_, WqT, id & 15, id >> 4, nullptr);
    else if (id < 1536)  { int i = id - 512;  wt_tile(wkv, D_, 2 * INNER_, WkvT,  i & 31, i >> 5, nullptr); }
    else if (id < 2560)  { int i = id - 1536; wt_tile(wkv, D_, 2 * INNER_, WkvTg, i & 31, i >> 5, gm); }
    else if (id < 3072)  { int i = id - 2560; wt_tile(wo, INNER_, D_, WoT, i & 31, i >> 5, nullptr); }
    else if (id < 7168)  { int i = id - 3072; wt_tile(w1, D_, FF_, W1T, i & 127, i >> 7, nullptr); }
    else                 { int i = id - 7168; wt_tile(w2, FF_, D_, W2T, i & 31, i >> 5, nullptr); }
}

// ---- bkv[n] = sum_k bm[k] * wkv[k][n] (fp32, atomic partials) ----
__global__ __launch_bounds__(256) void bias_k(const float* __restrict__ bm,
                                              const float* __restrict__ wkv,
                                              float* __restrict__ bkv) {
    int n = blockIdx.x * 256 + threadIdx.x;
    int k0 = blockIdx.y * 128;
    float s = 0.0f;
    for (int k = k0; k < k0 + 128; k++) s += bm[k] * wkv[(size_t)k * (2 * INNER_) + n];
    atomicAdd(&bkv[n], s);
}

// ---- V transpose per (bt,h): KV v-part (1088 x 64) -> vt (64 x 1088) ----
__global__ __launch_bounds__(256) void vtrans_k(const bf16* __restrict__ KV,
                                                bf16* __restrict__ vt) {
    __shared__ float t[32][33];
    int z = blockIdx.z, bt = z >> 3, h = z & 7;
    const bf16* src = KV + (size_t)bt * NKV_ * D_ + INNER_ + h * DH_;
    int j0 = blockIdx.x * 32, d0 = blockIdx.y * 32;
    int tx = threadIdx.x & 31, ty = threadIdx.x >> 5;
#pragma unroll
    for (int i = 0; i < 4; i++)
        t[ty + i * 8][tx] = (float)src[(size_t)(j0 + ty + i * 8) * D_ + d0 + tx];
    __syncthreads();
    bf16* dst = vt + (size_t)z * (DH_ * NKV_);
#pragma unroll
    for (int i = 0; i < 4; i++)
        dst[(size_t)(d0 + ty + i * 8) * NKV_ + j0 + tx] = (bf16)t[tx][ty + i * 8];
}

// ---- big NT GEMM: C[m,n] = sum_k A[m,k]*B[n,k]; 128x128 tile, BK=32 ----
// Swizzled LDS (T2, both-sides): stage source chunk q_g = (tid&3)^((tid>>3)&3),
// read chunk q ^ ((fr>>1)&3) -> 2-way banks (free).
// MODE 0: bf16 out. 1: bf16*scale. 2: fp32 +=. 3: bf16 gelu. 4: fp32 store (split-K partial).
// CMAP 0: linear rows. 1: x->KV rows (m + (m>>10)*64). 2: lat->KV rows (1024+(m&63)+(m>>6)*1088).
// BIAS: add bias[n] before store.
template<int MODE, int CMAP, int BIAS>
__global__ __launch_bounds__(256) void gemm128(const bf16* __restrict__ A, int lda,
                                               const bf16* __restrict__ Bw, int ldb,
                                               void* __restrict__ C, int ldc,
                                               int K, float scale,
                                               const float* __restrict__ bias,
                                               long long czs) {
    __shared__ bf16 As[128 * 32];
    __shared__ bf16 Bs[128 * 32];
    const int tid = threadIdx.x;
    const int wave = tid >> 6;
    const int lane = tid & 63;
    const size_t m0 = (size_t)blockIdx.x * 128;
    const size_t n0 = (size_t)blockIdx.y * 128;
    const int wm = (wave >> 1) * 64;
    const int wn = (wave & 1) * 64;

    // split-K (gridDim.z partitions)
    const int klen = K / gridDim.z;
    const int koff = blockIdx.z * klen;

    // staging: lane chunk -> row r0, swizzled source chunk
    const int r0 = tid >> 2;
    const int c0 = ((tid & 3) ^ ((tid >> 3) & 3)) * 8;
    const bf16* ga0 = A + (m0 + r0) * lda + c0 + koff;
    const bf16* ga1 = A + (m0 + r0 + 64) * lda + c0 + koff;
    const bf16* gb0 = Bw + (n0 + r0) * ldb + c0 + koff;
    const bf16* gb1 = Bw + (n0 + r0 + 64) * ldb + c0 + koff;
    bf16* la0 = As + wave * 512;
    bf16* la1 = As + 2048 + wave * 512;
    bf16* lb0 = Bs + wave * 512;
    bf16* lb1 = Bs + 2048 + wave * 512;

    f32x4 acc[4][4];
#pragma unroll
    for (int i = 0; i < 4; i++)
#pragma unroll
        for (int j = 0; j < 4; j++)
#pragma unroll
            for (int r = 0; r < 4; r++) acc[i][j][r] = 0.0f;

    const int fr = lane & 15;
    const int q = lane >> 4;
    const int sw = (q ^ ((fr >> 1) & 3)) * 8;   // swizzled k-chunk in LDS row

    for (int kt = 0; kt < klen; kt += 32) {
        gload_lds16(ga0 + kt, la0);
        gload_lds16(ga1 + kt, la1);
        gload_lds16(gb0 + kt, lb0);
        gload_lds16(gb1 + kt, lb1);
        __syncthreads();
        bf16x8 af[4], bfv[4];
#pragma unroll
        for (int i = 0; i < 4; i++) {
            af[i]  = *(const bf16x8*)(As + (wm + i * 16 + fr) * 32 + sw);
            bfv[i] = *(const bf16x8*)(Bs + (wn + i * 16 + fr) * 32 + sw);
        }
#pragma unroll
        for (int i = 0; i < 4; i++)
#pragma unroll
            for (int j = 0; j < 4; j++)
                acc[i][j] = __builtin_amdgcn_mfma_f32_16x16x32_bf16(af[i], bfv[j], acc[i][j], 0, 0, 0);
        __syncthreads();
    }

    const int fq = (lane >> 4) * 4;
#pragma unroll
    for (int i = 0; i < 4; i++)
#pragma unroll
        for (int j = 0; j < 4; j++) {
            size_t cb = n0 + wn + j * 16 + fr;
            float bv = BIAS ? bias[cb] : 0.0f;
#pragma unroll
            for (int r = 0; r < 4; r++) {
                size_t m = m0 + wm + i * 16 + fq + r;
                size_t rb;
                if (CMAP == 1)      rb = m + ((m >> 10) << 6);
                else if (CMAP == 2) rb = 1024 + (m & 63) + (m >> 6) * NKV_;
                else                rb = m;
                float v = acc[i][j][r] + bv;
                if (MODE == 2) {
                    ((float*)C)[rb * ldc + cb] += v;
                } else if (MODE == 4) {
                    ((float*)C + blockIdx.z * czs)[rb * ldc + cb] = v;
                } else {
                    if (MODE == 1) v *= scale;
                    if (MODE == 3) v = gelu_f(v);
                    ((bf16*)C)[rb * ldc + cb] = (bf16)v;
                }
            }
        }
}

// ---- QK: small batched NT GEMM (1 wave, 64x64 tile, direct global frags) ----
__global__ __launch_bounds__(64) void gemm_qk(const bf16* __restrict__ A, int lda,
                                              long long sAo, long long sAi,
                                              const bf16* __restrict__ Bm, int ldb,
                                              long long sBo, long long sBi,
                                              float* __restrict__ C, int ldc,
                                              long long sCo, long long sCi,
                                              int K) {
    int z = blockIdx.y;
    int n0 = blockIdx.x * 64;
    long long zo = z >> 3, zi = z & 7;
    const bf16* Ap = A + zo * sAo + zi * sAi;
    const bf16* Bp = Bm + zo * sBo + zi * sBi + (size_t)n0 * ldb;
    int lane = threadIdx.x;
    int fr = lane & 15, kq = (lane >> 4) * 8;

    f32x4 acc[4][4];
#pragma unroll
    for (int i = 0; i < 4; i++)
#pragma unroll
        for (int j = 0; j < 4; j++)
#pragma unroll
            for (int r = 0; r < 4; r++) acc[i][j][r] = 0.0f;

    for (int kt = 0; kt < K; kt += 32) {
        bf16x8 af[4], bfv[4];
#pragma unroll
        for (int i = 0; i < 4; i++)
            af[i] = *(const bf16x8*)(Ap + (size_t)(i * 16 + fr) * lda + kt + kq);
#pragma unroll
        for (int j = 0; j < 4; j++)
            bfv[j] = *(const bf16x8*)(Bp + (size_t)(j * 16 + fr) * ldb + kt + kq);
#pragma unroll
        for (int i = 0; i < 4; i++)
#pragma unroll
            for (int j = 0; j < 4; j++)
                acc[i][j] = __builtin_amdgcn_mfma_f32_16x16x32_bf16(af[i], bfv[j], acc[i][j], 0, 0, 0);
    }

    int fq = (lane >> 4) * 4;
    float* Cf = C + zo * sCo + zi * sCi;
#pragma unroll
    for (int i = 0; i < 4; i++)
#pragma unroll
        for (int j = 0; j < 4; j++)
#pragma unroll
            for (int r = 0; r < 4; r++)
                Cf[(size_t)(i * 16 + fq + r) * ldc + n0 + j * 16 + fr] = acc[i][j][r];
}

// ---- PV: 4-wave split-K per z, LDS tree reduce, bf16 store ----
__global__ __launch_bounds__(256) void gemm_pv(const bf16* __restrict__ P, // probs, lda=2176
                                               const bf16* __restrict__ vt,
                                               bf16* __restrict__ ob) {
    __shared__ f32x4 red0[16 * 64];
    __shared__ f32x4 red1[16 * 64];
    int z = blockIdx.x;
    int bt = z >> 3, h = z & 7;
    const bf16* Ap = P + (size_t)bt * 8 * NL_ * 2 * NKV_ + (size_t)h * NL_ * 2 * NKV_;
    const bf16* Bp = vt + (size_t)z * (DH_ * NKV_);
    int tid = threadIdx.x, w = tid >> 6, lane = tid & 63;
    int fr = lane & 15, kq = (lane >> 4) * 8;
    int ks = w * 288;
    int ke = (w < 3) ? ks + 288 : NKV_;

    f32x4 acc[4][4];
#pragma unroll
    for (int i = 0; i < 4; i++)
#pragma unroll
        for (int j = 0; j < 4; j++)
#pragma unroll
            for (int r = 0; r < 4; r++) acc[i][j][r] = 0.0f;

    for (int kt = ks; kt < ke; kt += 32) {
        bf16x8 af[4], bfv[4];
#pragma unroll
        for (int i = 0; i < 4; i++)
            af[i] = *(const bf16x8*)(Ap + (size_t)(i * 16 + fr) * (2 * NKV_) + kt + kq);
#pragma unroll
        for (int j = 0; j < 4; j++)
            bfv[j] = *(const bf16x8*)(Bp + (size_t)(j * 16 + fr) * NKV_ + kt + kq);
#pragma unroll
        for (int i = 0; i < 4; i++)
#pragma unroll
            for (int j = 0; j < 4; j++)
                acc[i][j] = __builtin_amdgcn_mfma_f32_16x16x32_bf16(af[i], bfv[j], acc[i][j], 0, 0, 0);
    }

    // tree reduce: w2->red0, w3->red1; w0+=red0, w1+=red1; w1->red0; w0+=red0
    if (w == 2) {
#pragma unroll
        for (int i = 0; i < 4; i++)
#pragma unroll
            for (int j = 0; j < 4; j++) red0[(i * 4 + j) * 64 + lane] = acc[i][j];
    } else if (w == 3) {
#pragma unroll
        for (int i = 0; i < 4; i++)
#pragma unroll
            for (int j = 0; j < 4; j++) red1[(i * 4 + j) * 64 + lane] = acc[i][j];
    }
    __syncthreads();
    if (w == 0) {
#pragma unroll
        for (int i = 0; i < 4; i++)
#pragma unroll
            for (int j = 0; j < 4; j++) acc[i][j] += red0[(i * 4 + j) * 64 + lane];
    } else if (w == 1) {
#pragma unroll
        for (int i = 0; i < 4; i++)
#pragma unroll
            for (int j = 0; j < 4; j++) acc[i][j] += red1[(i * 4 + j) * 64 + lane];
    }
    __syncthreads();
    if (w == 1) {
#pragma unroll
        for (int i = 0; i < 4; i++)
#pragma unroll
            for (int j = 0; j < 4; j++) red0[(i * 4 + j) * 64 + lane] = acc[i][j];
    }
    __syncthreads();
    if (w == 0) {
        int fq = (lane >> 4) * 4;
        bf16* Cb = ob + (size_t)bt * NL_ * INNER_ + (size_t)h * DH_;
#pragma unroll
        for (int i = 0; i < 4; i++)
#pragma unroll
            for (int j = 0; j < 4; j++) {
                f32x4 v = acc[i][j] + red0[(i * 4 + j) * 64 + lane];
#pragma unroll
                for (int r = 0; r < 4; r++)
                    Cb[(size_t)(i * 16 + fq + r) * INNER_ + j * 16 + fr] = (bf16)v[r];
            }
    }
}

// ---- softmax over 1088, in-place: fp32 scores -> bf16 probs at row start ----
__global__ __launch_bounds__(256) void softmax_k(float* __restrict__ simattn) {
    __shared__ float buf[NKV_];
    __shared__ float red[4];
    __shared__ float red2[4];
    float* s = simattn + (size_t)blockIdx.x * NKV_;
    int tid = threadIdx.x;
    float mx = -1e30f;
    for (int c = tid; c < NKV_; c += 256) { float v = s[c]; buf[c] = v; mx = fmaxf(mx, v); }
    mx = wred_max(mx);
    if ((tid & 63) == 0) red[tid >> 6] = mx;
    __syncthreads();
    mx = fmaxf(fmaxf(red[0], red[1]), fmaxf(red[2], red[3]));
    float sum = 0.0f;
    for (int c = tid; c < NKV_; c += 256) { float e = __expf(buf[c] - mx); buf[c] = e; sum += e; }
    sum = wred_sum(sum);
    if ((tid & 63) == 0) red2[tid >> 6] = sum;
    __syncthreads();
    sum = red2[0] + red2[1] + red2[2] + red2[3];
    float inv = 1.0f / sum;
    bf16* a = (bf16*)s;
    for (int c = tid; c < NKV_; c += 256) a[c] = (bf16)(buf[c] * inv);
}

// ---- FF2 partial add: lat += p0 + p1 ----
__global__ __launch_bounds__(256) void ffadd_k(float* __restrict__ lat,
                                               const float* __restrict__ p0,
                                               const float* __restrict__ p1) {
    size_t i = (size_t)blockIdx.x * D_ + threadIdx.x * 4;
    float4 a = *(const float4*)(lat + i);
    float4 x = *(const float4*)(p0 + i);
    float4 y = *(const float4*)(p1 + i);
    a.x += x.x + y.x; a.y += x.y + y.y; a.z += x.z + y.z; a.w += x.w + y.w;
    *(float4*)(lat + i) = a;
}

// ---- host side ----
extern "C" void kernel_launch(void* const* d_in, const int* in_sizes, int n_in,
                              void* d_out, int out_size, void* d_ws, size_t ws_size,
                              hipStream_t stream) {
    const float* x       = (const float*)d_in[0];
    const float* latents = (const float*)d_in[1];
    const float* fe      = (const float*)d_in[2];
    const float* g_media = (const float*)d_in[3];
    const float* b_media = (const float*)d_in[4];
    const float* g_lat   = (const float*)d_in[5];
    const float* b_lat   = (const float*)d_in[6];
    const float* Wq      = (const float*)d_in[7];
    const float* Wkv     = (const float*)d_in[8];
    const float* Wo      = (const float*)d_in[9];
    const float* g_ff    = (const float*)d_in[10];
    const float* b_ff    = (const float*)d_in[11];
    const float* W1      = (const float*)d_in[12];
    const float* W2      = (const float*)d_in[13];
    const float* g_out   = (const float*)d_in[14];
    const float* b_out   = (const float*)d_in[15];

    char* p = (char*)d_ws;
    auto alloc = [&](size_t bytes) { char* r = p; p += (bytes + 255) & ~(size_t)255; return r; };
    bf16*  xhat = (bf16*)alloc((size_t)MROWS_ * D_ * 2);          // 67 MB
    float* lat  = (float*)alloc((size_t)2048 * D_ * 4);           // 8 MB
    bf16*  lnl  = (bf16*)alloc((size_t)2048 * D_ * 2);            // 4 MB
    bf16*  qb   = (bf16*)alloc((size_t)2048 * INNER_ * 2);        // 2 MB
    float* sim  = (float*)alloc((size_t)ZB_ * NL_ * NKV_ * 4);    // 71 MB
    bf16*  KVb  = (bf16*)alloc((size_t)KVROWS_ * D_ * 2);         // 71 MB
    bf16*  vt   = (bf16*)alloc((size_t)ZB_ * DH_ * NKV_ * 2);     // 36 MB
    bf16*  ob   = (bf16*)alloc((size_t)2048 * INNER_ * 2);        // 2 MB
    bf16*  WqT  = (bf16*)alloc((size_t)INNER_ * D_ * 2);
    bf16*  WkvT = (bf16*)alloc((size_t)D_ * D_ * 2);
    bf16*  WkvTg= (bf16*)alloc((size_t)D_ * D_ * 2);
    bf16*  WoT  = (bf16*)alloc((size_t)D_ * INNER_ * 2);
    bf16*  W1T  = (bf16*)alloc((size_t)FF_ * D_ * 2);
    bf16*  W2T  = (bf16*)alloc((size_t)D_ * FF_ * 2);
    float* bkv  = (float*)alloc(1024 * 4);
    bf16*  ffh  = vt;            // alias: vt dead once PV done (16 MB <= 36 MB)
    float* ffp  = sim;           // alias: sim dead once PV done (2x8 MB <= 71 MB)

    xhat_k<<<MROWS_, 256, 0, stream>>>(x, fe, xhat);
    latinit_k<<<2048, 256, 0, stream>>>(latents, lat);

    for (int l = 0; l < L_; l++) {
        const float* gm = g_media + (size_t)l * D_;
        const float* bm = b_media + (size_t)l * D_;
        const float* gl = g_lat + (size_t)l * D_;
        const float* bl = b_lat + (size_t)l * D_;
        const float* gf = g_ff + (size_t)l * D_;
        const float* bf_ = b_ff + (size_t)l * D_;
        const float* wq = Wq + (size_t)l * D_ * INNER_;
        const float* wkv = Wkv + (size_t)l * D_ * 2 * INNER_;
        const float* wo = Wo + (size_t)l * INNER_ * D_;
        const float* w1 = W1 + (size_t)l * D_ * FF_;
        const float* w2 = W2 + (size_t)l * FF_ * D_;

        ln_k<0><<<2048, 256, 0, stream>>>(lat, gl, bl, lnl);
        wprep_k<<<11264, 256, 0, stream>>>(wq, wkv, wo, w1, w2, gm,
                                           WqT, WkvT, WkvTg, WoT, W1T, W2T);
        hipMemsetAsync(bkv, 0, 1024 * 4, stream);
        bias_k<<<dim3(4, 8), 256, 0, stream>>>(bm, wkv, bkv);

        // KV x-part: xhat @ WkvTg + bkv  -> KV rows bt*1088 + [0,1024)
        gemm128<0, 1, 1><<<dim3(256, 8), 256, 0, stream>>>(
            xhat, D_, WkvTg, D_, KVb, 2 * INNER_, D_, 1.0f, bkv, 0);
        // KV lat-part: lnl @ WkvT -> KV rows bt*1088 + 1024 + [0,64)
        gemm128<0, 2, 0><<<dim3(16, 8), 256, 0, stream>>>(
            lnl, D_, WkvT, D_, KVb, 2 * INNER_, D_, 1.0f, nullptr, 0);

        vtrans_k<<<dim3(34, 2, ZB_), 256, 0, stream>>>(KVb, vt);

        // q = (lnl @ WqT) * scale
        gemm128<1, 0, 0><<<dim3(16, 4), 256, 0, stream>>>(
            lnl, D_, WqT, D_, qb, INNER_, D_, 0.125f, nullptr, 0);

        // sim[z] = q_z @ k_z^T
        gemm_qk<<<dim3(17, ZB_), 64, 0, stream>>>(
            qb, INNER_, (long long)NL_ * INNER_, DH_,
            KVb, D_, (long long)NKV_ * D_, DH_,
            sim, NKV_, (long long)8 * NL_ * NKV_, (long long)NL_ * NKV_, DH_);

        softmax_k<<<ZB_ * NL_, 256, 0, stream>>>(sim);

        // o[z] = attn_z @ v_z (4-wave split-K)
        gemm_pv<<<ZB_, 256, 0, stream>>>((const bf16*)sim, vt, ob);

        // lat += o @ WoT
        gemm128<2, 0, 0><<<dim3(16, 8), 256, 0, stream>>>(
            ob, INNER_, WoT, INNER_, lat, D_, INNER_, 1.0f, nullptr, 0);

        // FF
        ln_k<0><<<2048, 256, 0, stream>>>(lat, gf, bf_, lnl);
        gemm128<3, 0, 0><<<dim3(16, 32), 256, 0, stream>>>(
            lnl, D_, W1T, D_, ffh, FF_, D_, 1.0f, nullptr, 0);
        gemm128<4, 0, 0><<<dim3(16, 8, 2), 256, 0, stream>>>(
            ffh, FF_, W2T, FF_, ffp, D_, FF_, 1.0f, nullptr, (long long)2048 * D_);
        ffadd_k<<<2048, 256, 0, stream>>>(lat, ffp, ffp + (size_t)2048 * D_);
    }

    ln_k<1><<<2048, 256, 0, stream>>>(lat, g_out, b_out, (float*)d_out);
}

// Round 3
// 2284.641 us; speedup vs baseline: 1.2086x; 1.0524x over previous
//
#include <hip/hip_runtime.h>
#include <math.h>

// ---- problem constants ----
#define D_      1024
#define DH_     64
#define H_      8
#define INNER_  512
#define L_      6
#define NL_     64
#define FF_     4096
#define B_      4
#define T_      8
#define FV_     1024          // F*V
#define BT_     32            // B*T
#define MROWS_  32768         // BT*FV
#define NKV_    1088          // FV + NL
#define KVROWS_ 34816         // BT*NKV
#define ZB_     256           // BT*H

typedef __bf16 bf16;
typedef __bf16 bf16x8 __attribute__((ext_vector_type(8)));
typedef __bf16 bf16x4 __attribute__((ext_vector_type(4)));
typedef float  f32x4  __attribute__((ext_vector_type(4)));

#define BARRIER() { asm volatile("" ::: "memory"); __builtin_amdgcn_s_barrier(); asm volatile("" ::: "memory"); }

// ---- helpers ----
__device__ __forceinline__ void gload_lds16(const bf16* g, bf16* l) {
    __builtin_amdgcn_global_load_lds(
        (const __attribute__((address_space(1))) unsigned int*)g,
        (__attribute__((address_space(3))) unsigned int*)l, 16, 0, 0);
}

__device__ __forceinline__ float wred_sum(float v) {
#pragma unroll
    for (int o = 32; o > 0; o >>= 1) v += __shfl_xor(v, o, 64);
    return v;
}
__device__ __forceinline__ float wred_max(float v) {
#pragma unroll
    for (int o = 32; o > 0; o >>= 1) v = fmaxf(v, __shfl_xor(v, o, 64));
    return v;
}

__device__ __forceinline__ float gelu_f(float x) {
    return 0.5f * x * (1.0f + erff(x * 0.70710678118654752440f));
}

// ---- xhat: LN-normalize (x + frame_embs[t]) once, no affine, bf16 out ----
__global__ __launch_bounds__(256) void xhat_k(const float* __restrict__ x,
                                              const float* __restrict__ fe,
                                              bf16* __restrict__ xhat) {
    __shared__ float red[8];
    int row = blockIdx.x;                // bt*FV + fv
    int t = (row >> 10) & 7;
    const float* xr = x + (size_t)row * D_;
    const float* fr_ = fe + (size_t)t * D_;
    int tid = threadIdx.x, c = tid * 4;
    float4 v = *(const float4*)(xr + c);
    float4 f = *(const float4*)(fr_ + c);
    v.x += f.x; v.y += f.y; v.z += f.z; v.w += f.w;
    float s = v.x + v.y + v.z + v.w;
    float ss = v.x * v.x + v.y * v.y + v.z * v.z + v.w * v.w;
    s = wred_sum(s); ss = wred_sum(ss);
    if ((tid & 63) == 0) { red[tid >> 6] = s; red[4 + (tid >> 6)] = ss; }
    __syncthreads();
    s = red[0] + red[1] + red[2] + red[3];
    ss = red[4] + red[5] + red[6] + red[7];
    float mean = s * (1.0f / D_);
    float rstd = rsqrtf(ss * (1.0f / D_) - mean * mean + 1e-5f);
    bf16x4 o;
    o[0] = (bf16)((v.x - mean) * rstd);
    o[1] = (bf16)((v.y - mean) * rstd);
    o[2] = (bf16)((v.z - mean) * rstd);
    o[3] = (bf16)((v.w - mean) * rstd);
    *(bf16x4*)(xhat + (size_t)row * D_ + c) = o;
}

// ---- lat init ----
__global__ __launch_bounds__(256) void latinit_k(const float* __restrict__ latents,
                                                 float* __restrict__ lat) {
    int row = blockIdx.x;
    int i = row & 63;
    int c = threadIdx.x * 4;
    float4 v = *(const float4*)(latents + (size_t)i * D_ + c);
    *(float4*)(lat + (size_t)row * D_ + c) = v;
}

// ---- row LayerNorm with affine: fp32 in, bf16 (OUTF=0) or fp32 (OUTF=1) out ----
template<int OUTF>
__global__ __launch_bounds__(256) void ln_k(const float* __restrict__ in,
                                            const float* __restrict__ g,
                                            const float* __restrict__ b,
                                            void* __restrict__ out) {
    __shared__ float red[8];
    int row = blockIdx.x;
    const float* x = in + (size_t)row * D_;
    int tid = threadIdx.x, c = tid * 4;
    float4 v = *(const float4*)(x + c);
    float s = v.x + v.y + v.z + v.w;
    float ss = v.x * v.x + v.y * v.y + v.z * v.z + v.w * v.w;
    s = wred_sum(s); ss = wred_sum(ss);
    if ((tid & 63) == 0) { red[tid >> 6] = s; red[4 + (tid >> 6)] = ss; }
    __syncthreads();
    s = red[0] + red[1] + red[2] + red[3];
    ss = red[4] + red[5] + red[6] + red[7];
    float mean = s * (1.0f / D_);
    float rstd = rsqrtf(ss * (1.0f / D_) - mean * mean + 1e-5f);
    float4 gv = *(const float4*)(g + c);
    float4 bv = *(const float4*)(b + c);
    float o0 = (v.x - mean) * rstd * gv.x + bv.x;
    float o1 = (v.y - mean) * rstd * gv.y + bv.y;
    float o2 = (v.z - mean) * rstd * gv.z + bv.z;
    float o3 = (v.w - mean) * rstd * gv.w + bv.w;
    if (OUTF) {
        *(float4*)((float*)out + (size_t)row * D_ + c) = make_float4(o0, o1, o2, o3);
    } else {
        bf16x4 o; o[0] = (bf16)o0; o[1] = (bf16)o1; o[2] = (bf16)o2; o[3] = (bf16)o3;
        *(bf16x4*)((bf16*)out + (size_t)row * D_ + c) = o;
    }
}

// ---- fused weight prep: transpose fp32->bf16, one launch per layer ----
__device__ __forceinline__ void wt_tile(const float* __restrict__ in, int R, int C,
                                        bf16* __restrict__ out, int bx, int by,
                                        const float* __restrict__ sc) {
    __shared__ float t[32][33];
    int c0 = bx * 32, r0 = by * 32;
    int tx = threadIdx.x & 31, ty = threadIdx.x >> 5;
#pragma unroll
    for (int i = 0; i < 4; i++)
        t[ty + i * 8][tx] = in[(size_t)(r0 + ty + i * 8) * C + c0 + tx];
    __syncthreads();
    float scale = sc ? sc[r0 + tx] : 1.0f;
#pragma unroll
    for (int i = 0; i < 4; i++)
        out[(size_t)(c0 + ty + i * 8) * R + r0 + tx] = (bf16)(t[tx][ty + i * 8] * scale);
}

__global__ __launch_bounds__(256) void wprep_k(const float* __restrict__ wq,
                                               const float* __restrict__ wkv,
                                               const float* __restrict__ wo,
                                               const float* __restrict__ w1,
                                               const float* __restrict__ w2,
                                               const float* __restrict__ gm,
                                               bf16* __restrict__ WqT,
                                               bf16* __restrict__ WkvT,
                                               bf16* __restrict__ WkvTg,
                                               bf16* __restrict__ WoT,
                                               bf16* __restrict__ W1T,
                                               bf16* __restrict__ W2T) {
    int id = blockIdx.x;
    if (id < 512)            wt_tile(wq, D_, INNER_, WqT, id & 15, id >> 4, nullptr);
    else if (id < 1536)  { int i = id - 512;  wt_tile(wkv, D_, 2 * INNER_, WkvT,  i & 31, i >> 5, nullptr); }
    else if (id < 2560)  { int i = id - 1536; wt_tile(wkv, D_, 2 * INNER_, WkvTg, i & 31, i >> 5, gm); }
    else if (id < 3072)  { int i = id - 2560; wt_tile(wo, INNER_, D_, WoT, i & 31, i >> 5, nullptr); }
    else if (id < 7168)  { int i = id - 3072; wt_tile(w1, D_, FF_, W1T, i & 127, i >> 7, nullptr); }
    else                 { int i = id - 7168; wt_tile(w2, FF_, D_, W2T, i & 31, i >> 5, nullptr); }
}

// ---- bkv[n] = sum_k bm[k] * wkv[k][n] (fp32, atomic partials) ----
__global__ __launch_bounds__(256) void bias_k(const float* __restrict__ bm,
                                              const float* __restrict__ wkv,
                                              float* __restrict__ bkv) {
    int n = blockIdx.x * 256 + threadIdx.x;
    int k0 = blockIdx.y * 128;
    float s = 0.0f;
    for (int k = k0; k < k0 + 128; k++) s += bm[k] * wkv[(size_t)k * (2 * INNER_) + n];
    atomicAdd(&bkv[n], s);
}

// ---- V transpose per (bt,h) ----
__global__ __launch_bounds__(256) void vtrans_k(const bf16* __restrict__ KV,
                                                bf16* __restrict__ vt) {
    __shared__ float t[32][33];
    int z = blockIdx.z, bt = z >> 3, h = z & 7;
    const bf16* src = KV + (size_t)bt * NKV_ * D_ + INNER_ + h * DH_;
    int j0 = blockIdx.x * 32, d0 = blockIdx.y * 32;
    int tx = threadIdx.x & 31, ty = threadIdx.x >> 5;
#pragma unroll
    for (int i = 0; i < 4; i++)
        t[ty + i * 8][tx] = (float)src[(size_t)(j0 + ty + i * 8) * D_ + d0 + tx];
    __syncthreads();
    bf16* dst = vt + (size_t)z * (DH_ * NKV_);
#pragma unroll
    for (int i = 0; i < 4; i++)
        dst[(size_t)(d0 + ty + i * 8) * NKV_ + j0 + tx] = (bf16)t[tx][ty + i * 8];
}

// ======== 256x256 8-phase deep-pipelined NT GEMM (T2+T3+T4+T5) ========
// C[m,n] = sum_k A[m,k]*B[n,k]. BK=64, 8 waves (2Mx4N), LDS 128KiB dbuf.
// Counted vmcnt(6): 3 half-tiles in flight across barriers. Row-XOR LDS swizzle
// (k16 ^= row&7), applied on the global source for staging + on ds_read addr.
// MODE 0: bf16 out (+bias). 1: bf16*scale. 3: bf16 gelu.
// CMAP 0: linear rows. 1: x->KV rows (m + (m>>10)*64).
template<int MODE, int CMAP, int BIAS>
__global__ __launch_bounds__(512, 1) void gemm256(const bf16* __restrict__ Ag, int lda,
                                                  const bf16* __restrict__ Bg, int ldb,
                                                  void* __restrict__ C, int ldc,
                                                  int K, float scale,
                                                  const float* __restrict__ bias) {
    __shared__ bf16 lds[2][32768];   // [buf][Alo 0 | Ahi 8192 | Blo 16384 | Bhi 24576]
    const int tid = threadIdx.x;
    const int w = tid >> 6, lane = tid & 63;
    const int wm = w >> 2, wn = w & 3;
    const size_t m0 = (size_t)blockIdx.x * 256;
    const size_t n0 = (size_t)blockIdx.y * 256;
    const int nt = K >> 6;

    // staging lane geometry (chunk = 16B = 8 bf16; 8 chunks per 64-elem row)
    const int p0 = (w * 2) * 64 + lane, p1 = p0 + 64;
    const int sr0 = p0 >> 3, sk0 = ((p0 & 7) ^ (sr0 & 7)) * 8;
    const int sr1 = p1 >> 3, sk1 = ((p1 & 7) ^ (sr1 & 7)) * 8;
    const int scw0 = (w * 2) * 512, scw1 = scw0 + 512;   // wave-uniform LDS chunk bases

    auto STAGE = [&](const bf16* g, int ld, size_t row0, int k0, bf16* bufb, int rb) {
        gload_lds16(g + (row0 + sr0) * (size_t)ld + k0 + sk0, bufb + rb + scw0);
        gload_lds16(g + (row0 + sr1) * (size_t)ld + k0 + sk1, bufb + rb + scw1);
    };

    // fragment-read geometry
    const int fr = lane & 15;
    const int pK0 = (((lane >> 4)) ^ (fr & 7)) * 8;       // ksub 0
    const int pK1 = ((4 + (lane >> 4)) ^ (fr & 7)) * 8;   // ksub 1
    const size_t aoff = (size_t)(wm * 128 + fr) * 64;
    const size_t boff = 16384 + (size_t)(wn * 64 + fr) * 64;

    f32x4 acc[8][4];
#pragma unroll
    for (int i = 0; i < 8; i++)
#pragma unroll
        for (int j = 0; j < 4; j++)
#pragma unroll
            for (int r = 0; r < 4; r++) acc[i][j][r] = 0.0f;

    // ---- prologue: tile0 fully + 3 half-tiles of tile1 ----
    STAGE(Bg, ldb, n0,       0, lds[0], 16384);
    STAGE(Bg, ldb, n0 + 128, 0, lds[0], 24576);
    STAGE(Ag, lda, m0,       0, lds[0], 0);
    STAGE(Ag, lda, m0 + 128, 0, lds[0], 8192);
    if (nt > 1) {
        STAGE(Bg, ldb, n0,       64, lds[1], 16384);
        STAGE(Bg, ldb, n0 + 128, 64, lds[1], 24576);
        STAGE(Ag, lda, m0,       64, lds[1], 0);
        asm volatile("s_waitcnt vmcnt(6)");
    } else {
        asm volatile("s_waitcnt vmcnt(0)");
    }
    BARRIER();

    for (int t = 0; t < nt; ++t) {
        const bf16* lb = lds[t & 1];
        bf16* lbw = lds[t & 1];
        bf16* lbn = lds[(t + 1) & 1];
        const int kt1 = (t + 1) << 6, kt2 = (t + 2) << 6;
        bf16x8 bfr[4][2];

        // ---- phase 0: B frags (8) + A rows 0-1; stage Ahi(t+1) -> other buf ----
        {
#pragma unroll
            for (int j = 0; j < 4; j++) {
                bfr[j][0] = *(const bf16x8*)(lb + boff + j * 1024 + pK0);
                bfr[j][1] = *(const bf16x8*)(lb + boff + j * 1024 + pK1);
            }
            bf16x8 a00 = *(const bf16x8*)(lb + aoff + 0 * 1024 + pK0);
            bf16x8 a01 = *(const bf16x8*)(lb + aoff + 0 * 1024 + pK1);
            bf16x8 a10 = *(const bf16x8*)(lb + aoff + 1 * 1024 + pK0);
            bf16x8 a11 = *(const bf16x8*)(lb + aoff + 1 * 1024 + pK1);
            if (t + 1 < nt) STAGE(Ag, lda, m0 + 128, kt1, lbn, 8192);
            BARRIER();
            asm volatile("s_waitcnt lgkmcnt(0)");
            __builtin_amdgcn_s_setprio(1);
#pragma unroll
            for (int j = 0; j < 4; j++) {
                acc[0][j] = __builtin_amdgcn_mfma_f32_16x16x32_bf16(a00, bfr[j][0], acc[0][j], 0, 0, 0);
                acc[0][j] = __builtin_amdgcn_mfma_f32_16x16x32_bf16(a01, bfr[j][1], acc[0][j], 0, 0, 0);
                acc[1][j] = __builtin_amdgcn_mfma_f32_16x16x32_bf16(a10, bfr[j][0], acc[1][j], 0, 0, 0);
                acc[1][j] = __builtin_amdgcn_mfma_f32_16x16x32_bf16(a11, bfr[j][1], acc[1][j], 0, 0, 0);
            }
            __builtin_amdgcn_s_setprio(0);
            BARRIER();
        }
        // ---- phase 1: A rows 2-3; stage Blo(t+2) -> current buf ----
        {
            bf16x8 a00 = *(const bf16x8*)(lb + aoff + 2 * 1024 + pK0);
            bf16x8 a01 = *(const bf16x8*)(lb + aoff + 2 * 1024 + pK1);
            bf16x8 a10 = *(const bf16x8*)(lb + aoff + 3 * 1024 + pK0);
            bf16x8 a11 = *(const bf16x8*)(lb + aoff + 3 * 1024 + pK1);
            if (t + 2 < nt) STAGE(Bg, ldb, n0, kt2, lbw, 16384);
            BARRIER();
            asm volatile("s_waitcnt lgkmcnt(0)");
            __builtin_amdgcn_s_setprio(1);
#pragma unroll
            for (int j = 0; j < 4; j++) {
                acc[2][j] = __builtin_amdgcn_mfma_f32_16x16x32_bf16(a00, bfr[j][0], acc[2][j], 0, 0, 0);
                acc[2][j] = __builtin_amdgcn_mfma_f32_16x16x32_bf16(a01, bfr[j][1], acc[2][j], 0, 0, 0);
                acc[3][j] = __builtin_amdgcn_mfma_f32_16x16x32_bf16(a10, bfr[j][0], acc[3][j], 0, 0, 0);
                acc[3][j] = __builtin_amdgcn_mfma_f32_16x16x32_bf16(a11, bfr[j][1], acc[3][j], 0, 0, 0);
            }
            __builtin_amdgcn_s_setprio(0);
            BARRIER();
        }
        // ---- phase 2: A rows 4-5; stage Bhi(t+2) ----
        {
            bf16x8 a00 = *(const bf16x8*)(lb + aoff + 4 * 1024 + pK0);
            bf16x8 a01 = *(const bf16x8*)(lb + aoff + 4 * 1024 + pK1);
            bf16x8 a10 = *(const bf16x8*)(lb + aoff + 5 * 1024 + pK0);
            bf16x8 a11 = *(const bf16x8*)(lb + aoff + 5 * 1024 + pK1);
            if (t + 2 < nt) STAGE(Bg, ldb, n0 + 128, kt2, lbw, 24576);
            BARRIER();
            asm volatile("s_waitcnt lgkmcnt(0)");
            __builtin_amdgcn_s_setprio(1);
#pragma unroll
            for (int j = 0; j < 4; j++) {
                acc[4][j] = __builtin_amdgcn_mfma_f32_16x16x32_bf16(a00, bfr[j][0], acc[4][j], 0, 0, 0);
                acc[4][j] = __builtin_amdgcn_mfma_f32_16x16x32_bf16(a01, bfr[j][1], acc[4][j], 0, 0, 0);
                acc[5][j] = __builtin_amdgcn_mfma_f32_16x16x32_bf16(a10, bfr[j][0], acc[5][j], 0, 0, 0);
                acc[5][j] = __builtin_amdgcn_mfma_f32_16x16x32_bf16(a11, bfr[j][1], acc[5][j], 0, 0, 0);
            }
            __builtin_amdgcn_s_setprio(0);
            BARRIER();
        }
        // ---- phase 3: A rows 6-7; stage Alo(t+2); tile-end counted vmcnt ----
        {
            bf16x8 a00 = *(const bf16x8*)(lb + aoff + 6 * 1024 + pK0);
            bf16x8 a01 = *(const bf16x8*)(lb + aoff + 6 * 1024 + pK1);
            bf16x8 a10 = *(const bf16x8*)(lb + aoff + 7 * 1024 + pK0);
            bf16x8 a11 = *(const bf16x8*)(lb + aoff + 7 * 1024 + pK1);
            if (t + 2 < nt) STAGE(Ag, lda, m0, kt2, lbw, 0);
            BARRIER();
            asm volatile("s_waitcnt lgkmcnt(0)");
            __builtin_amdgcn_s_setprio(1);
#pragma unroll
            for (int j = 0; j < 4; j++) {
                acc[6][j] = __builtin_amdgcn_mfma_f32_16x16x32_bf16(a00, bfr[j][0], acc[6][j], 0, 0, 0);
                acc[6][j] = __builtin_amdgcn_mfma_f32_16x16x32_bf16(a01, bfr[j][1], acc[6][j], 0, 0, 0);
                acc[7][j] = __builtin_amdgcn_mfma_f32_16x16x32_bf16(a10, bfr[j][0], acc[7][j], 0, 0, 0);
                acc[7][j] = __builtin_amdgcn_mfma_f32_16x16x32_bf16(a11, bfr[j][1], acc[7][j], 0, 0, 0);
            }
            __builtin_amdgcn_s_setprio(0);
            if (t < nt - 2)       { asm volatile("s_waitcnt vmcnt(6)"); }
            else if (t == nt - 2) { asm volatile("s_waitcnt vmcnt(0)"); }
            BARRIER();
        }
    }

    // ---- epilogue ----
    const int fq = (lane >> 4) * 4;
    bf16* Cb = (bf16*)C;
#pragma unroll
    for (int i = 0; i < 8; i++)
#pragma unroll
        for (int j = 0; j < 4; j++) {
            size_t cb = n0 + wn * 64 + j * 16 + fr;
            float bv = BIAS ? bias[cb] : 0.0f;
#pragma unroll
            for (int r = 0; r < 4; r++) {
                size_t m = m0 + wm * 128 + i * 16 + fq + r;
                size_t rb = (CMAP == 1) ? (m + ((m >> 10) << 6)) : m;
                float v = acc[i][j][r] + bv;
                if (MODE == 1) v *= scale;
                if (MODE == 3) v = gelu_f(v);
                Cb[rb * (size_t)ldc + cb] = (bf16)v;
            }
        }
}

// ---- 128x128 NT GEMM (swizzled LDS) for small-M GEMMs ----
// MODE 0: bf16 out. 1: bf16*scale. 2: fp32 +=. 3: bf16 gelu. 4: fp32 store (split-K partial).
// CMAP 0: linear. 2: lat->KV rows (1024+(m&63)+(m>>6)*1088).
template<int MODE, int CMAP, int BIAS>
__global__ __launch_bounds__(256) void gemm128(const bf16* __restrict__ A, int lda,
                                               const bf16* __restrict__ Bw, int ldb,
                                               void* __restrict__ C, int ldc,
                                               int K, float scale,
                                               const float* __restrict__ bias,
                                               long long czs) {
    __shared__ bf16 As[128 * 32];
    __shared__ bf16 Bs[128 * 32];
    const int tid = threadIdx.x;
    const int wave = tid >> 6;
    const int lane = tid & 63;
    const size_t m0 = (size_t)blockIdx.x * 128;
    const size_t n0 = (size_t)blockIdx.y * 128;
    const int wm = (wave >> 1) * 64;
    const int wn = (wave & 1) * 64;

    const int klen = K / gridDim.z;
    const int koff = blockIdx.z * klen;

    const int r0 = tid >> 2;
    const int c0 = ((tid & 3) ^ ((tid >> 3) & 3)) * 8;
    const bf16* ga0 = A + (m0 + r0) * lda + c0 + koff;
    const bf16* ga1 = A + (m0 + r0 + 64) * lda + c0 + koff;
    const bf16* gb0 = Bw + (n0 + r0) * ldb + c0 + koff;
    const bf16* gb1 = Bw + (n0 + r0 + 64) * ldb + c0 + koff;
    bf16* la0 = As + wave * 512;
    bf16* la1 = As + 2048 + wave * 512;
    bf16* lb0 = Bs + wave * 512;
    bf16* lb1 = Bs + 2048 + wave * 512;

    f32x4 acc[4][4];
#pragma unroll
    for (int i = 0; i < 4; i++)
#pragma unroll
        for (int j = 0; j < 4; j++)
#pragma unroll
            for (int r = 0; r < 4; r++) acc[i][j][r] = 0.0f;

    const int fr = lane & 15;
    const int q = lane >> 4;
    const int sw = (q ^ ((fr >> 1) & 3)) * 8;

    for (int kt = 0; kt < klen; kt += 32) {
        gload_lds16(ga0 + kt, la0);
        gload_lds16(ga1 + kt, la1);
        gload_lds16(gb0 + kt, lb0);
        gload_lds16(gb1 + kt, lb1);
        __syncthreads();
        bf16x8 af[4], bfv[4];
#pragma unroll
        for (int i = 0; i < 4; i++) {
            af[i]  = *(const bf16x8*)(As + (wm + i * 16 + fr) * 32 + sw);
            bfv[i] = *(const bf16x8*)(Bs + (wn + i * 16 + fr) * 32 + sw);
        }
#pragma unroll
        for (int i = 0; i < 4; i++)
#pragma unroll
            for (int j = 0; j < 4; j++)
                acc[i][j] = __builtin_amdgcn_mfma_f32_16x16x32_bf16(af[i], bfv[j], acc[i][j], 0, 0, 0);
        __syncthreads();
    }

    const int fq = (lane >> 4) * 4;
#pragma unroll
    for (int i = 0; i < 4; i++)
#pragma unroll
        for (int j = 0; j < 4; j++) {
            size_t cb = n0 + wn + j * 16 + fr;
            float bv = BIAS ? bias[cb] : 0.0f;
#pragma unroll
            for (int r = 0; r < 4; r++) {
                size_t m = m0 + wm + i * 16 + fq + r;
                size_t rb;
                if (CMAP == 2) rb = 1024 + (m & 63) + (m >> 6) * NKV_;
                else           rb = m;
                float v = acc[i][j][r] + bv;
                if (MODE == 2) {
                    ((float*)C)[rb * ldc + cb] += v;
                } else if (MODE == 4) {
                    ((float*)C + blockIdx.z * czs)[rb * ldc + cb] = v;
                } else {
                    if (MODE == 1) v *= scale;
                    if (MODE == 3) v = gelu_f(v);
                    ((bf16*)C)[rb * ldc + cb] = (bf16)v;
                }
            }
        }
}

// ---- QK: small batched NT GEMM (1 wave, 64x64 tile, direct global frags) ----
__global__ __launch_bounds__(64) void gemm_qk(const bf16* __restrict__ A, int lda,
                                              long long sAo, long long sAi,
                                              const bf16* __restrict__ Bm, int ldb,
                                              long long sBo, long long sBi,
                                              float* __restrict__ C, int ldc,
                                              long long sCo, long long sCi,
                                              int K) {
    int z = blockIdx.y;
    int n0 = blockIdx.x * 64;
    long long zo = z >> 3, zi = z & 7;
    const bf16* Ap = A + zo * sAo + zi * sAi;
    const bf16* Bp = Bm + zo * sBo + zi * sBi + (size_t)n0 * ldb;
    int lane = threadIdx.x;
    int fr = lane & 15, kq = (lane >> 4) * 8;

    f32x4 acc[4][4];
#pragma unroll
    for (int i = 0; i < 4; i++)
#pragma unroll
        for (int j = 0; j < 4; j++)
#pragma unroll
            for (int r = 0; r < 4; r++) acc[i][j][r] = 0.0f;

    for (int kt = 0; kt < K; kt += 32) {
        bf16x8 af[4], bfv[4];
#pragma unroll
        for (int i = 0; i < 4; i++)
            af[i] = *(const bf16x8*)(Ap + (size_t)(i * 16 + fr) * lda + kt + kq);
#pragma unroll
        for (int j = 0; j < 4; j++)
            bfv[j] = *(const bf16x8*)(Bp + (size_t)(j * 16 + fr) * ldb + kt + kq);
#pragma unroll
        for (int i = 0; i < 4; i++)
#pragma unroll
            for (int j = 0; j < 4; j++)
                acc[i][j] = __builtin_amdgcn_mfma_f32_16x16x32_bf16(af[i], bfv[j], acc[i][j], 0, 0, 0);
    }

    int fq = (lane >> 4) * 4;
    float* Cf = C + zo * sCo + zi * sCi;
#pragma unroll
    for (int i = 0; i < 4; i++)
#pragma unroll
        for (int j = 0; j < 4; j++)
#pragma unroll
            for (int r = 0; r < 4; r++)
                Cf[(size_t)(i * 16 + fq + r) * ldc + n0 + j * 16 + fr] = acc[i][j][r];
}

// ---- PV: 4-wave split-K per z, LDS tree reduce, bf16 store ----
__global__ __launch_bounds__(256) void gemm_pv(const bf16* __restrict__ P,
                                               const bf16* __restrict__ vt,
                                               bf16* __restrict__ ob) {
    __shared__ f32x4 red0[16 * 64];
    __shared__ f32x4 red1[16 * 64];
    int z = blockIdx.x;
    int bt = z >> 3, h = z & 7;
    const bf16* Ap = P + (size_t)bt * 8 * NL_ * 2 * NKV_ + (size_t)h * NL_ * 2 * NKV_;
    const bf16* Bp = vt + (size_t)z * (DH_ * NKV_);
    int tid = threadIdx.x, w = tid >> 6, lane = tid & 63;
    int fr = lane & 15, kq = (lane >> 4) * 8;
    int ks = w * 288;
    int ke = (w < 3) ? ks + 288 : NKV_;

    f32x4 acc[4][4];
#pragma unroll
    for (int i = 0; i < 4; i++)
#pragma unroll
        for (int j = 0; j < 4; j++)
#pragma unroll
            for (int r = 0; r < 4; r++) acc[i][j][r] = 0.0f;

    for (int kt = ks; kt < ke; kt += 32) {
        bf16x8 af[4], bfv[4];
#pragma unroll
        for (int i = 0; i < 4; i++)
            af[i] = *(const bf16x8*)(Ap + (size_t)(i * 16 + fr) * (2 * NKV_) + kt + kq);
#pragma unroll
        for (int j = 0; j < 4; j++)
            bfv[j] = *(const bf16x8*)(Bp + (size_t)(j * 16 + fr) * NKV_ + kt + kq);
#pragma unroll
        for (int i = 0; i < 4; i++)
#pragma unroll
            for (int j = 0; j < 4; j++)
                acc[i][j] = __builtin_amdgcn_mfma_f32_16x16x32_bf16(af[i], bfv[j], acc[i][j], 0, 0, 0);
    }

    if (w == 2) {
#pragma unroll
        for (int i = 0; i < 4; i++)
#pragma unroll
            for (int j = 0; j < 4; j++) red0[(i * 4 + j) * 64 + lane] = acc[i][j];
    } else if (w == 3) {
#pragma unroll
        for (int i = 0; i < 4; i++)
#pragma unroll
            for (int j = 0; j < 4; j++) red1[(i * 4 + j) * 64 + lane] = acc[i][j];
    }
    __syncthreads();
    if (w == 0) {
#pragma unroll
        for (int i = 0; i < 4; i++)
#pragma unroll
            for (int j = 0; j < 4; j++) acc[i][j] += red0[(i * 4 + j) * 64 + lane];
    } else if (w == 1) {
#pragma unroll
        for (int i = 0; i < 4; i++)
#pragma unroll
            for (int j = 0; j < 4; j++) acc[i][j] += red1[(i * 4 + j) * 64 + lane];
    }
    __syncthreads();
    if (w == 1) {
#pragma unroll
        for (int i = 0; i < 4; i++)
#pragma unroll
            for (int j = 0; j < 4; j++) red0[(i * 4 + j) * 64 + lane] = acc[i][j];
    }
    __syncthreads();
    if (w == 0) {
        int fq = (lane >> 4) * 4;
        bf16* Cb = ob + (size_t)bt * NL_ * INNER_ + (size_t)h * DH_;
#pragma unroll
        for (int i = 0; i < 4; i++)
#pragma unroll
            for (int j = 0; j < 4; j++) {
                f32x4 v = acc[i][j] + red0[(i * 4 + j) * 64 + lane];
#pragma unroll
                for (int r = 0; r < 4; r++)
                    Cb[(size_t)(i * 16 + fq + r) * INNER_ + j * 16 + fr] = (bf16)v[r];
            }
    }
}

// ---- softmax over 1088, in-place: fp32 scores -> bf16 probs at row start ----
__global__ __launch_bounds__(256) void softmax_k(float* __restrict__ simattn) {
    __shared__ float buf[NKV_];
    __shared__ float red[4];
    __shared__ float red2[4];
    float* s = simattn + (size_t)blockIdx.x * NKV_;
    int tid = threadIdx.x;
    float mx = -1e30f;
    for (int c = tid; c < NKV_; c += 256) { float v = s[c]; buf[c] = v; mx = fmaxf(mx, v); }
    mx = wred_max(mx);
    if ((tid & 63) == 0) red[tid >> 6] = mx;
    __syncthreads();
    mx = fmaxf(fmaxf(red[0], red[1]), fmaxf(red[2], red[3]));
    float sum = 0.0f;
    for (int c = tid; c < NKV_; c += 256) { float e = __expf(buf[c] - mx); buf[c] = e; sum += e; }
    sum = wred_sum(sum);
    if ((tid & 63) == 0) red2[tid >> 6] = sum;
    __syncthreads();
    sum = red2[0] + red2[1] + red2[2] + red2[3];
    float inv = 1.0f / sum;
    bf16* a = (bf16*)s;
    for (int c = tid; c < NKV_; c += 256) a[c] = (bf16)(buf[c] * inv);
}

// ---- FF2 partial add ----
__global__ __launch_bounds__(256) void ffadd_k(float* __restrict__ lat,
                                               const float* __restrict__ p0,
                                               const float* __restrict__ p1) {
    size_t i = (size_t)blockIdx.x * D_ + threadIdx.x * 4;
    float4 a = *(const float4*)(lat + i);
    float4 x = *(const float4*)(p0 + i);
    float4 y = *(const float4*)(p1 + i);
    a.x += x.x + y.x; a.y += x.y + y.y; a.z += x.z + y.z; a.w += x.w + y.w;
    *(float4*)(lat + i) = a;
}

// ---- host side ----
extern "C" void kernel_launch(void* const* d_in, const int* in_sizes, int n_in,
                              void* d_out, int out_size, void* d_ws, size_t ws_size,
                              hipStream_t stream) {
    const float* x       = (const float*)d_in[0];
    const float* latents = (const float*)d_in[1];
    const float* fe      = (const float*)d_in[2];
    const float* g_media = (const float*)d_in[3];
    const float* b_media = (const float*)d_in[4];
    const float* g_lat   = (const float*)d_in[5];
    const float* b_lat   = (const float*)d_in[6];
    const float* Wq      = (const float*)d_in[7];
    const float* Wkv     = (const float*)d_in[8];
    const float* Wo      = (const float*)d_in[9];
    const float* g_ff    = (const float*)d_in[10];
    const float* b_ff    = (const float*)d_in[11];
    const float* W1      = (const float*)d_in[12];
    const float* W2      = (const float*)d_in[13];
    const float* g_out   = (const float*)d_in[14];
    const float* b_out   = (const float*)d_in[15];

    char* p = (char*)d_ws;
    auto alloc = [&](size_t bytes) { char* r = p; p += (bytes + 255) & ~(size_t)255; return r; };
    bf16*  xhat = (bf16*)alloc((size_t)MROWS_ * D_ * 2);
    float* lat  = (float*)alloc((size_t)2048 * D_ * 4);
    bf16*  lnl  = (bf16*)alloc((size_t)2048 * D_ * 2);
    bf16*  qb   = (bf16*)alloc((size_t)2048 * INNER_ * 2);
    float* sim  = (float*)alloc((size_t)ZB_ * NL_ * NKV_ * 4);
    bf16*  KVb  = (bf16*)alloc((size_t)KVROWS_ * D_ * 2);
    bf16*  vt   = (bf16*)alloc((size_t)ZB_ * DH_ * NKV_ * 2);
    bf16*  ob   = (bf16*)alloc((size_t)2048 * INNER_ * 2);
    bf16*  WqT  = (bf16*)alloc((size_t)INNER_ * D_ * 2);
    bf16*  WkvT = (bf16*)alloc((size_t)D_ * D_ * 2);
    bf16*  WkvTg= (bf16*)alloc((size_t)D_ * D_ * 2);
    bf16*  WoT  = (bf16*)alloc((size_t)D_ * INNER_ * 2);
    bf16*  W1T  = (bf16*)alloc((size_t)FF_ * D_ * 2);
    bf16*  W2T  = (bf16*)alloc((size_t)D_ * FF_ * 2);
    float* bkv  = (float*)alloc(1024 * 4);
    bf16*  ffh  = vt;            // alias: vt dead once PV done
    float* ffp  = sim;           // alias: sim dead once PV done

    xhat_k<<<MROWS_, 256, 0, stream>>>(x, fe, xhat);
    latinit_k<<<2048, 256, 0, stream>>>(latents, lat);

    for (int l = 0; l < L_; l++) {
        const float* gm = g_media + (size_t)l * D_;
        const float* bm = b_media + (size_t)l * D_;
        const float* gl = g_lat + (size_t)l * D_;
        const float* bl = b_lat + (size_t)l * D_;
        const float* gf = g_ff + (size_t)l * D_;
        const float* bf_ = b_ff + (size_t)l * D_;
        const float* wq = Wq + (size_t)l * D_ * INNER_;
        const float* wkv = Wkv + (size_t)l * D_ * 2 * INNER_;
        const float* wo = Wo + (size_t)l * INNER_ * D_;
        const float* w1 = W1 + (size_t)l * D_ * FF_;
        const float* w2 = W2 + (size_t)l * FF_ * D_;

        ln_k<0><<<2048, 256, 0, stream>>>(lat, gl, bl, lnl);
        wprep_k<<<11264, 256, 0, stream>>>(wq, wkv, wo, w1, w2, gm,
                                           WqT, WkvT, WkvTg, WoT, W1T, W2T);
        hipMemsetAsync(bkv, 0, 1024 * 4, stream);
        bias_k<<<dim3(4, 8), 256, 0, stream>>>(bm, wkv, bkv);

        // KV x-part: xhat @ WkvTg + bkv  -> KV rows bt*1088 + [0,1024)   [8-phase 256²]
        gemm256<0, 1, 1><<<dim3(128, 4), 512, 0, stream>>>(
            xhat, D_, WkvTg, D_, KVb, 2 * INNER_, D_, 1.0f, bkv);
        // KV lat-part: lnl @ WkvT -> KV rows bt*1088 + 1024 + [0,64)
        gemm128<0, 2, 0><<<dim3(16, 8), 256, 0, stream>>>(
            lnl, D_, WkvT, D_, KVb, 2 * INNER_, D_, 1.0f, nullptr, 0);

        vtrans_k<<<dim3(34, 2, ZB_), 256, 0, stream>>>(KVb, vt);

        // q = (lnl @ WqT) * scale
        gemm128<1, 0, 0><<<dim3(16, 4), 256, 0, stream>>>(
            lnl, D_, WqT, D_, qb, INNER_, D_, 0.125f, nullptr, 0);

        // sim[z] = q_z @ k_z^T
        gemm_qk<<<dim3(17, ZB_), 64, 0, stream>>>(
            qb, INNER_, (long long)NL_ * INNER_, DH_,
            KVb, D_, (long long)NKV_ * D_, DH_,
            sim, NKV_, (long long)8 * NL_ * NKV_, (long long)NL_ * NKV_, DH_);

        softmax_k<<<ZB_ * NL_, 256, 0, stream>>>(sim);

        // o[z] = attn_z @ v_z (4-wave split-K)
        gemm_pv<<<ZB_, 256, 0, stream>>>((const bf16*)sim, vt, ob);

        // lat += o @ WoT
        gemm128<2, 0, 0><<<dim3(16, 8), 256, 0, stream>>>(
            ob, INNER_, WoT, INNER_, lat, D_, INNER_, 1.0f, nullptr, 0);

        // FF: ffh = gelu(LN(lat) @ W1T)   [8-phase 256²]
        ln_k<0><<<2048, 256, 0, stream>>>(lat, gf, bf_, lnl);
        gemm256<3, 0, 0><<<dim3(8, 16), 512, 0, stream>>>(
            lnl, D_, W1T, D_, ffh, FF_, D_, 1.0f, nullptr);
        gemm128<4, 0, 0><<<dim3(16, 8, 2), 256, 0, stream>>>(
            ffh, FF_, W2T, FF_, ffp, D_, FF_, 1.0f, nullptr, (long long)2048 * D_);
        ffadd_k<<<2048, 256, 0, stream>>>(lat, ffp, ffp + (size_t)2048 * D_);
    }

    ln_k<1><<<2048, 256, 0, stream>>>(lat, g_out, b_out, (float*)d_out);
}

// Round 4
// 1696.379 us; speedup vs baseline: 1.6277x; 1.3468x over previous
//
#include <hip/hip_runtime.h>
#include <math.h>

// ---- problem constants ----
#define D_      1024
#define DH_     64
#define H_      8
#define INNER_  512
#define L_      6
#define NL_     64
#define FF_     4096
#define B_      4
#define T_      8
#define FV_     1024          // F*V
#define BT_     32            // B*T
#define MROWS_  32768         // BT*FV
#define NKV_    1088          // FV + NL
#define KVROWS_ 34816         // BT*NKV
#define ZB_     256           // BT*H

typedef __bf16 bf16;
typedef __bf16 bf16x8 __attribute__((ext_vector_type(8)));
typedef __bf16 bf16x4 __attribute__((ext_vector_type(4)));
typedef float  f32x4  __attribute__((ext_vector_type(4)));

#define BARRIER() { asm volatile("" ::: "memory"); __builtin_amdgcn_s_barrier(); asm volatile("" ::: "memory"); }

// ---- helpers ----
__device__ __forceinline__ void gload_lds16(const bf16* g, bf16* l) {
    __builtin_amdgcn_global_load_lds(
        (const __attribute__((address_space(1))) unsigned int*)g,
        (__attribute__((address_space(3))) unsigned int*)l, 16, 0, 0);
}

__device__ __forceinline__ float wred_sum(float v) {
#pragma unroll
    for (int o = 32; o > 0; o >>= 1) v += __shfl_xor(v, o, 64);
    return v;
}
__device__ __forceinline__ float wred_max(float v) {
#pragma unroll
    for (int o = 32; o > 0; o >>= 1) v = fmaxf(v, __shfl_xor(v, o, 64));
    return v;
}

__device__ __forceinline__ float gelu_f(float x) {
    return 0.5f * x * (1.0f + erff(x * 0.70710678118654752440f));
}

// ---- xhat: LN-normalize (x + frame_embs[t]) once, no affine, bf16 out ----
__global__ __launch_bounds__(256) void xhat_k(const float* __restrict__ x,
                                              const float* __restrict__ fe,
                                              bf16* __restrict__ xhat) {
    __shared__ float red[8];
    int row = blockIdx.x;                // bt*FV + fv
    int t = (row >> 10) & 7;
    const float* xr = x + (size_t)row * D_;
    const float* fr_ = fe + (size_t)t * D_;
    int tid = threadIdx.x, c = tid * 4;
    float4 v = *(const float4*)(xr + c);
    float4 f = *(const float4*)(fr_ + c);
    v.x += f.x; v.y += f.y; v.z += f.z; v.w += f.w;
    float s = v.x + v.y + v.z + v.w;
    float ss = v.x * v.x + v.y * v.y + v.z * v.z + v.w * v.w;
    s = wred_sum(s); ss = wred_sum(ss);
    if ((tid & 63) == 0) { red[tid >> 6] = s; red[4 + (tid >> 6)] = ss; }
    __syncthreads();
    s = red[0] + red[1] + red[2] + red[3];
    ss = red[4] + red[5] + red[6] + red[7];
    float mean = s * (1.0f / D_);
    float rstd = rsqrtf(ss * (1.0f / D_) - mean * mean + 1e-5f);
    bf16x4 o;
    o[0] = (bf16)((v.x - mean) * rstd);
    o[1] = (bf16)((v.y - mean) * rstd);
    o[2] = (bf16)((v.z - mean) * rstd);
    o[3] = (bf16)((v.w - mean) * rstd);
    *(bf16x4*)(xhat + (size_t)row * D_ + c) = o;
}

// ---- lat init ----
__global__ __launch_bounds__(256) void latinit_k(const float* __restrict__ latents,
                                                 float* __restrict__ lat) {
    int row = blockIdx.x;
    int i = row & 63;
    int c = threadIdx.x * 4;
    float4 v = *(const float4*)(latents + (size_t)i * D_ + c);
    *(float4*)(lat + (size_t)row * D_ + c) = v;
}

// ---- row LayerNorm with affine: fp32 in, bf16 (OUTF=0) or fp32 (OUTF=1) out ----
template<int OUTF>
__global__ __launch_bounds__(256) void ln_k(const float* __restrict__ in,
                                            const float* __restrict__ g,
                                            const float* __restrict__ b,
                                            void* __restrict__ out) {
    __shared__ float red[8];
    int row = blockIdx.x;
    const float* x = in + (size_t)row * D_;
    int tid = threadIdx.x, c = tid * 4;
    float4 v = *(const float4*)(x + c);
    float s = v.x + v.y + v.z + v.w;
    float ss = v.x * v.x + v.y * v.y + v.z * v.z + v.w * v.w;
    s = wred_sum(s); ss = wred_sum(ss);
    if ((tid & 63) == 0) { red[tid >> 6] = s; red[4 + (tid >> 6)] = ss; }
    __syncthreads();
    s = red[0] + red[1] + red[2] + red[3];
    ss = red[4] + red[5] + red[6] + red[7];
    float mean = s * (1.0f / D_);
    float rstd = rsqrtf(ss * (1.0f / D_) - mean * mean + 1e-5f);
    float4 gv = *(const float4*)(g + c);
    float4 bv = *(const float4*)(b + c);
    float o0 = (v.x - mean) * rstd * gv.x + bv.x;
    float o1 = (v.y - mean) * rstd * gv.y + bv.y;
    float o2 = (v.z - mean) * rstd * gv.z + bv.z;
    float o3 = (v.w - mean) * rstd * gv.w + bv.w;
    if (OUTF) {
        *(float4*)((float*)out + (size_t)row * D_ + c) = make_float4(o0, o1, o2, o3);
    } else {
        bf16x4 o; o[0] = (bf16)o0; o[1] = (bf16)o1; o[2] = (bf16)o2; o[3] = (bf16)o3;
        *(bf16x4*)((bf16*)out + (size_t)row * D_ + c) = o;
    }
}

// ---- fused weight prep: transpose fp32->bf16, one launch per layer ----
__device__ __forceinline__ void wt_tile(const float* __restrict__ in, int R, int C,
                                        bf16* __restrict__ out, int bx, int by,
                                        const float* __restrict__ sc) {
    __shared__ float t[32][33];
    int c0 = bx * 32, r0 = by * 32;
    int tx = threadIdx.x & 31, ty = threadIdx.x >> 5;
#pragma unroll
    for (int i = 0; i < 4; i++)
        t[ty + i * 8][tx] = in[(size_t)(r0 + ty + i * 8) * C + c0 + tx];
    __syncthreads();
    float scale = sc ? sc[r0 + tx] : 1.0f;
#pragma unroll
    for (int i = 0; i < 4; i++)
        out[(size_t)(c0 + ty + i * 8) * R + r0 + tx] = (bf16)(t[tx][ty + i * 8] * scale);
}

__global__ __launch_bounds__(256) void wprep_k(const float* __restrict__ wq,
                                               const float* __restrict__ wkv,
                                               const float* __restrict__ wo,
                                               const float* __restrict__ w1,
                                               const float* __restrict__ w2,
                                               const float* __restrict__ gm,
                                               bf16* __restrict__ BcatQ,   // rows 0..511
                                               bf16* __restrict__ BcatKV,  // rows 512..1535
                                               bf16* __restrict__ WkvTg,
                                               bf16* __restrict__ WoT,
                                               bf16* __restrict__ W1T,
                                               bf16* __restrict__ W2T) {
    int id = blockIdx.x;
    if (id < 512)            wt_tile(wq, D_, INNER_, BcatQ, id & 15, id >> 4, nullptr);
    else if (id < 1536)  { int i = id - 512;  wt_tile(wkv, D_, 2 * INNER_, BcatKV, i & 31, i >> 5, nullptr); }
    else if (id < 2560)  { int i = id - 1536; wt_tile(wkv, D_, 2 * INNER_, WkvTg, i & 31, i >> 5, gm); }
    else if (id < 3072)  { int i = id - 2560; wt_tile(wo, INNER_, D_, WoT, i & 31, i >> 5, nullptr); }
    else if (id < 7168)  { int i = id - 3072; wt_tile(w1, D_, FF_, W1T, i & 127, i >> 7, nullptr); }
    else                 { int i = id - 7168; wt_tile(w2, FF_, D_, W2T, i & 31, i >> 5, nullptr); }
}

// ---- bkv[n] = sum_k bm[k] * wkv[k][n] (fp32, atomic partials) ----
__global__ __launch_bounds__(256) void bias_k(const float* __restrict__ bm,
                                              const float* __restrict__ wkv,
                                              float* __restrict__ bkv) {
    int n = blockIdx.x * 256 + threadIdx.x;
    int k0 = blockIdx.y * 128;
    float s = 0.0f;
    for (int k = k0; k < k0 + 128; k++) s += bm[k] * wkv[(size_t)k * (2 * INNER_) + n];
    atomicAdd(&bkv[n], s);
}

// ---- V transpose per (bt,h) ----
__global__ __launch_bounds__(256) void vtrans_k(const bf16* __restrict__ KV,
                                                bf16* __restrict__ vt) {
    __shared__ float t[32][33];
    int z = blockIdx.z, bt = z >> 3, h = z & 7;
    const bf16* src = KV + (size_t)bt * NKV_ * D_ + INNER_ + h * DH_;
    int j0 = blockIdx.x * 32, d0 = blockIdx.y * 32;
    int tx = threadIdx.x & 31, ty = threadIdx.x >> 5;
#pragma unroll
    for (int i = 0; i < 4; i++)
        t[ty + i * 8][tx] = (float)src[(size_t)(j0 + ty + i * 8) * D_ + d0 + tx];
    __syncthreads();
    bf16* dst = vt + (size_t)z * (DH_ * NKV_);
#pragma unroll
    for (int i = 0; i < 4; i++)
        dst[(size_t)(d0 + ty + i * 8) * NKV_ + j0 + tx] = (bf16)t[tx][ty + i * 8];
}

// ======== 256x256 8-phase deep-pipelined NT GEMM (T2+T3+T4+T5) ========
template<int MODE, int CMAP, int BIAS>
__global__ __launch_bounds__(512, 1) void gemm256(const bf16* __restrict__ Ag, int lda,
                                                  const bf16* __restrict__ Bg, int ldb,
                                                  void* __restrict__ C, int ldc,
                                                  int K, float scale,
                                                  const float* __restrict__ bias) {
    __shared__ bf16 lds[2][32768];   // [buf][Alo 0 | Ahi 8192 | Blo 16384 | Bhi 24576]
    const int tid = threadIdx.x;
    const int w = tid >> 6, lane = tid & 63;
    const int wm = w >> 2, wn = w & 3;
    const size_t m0 = (size_t)blockIdx.x * 256;
    const size_t n0 = (size_t)blockIdx.y * 256;
    const int nt = K >> 6;

    const int p0 = (w * 2) * 64 + lane, p1 = p0 + 64;
    const int sr0 = p0 >> 3, sk0 = ((p0 & 7) ^ (sr0 & 7)) * 8;
    const int sr1 = p1 >> 3, sk1 = ((p1 & 7) ^ (sr1 & 7)) * 8;
    const int scw0 = (w * 2) * 512, scw1 = scw0 + 512;

    auto STAGE = [&](const bf16* g, int ld, size_t row0, int k0, bf16* bufb, int rb) {
        gload_lds16(g + (row0 + sr0) * (size_t)ld + k0 + sk0, bufb + rb + scw0);
        gload_lds16(g + (row0 + sr1) * (size_t)ld + k0 + sk1, bufb + rb + scw1);
    };

    const int fr = lane & 15;
    const int pK0 = (((lane >> 4)) ^ (fr & 7)) * 8;
    const int pK1 = ((4 + (lane >> 4)) ^ (fr & 7)) * 8;
    const size_t aoff = (size_t)(wm * 128 + fr) * 64;
    const size_t boff = 16384 + (size_t)(wn * 64 + fr) * 64;

    f32x4 acc[8][4];
#pragma unroll
    for (int i = 0; i < 8; i++)
#pragma unroll
        for (int j = 0; j < 4; j++)
#pragma unroll
            for (int r = 0; r < 4; r++) acc[i][j][r] = 0.0f;

    STAGE(Bg, ldb, n0,       0, lds[0], 16384);
    STAGE(Bg, ldb, n0 + 128, 0, lds[0], 24576);
    STAGE(Ag, lda, m0,       0, lds[0], 0);
    STAGE(Ag, lda, m0 + 128, 0, lds[0], 8192);
    if (nt > 1) {
        STAGE(Bg, ldb, n0,       64, lds[1], 16384);
        STAGE(Bg, ldb, n0 + 128, 64, lds[1], 24576);
        STAGE(Ag, lda, m0,       64, lds[1], 0);
        asm volatile("s_waitcnt vmcnt(6)");
    } else {
        asm volatile("s_waitcnt vmcnt(0)");
    }
    BARRIER();

    for (int t = 0; t < nt; ++t) {
        const bf16* lb = lds[t & 1];
        bf16* lbw = lds[t & 1];
        bf16* lbn = lds[(t + 1) & 1];
        const int kt1 = (t + 1) << 6, kt2 = (t + 2) << 6;
        bf16x8 bfr[4][2];

        {
#pragma unroll
            for (int j = 0; j < 4; j++) {
                bfr[j][0] = *(const bf16x8*)(lb + boff + j * 1024 + pK0);
                bfr[j][1] = *(const bf16x8*)(lb + boff + j * 1024 + pK1);
            }
            bf16x8 a00 = *(const bf16x8*)(lb + aoff + 0 * 1024 + pK0);
            bf16x8 a01 = *(const bf16x8*)(lb + aoff + 0 * 1024 + pK1);
            bf16x8 a10 = *(const bf16x8*)(lb + aoff + 1 * 1024 + pK0);
            bf16x8 a11 = *(const bf16x8*)(lb + aoff + 1 * 1024 + pK1);
            if (t + 1 < nt) STAGE(Ag, lda, m0 + 128, kt1, lbn, 8192);
            BARRIER();
            asm volatile("s_waitcnt lgkmcnt(0)");
            __builtin_amdgcn_s_setprio(1);
#pragma unroll
            for (int j = 0; j < 4; j++) {
                acc[0][j] = __builtin_amdgcn_mfma_f32_16x16x32_bf16(a00, bfr[j][0], acc[0][j], 0, 0, 0);
                acc[0][j] = __builtin_amdgcn_mfma_f32_16x16x32_bf16(a01, bfr[j][1], acc[0][j], 0, 0, 0);
                acc[1][j] = __builtin_amdgcn_mfma_f32_16x16x32_bf16(a10, bfr[j][0], acc[1][j], 0, 0, 0);
                acc[1][j] = __builtin_amdgcn_mfma_f32_16x16x32_bf16(a11, bfr[j][1], acc[1][j], 0, 0, 0);
            }
            __builtin_amdgcn_s_setprio(0);
            BARRIER();
        }
        {
            bf16x8 a00 = *(const bf16x8*)(lb + aoff + 2 * 1024 + pK0);
            bf16x8 a01 = *(const bf16x8*)(lb + aoff + 2 * 1024 + pK1);
            bf16x8 a10 = *(const bf16x8*)(lb + aoff + 3 * 1024 + pK0);
            bf16x8 a11 = *(const bf16x8*)(lb + aoff + 3 * 1024 + pK1);
            if (t + 2 < nt) STAGE(Bg, ldb, n0, kt2, lbw, 16384);
            BARRIER();
            asm volatile("s_waitcnt lgkmcnt(0)");
            __builtin_amdgcn_s_setprio(1);
#pragma unroll
            for (int j = 0; j < 4; j++) {
                acc[2][j] = __builtin_amdgcn_mfma_f32_16x16x32_bf16(a00, bfr[j][0], acc[2][j], 0, 0, 0);
                acc[2][j] = __builtin_amdgcn_mfma_f32_16x16x32_bf16(a01, bfr[j][1], acc[2][j], 0, 0, 0);
                acc[3][j] = __builtin_amdgcn_mfma_f32_16x16x32_bf16(a10, bfr[j][0], acc[3][j], 0, 0, 0);
                acc[3][j] = __builtin_amdgcn_mfma_f32_16x16x32_bf16(a11, bfr[j][1], acc[3][j], 0, 0, 0);
            }
            __builtin_amdgcn_s_setprio(0);
            BARRIER();
        }
        {
            bf16x8 a00 = *(const bf16x8*)(lb + aoff + 4 * 1024 + pK0);
            bf16x8 a01 = *(const bf16x8*)(lb + aoff + 4 * 1024 + pK1);
            bf16x8 a10 = *(const bf16x8*)(lb + aoff + 5 * 1024 + pK0);
            bf16x8 a11 = *(const bf16x8*)(lb + aoff + 5 * 1024 + pK1);
            if (t + 2 < nt) STAGE(Bg, ldb, n0 + 128, kt2, lbw, 24576);
            BARRIER();
            asm volatile("s_waitcnt lgkmcnt(0)");
            __builtin_amdgcn_s_setprio(1);
#pragma unroll
            for (int j = 0; j < 4; j++) {
                acc[4][j] = __builtin_amdgcn_mfma_f32_16x16x32_bf16(a00, bfr[j][0], acc[4][j], 0, 0, 0);
                acc[4][j] = __builtin_amdgcn_mfma_f32_16x16x32_bf16(a01, bfr[j][1], acc[4][j], 0, 0, 0);
                acc[5][j] = __builtin_amdgcn_mfma_f32_16x16x32_bf16(a10, bfr[j][0], acc[5][j], 0, 0, 0);
                acc[5][j] = __builtin_amdgcn_mfma_f32_16x16x32_bf16(a11, bfr[j][1], acc[5][j], 0, 0, 0);
            }
            __builtin_amdgcn_s_setprio(0);
            BARRIER();
        }
        {
            bf16x8 a00 = *(const bf16x8*)(lb + aoff + 6 * 1024 + pK0);
            bf16x8 a01 = *(const bf16x8*)(lb + aoff + 6 * 1024 + pK1);
            bf16x8 a10 = *(const bf16x8*)(lb + aoff + 7 * 1024 + pK0);
            bf16x8 a11 = *(const bf16x8*)(lb + aoff + 7 * 1024 + pK1);
            if (t + 2 < nt) STAGE(Ag, lda, m0, kt2, lbw, 0);
            BARRIER();
            asm volatile("s_waitcnt lgkmcnt(0)");
            __builtin_amdgcn_s_setprio(1);
#pragma unroll
            for (int j = 0; j < 4; j++) {
                acc[6][j] = __builtin_amdgcn_mfma_f32_16x16x32_bf16(a00, bfr[j][0], acc[6][j], 0, 0, 0);
                acc[6][j] = __builtin_amdgcn_mfma_f32_16x16x32_bf16(a01, bfr[j][1], acc[6][j], 0, 0, 0);
                acc[7][j] = __builtin_amdgcn_mfma_f32_16x16x32_bf16(a10, bfr[j][0], acc[7][j], 0, 0, 0);
                acc[7][j] = __builtin_amdgcn_mfma_f32_16x16x32_bf16(a11, bfr[j][1], acc[7][j], 0, 0, 0);
            }
            __builtin_amdgcn_s_setprio(0);
            if (t < nt - 2)       { asm volatile("s_waitcnt vmcnt(6)"); }
            else if (t == nt - 2) { asm volatile("s_waitcnt vmcnt(0)"); }
            BARRIER();
        }
    }

    const int fq = (lane >> 4) * 4;
    bf16* Cb = (bf16*)C;
#pragma unroll
    for (int i = 0; i < 8; i++)
#pragma unroll
        for (int j = 0; j < 4; j++) {
            size_t cb = n0 + wn * 64 + j * 16 + fr;
            float bv = BIAS ? bias[cb] : 0.0f;
#pragma unroll
            for (int r = 0; r < 4; r++) {
                size_t m = m0 + wm * 128 + i * 16 + fq + r;
                size_t rb = (CMAP == 1) ? (m + ((m >> 10) << 6)) : m;
                float v = acc[i][j][r] + bv;
                if (MODE == 1) v *= scale;
                if (MODE == 3) v = gelu_f(v);
                Cb[rb * (size_t)ldc + cb] = (bf16)v;
            }
        }
}

// ---- 128x128 NT GEMM (swizzled LDS) for small-M GEMMs ----
// MODE 2: fp32 +=. 4: fp32 store (split-K partial, czs stride).
// CMAP 3: col<512 -> qb*scale; col>=512 -> KV lat rows (C2).
template<int MODE, int CMAP, int BIAS>
__global__ __launch_bounds__(256) void gemm128(const bf16* __restrict__ A, int lda,
                                               const bf16* __restrict__ Bw, int ldb,
                                               void* __restrict__ C, int ldc,
                                               int K, float scale,
                                               const float* __restrict__ bias,
                                               long long czs, void* __restrict__ C2) {
    __shared__ bf16 As[128 * 32];
    __shared__ bf16 Bs[128 * 32];
    const int tid = threadIdx.x;
    const int wave = tid >> 6;
    const int lane = tid & 63;
    const size_t m0 = (size_t)blockIdx.x * 128;
    const size_t n0 = (size_t)blockIdx.y * 128;
    const int wm = (wave >> 1) * 64;
    const int wn = (wave & 1) * 64;

    const int klen = K / gridDim.z;
    const int koff = blockIdx.z * klen;

    const int r0 = tid >> 2;
    const int c0 = ((tid & 3) ^ ((tid >> 3) & 3)) * 8;
    const bf16* ga0 = A + (m0 + r0) * lda + c0 + koff;
    const bf16* ga1 = A + (m0 + r0 + 64) * lda + c0 + koff;
    const bf16* gb0 = Bw + (n0 + r0) * ldb + c0 + koff;
    const bf16* gb1 = Bw + (n0 + r0 + 64) * ldb + c0 + koff;
    bf16* la0 = As + wave * 512;
    bf16* la1 = As + 2048 + wave * 512;
    bf16* lb0 = Bs + wave * 512;
    bf16* lb1 = Bs + 2048 + wave * 512;

    f32x4 acc[4][4];
#pragma unroll
    for (int i = 0; i < 4; i++)
#pragma unroll
        for (int j = 0; j < 4; j++)
#pragma unroll
            for (int r = 0; r < 4; r++) acc[i][j][r] = 0.0f;

    const int fr = lane & 15;
    const int q = lane >> 4;
    const int sw = (q ^ ((fr >> 1) & 3)) * 8;

    for (int kt = 0; kt < klen; kt += 32) {
        gload_lds16(ga0 + kt, la0);
        gload_lds16(ga1 + kt, la1);
        gload_lds16(gb0 + kt, lb0);
        gload_lds16(gb1 + kt, lb1);
        __syncthreads();
        bf16x8 af[4], bfv[4];
#pragma unroll
        for (int i = 0; i < 4; i++) {
            af[i]  = *(const bf16x8*)(As + (wm + i * 16 + fr) * 32 + sw);
            bfv[i] = *(const bf16x8*)(Bs + (wn + i * 16 + fr) * 32 + sw);
        }
#pragma unroll
        for (int i = 0; i < 4; i++)
#pragma unroll
            for (int j = 0; j < 4; j++)
                acc[i][j] = __builtin_amdgcn_mfma_f32_16x16x32_bf16(af[i], bfv[j], acc[i][j], 0, 0, 0);
        __syncthreads();
    }

    const int fq = (lane >> 4) * 4;
#pragma unroll
    for (int i = 0; i < 4; i++)
#pragma unroll
        for (int j = 0; j < 4; j++) {
            size_t cb = n0 + wn + j * 16 + fr;
            float bv = BIAS ? bias[cb] : 0.0f;
#pragma unroll
            for (int r = 0; r < 4; r++) {
                size_t m = m0 + wm + i * 16 + fq + r;
                float v = acc[i][j][r] + bv;
                if (CMAP == 3) {
                    if (cb < 512) ((bf16*)C)[m * 512 + cb] = (bf16)(v * scale);
                    else ((bf16*)C2)[(1024 + (m & 63) + (m >> 6) * (size_t)NKV_) * 1024 + (cb - 512)] = (bf16)v;
                } else if (MODE == 2) {
                    ((float*)C)[m * ldc + cb] += v;
                } else if (MODE == 4) {
                    ((float*)C + blockIdx.z * czs)[m * ldc + cb] = v;
                } else {
                    ((bf16*)C)[m * ldc + cb] = (bf16)v;
                }
            }
        }
}

// ======== fused attention: QK^T + online softmax + PV, one block per z ========
// 4 waves; wave w handles key-chunks {w, w+4, ...} (64 keys each, 17 chunks).
// Swapped QK (mfma(K,Q) -> C[key][q]); P bounced via per-wave LDS tile (72-pad);
// per-wave (m,l,O) combined across waves with max-correction in LDS.
__global__ __launch_bounds__(256, 2) void attn_k(const bf16* __restrict__ qb,
                                                 const bf16* __restrict__ KVb,
                                                 const bf16* __restrict__ vt,
                                                 bf16* __restrict__ ob) {
    __shared__ float comb[4][64 * 66];   // 67.6KB; chunk phase: per-wave P bounce aliases comb[w]
    __shared__ float sc[4][64];
    __shared__ float mw[4][64], lw[4][64];
    const int z = blockIdx.x, bt = z >> 3, h = z & 7;
    const int tid = threadIdx.x, w = tid >> 6, lane = tid & 63;
    const int fr = lane & 15, g = lane >> 4;
    const bf16* Qz = qb + (size_t)(bt * 64) * INNER_ + h * DH_;
    const bf16* Kz = KVb + (size_t)bt * NKV_ * D_ + h * DH_;
    const bf16* Vz = vt + (size_t)z * (DH_ * NKV_);
    bf16* Pw = (bf16*)(&comb[w][0]);     // 64x72 bf16 (9216B < 16896B per-wave region)

    // Q B-frags: B[n=q][k=d]
    bf16x8 qf[4][2];
#pragma unroll
    for (int nj = 0; nj < 4; nj++)
#pragma unroll
        for (int ks = 0; ks < 2; ks++)
            qf[nj][ks] = *(const bf16x8*)(Qz + (size_t)(fr + 16 * nj) * INNER_ + g * 8 + ks * 32);

    f32x4 acc_o[4][4];
#pragma unroll
    for (int i = 0; i < 4; i++)
#pragma unroll
        for (int j = 0; j < 4; j++)
#pragma unroll
            for (int r = 0; r < 4; r++) acc_o[i][j][r] = 0.0f;
    float m_reg[4] = {-INFINITY, -INFINITY, -INFINITY, -INFINITY};
    float l_reg[4] = {0.0f, 0.0f, 0.0f, 0.0f};

    const int nch = (w == 0) ? 5 : 4;
    for (int ci = 0; ci < nch; ci++) {
        const int kc0 = (w + ci * 4) * 64;
        // ---- S^T chunk = mfma(K, Q): C[key][q] ----
        f32x4 s[4][4];
#pragma unroll
        for (int i = 0; i < 4; i++)
#pragma unroll
            for (int j = 0; j < 4; j++)
#pragma unroll
                for (int r = 0; r < 4; r++) s[i][j][r] = 0.0f;
#pragma unroll
        for (int ks = 0; ks < 2; ks++) {
            bf16x8 kf[4];
#pragma unroll
            for (int mi = 0; mi < 4; mi++)
                kf[mi] = *(const bf16x8*)(Kz + (size_t)(kc0 + fr + 16 * mi) * D_ + g * 8 + ks * 32);
#pragma unroll
            for (int mi = 0; mi < 4; mi++)
#pragma unroll
                for (int nj = 0; nj < 4; nj++)
                    s[mi][nj] = __builtin_amdgcn_mfma_f32_16x16x32_bf16(kf[mi], qf[nj][ks], s[mi][nj], 0, 0, 0);
        }
        // ---- chunk max per q (cols); reduce over quad groups ----
        float pmax[4];
#pragma unroll
        for (int nj = 0; nj < 4; nj++) {
            float mx = s[0][nj][0];
#pragma unroll
            for (int mi = 0; mi < 4; mi++)
#pragma unroll
                for (int r = 0; r < 4; r++) mx = fmaxf(mx, s[mi][nj][r]);
            mx = fmaxf(mx, __shfl_xor(mx, 16, 64));
            mx = fmaxf(mx, __shfl_xor(mx, 32, 64));
            pmax[nj] = mx;
        }
        bool grew = (pmax[0] > m_reg[0]) || (pmax[1] > m_reg[1]) ||
                    (pmax[2] > m_reg[2]) || (pmax[3] > m_reg[3]);
        if (__any(grew ? 1 : 0)) {
            float so[4];
#pragma unroll
            for (int nj = 0; nj < 4; nj++) {
                float mn = fmaxf(m_reg[nj], pmax[nj]);
                so[nj] = __expf(m_reg[nj] - mn);
                m_reg[nj] = mn;
                l_reg[nj] *= so[nj];
            }
            if (g == 0) {
#pragma unroll
                for (int nj = 0; nj < 4; nj++) sc[w][fr + 16 * nj] = so[nj];
            }
            asm volatile("s_waitcnt lgkmcnt(0)" ::: "memory");
            // rescale O (row q = 16mi + 4g + r)
#pragma unroll
            for (int mi = 0; mi < 4; mi++)
#pragma unroll
                for (int r = 0; r < 4; r++) {
                    float sq = sc[w][16 * mi + 4 * g + r];
#pragma unroll
                    for (int jd = 0; jd < 4; jd++) acc_o[mi][jd][r] *= sq;
                }
        }
        // ---- P = exp(s - m) -> bf16 into Pw; accumulate l ----
        float psum[4] = {0.0f, 0.0f, 0.0f, 0.0f};
#pragma unroll
        for (int mi = 0; mi < 4; mi++)
#pragma unroll
            for (int nj = 0; nj < 4; nj++) {
                bf16x4 pb4;
#pragma unroll
                for (int r = 0; r < 4; r++) {
                    float pv = __expf(s[mi][nj][r] - m_reg[nj]);
                    psum[nj] += pv;
                    pb4[r] = (bf16)pv;
                }
                *(bf16x4*)(Pw + (size_t)(fr + 16 * nj) * 72 + 16 * mi + 4 * g) = pb4;
            }
#pragma unroll
        for (int nj = 0; nj < 4; nj++) {
            float ps = psum[nj];
            ps += __shfl_xor(ps, 16, 64);
            ps += __shfl_xor(ps, 32, 64);
            l_reg[nj] += ps;
        }
        asm volatile("s_waitcnt lgkmcnt(0)" ::: "memory");
        // ---- PV: O[q][d] += P @ V ----
#pragma unroll
        for (int ks = 0; ks < 2; ks++) {
            bf16x8 af[4], vf[4];
#pragma unroll
            for (int mi = 0; mi < 4; mi++)
                af[mi] = *(const bf16x8*)(Pw + (size_t)(fr + 16 * mi) * 72 + g * 8 + ks * 32);
#pragma unroll
            for (int jd = 0; jd < 4; jd++)
                vf[jd] = *(const bf16x8*)(Vz + (size_t)(fr + 16 * jd) * NKV_ + kc0 + g * 8 + ks * 32);
#pragma unroll
            for (int mi = 0; mi < 4; mi++)
#pragma unroll
                for (int jd = 0; jd < 4; jd++)
                    acc_o[mi][jd] = __builtin_amdgcn_mfma_f32_16x16x32_bf16(af[mi], vf[jd], acc_o[mi][jd], 0, 0, 0);
        }
    }

    // ---- write per-wave stats and O (own region only), then combine ----
    if (g == 0) {
#pragma unroll
        for (int nj = 0; nj < 4; nj++) {
            mw[w][fr + 16 * nj] = m_reg[nj];
            lw[w][fr + 16 * nj] = l_reg[nj];
        }
    }
    asm volatile("s_waitcnt lgkmcnt(0)" ::: "memory");   // Pw reads done before overwrite
#pragma unroll
    for (int mi = 0; mi < 4; mi++)
#pragma unroll
        for (int jd = 0; jd < 4; jd++)
#pragma unroll
            for (int r = 0; r < 4; r++)
                comb[w][(16 * mi + 4 * g + r) * 66 + fr + 16 * jd] = acc_o[mi][jd][r];
    __syncthreads();
    {
        int q = tid >> 2, d0 = (tid & 3) * 16;
        float M = fmaxf(fmaxf(mw[0][q], mw[1][q]), fmaxf(mw[2][q], mw[3][q]));
        float al[4], l = 0.0f;
#pragma unroll
        for (int ww = 0; ww < 4; ww++) { al[ww] = __expf(mw[ww][q] - M); l += al[ww] * lw[ww][q]; }
        float inv = 1.0f / l;
        bf16 outv[16];
#pragma unroll
        for (int dd = 0; dd < 16; dd++) {
            float o = 0.0f;
#pragma unroll
            for (int ww = 0; ww < 4; ww++) o += comb[ww][q * 66 + d0 + dd] * al[ww];
            outv[dd] = (bf16)(o * inv);
        }
        bf16* dst = ob + (size_t)(bt * 64 + q) * INNER_ + h * 64 + d0;
        *(bf16x8*)dst = *(bf16x8*)outv;
        *(bf16x8*)(dst + 8) = *(bf16x8*)(outv + 8);
    }
}

// ---- FF2 partial add: lat += p0+p1+p2+p3 ----
__global__ __launch_bounds__(256) void ffadd4_k(float* __restrict__ lat,
                                                const float* __restrict__ p,
                                                long long s) {
    size_t i = (size_t)blockIdx.x * D_ + threadIdx.x * 4;
    float4 a = *(const float4*)(lat + i);
#pragma unroll
    for (int w = 0; w < 4; w++) {
        float4 x = *(const float4*)(p + w * s + i);
        a.x += x.x; a.y += x.y; a.z += x.z; a.w += x.w;
    }
    *(float4*)(lat + i) = a;
}

// ---- host side ----
extern "C" void kernel_launch(void* const* d_in, const int* in_sizes, int n_in,
                              void* d_out, int out_size, void* d_ws, size_t ws_size,
                              hipStream_t stream) {
    const float* x       = (const float*)d_in[0];
    const float* latents = (const float*)d_in[1];
    const float* fe      = (const float*)d_in[2];
    const float* g_media = (const float*)d_in[3];
    const float* b_media = (const float*)d_in[4];
    const float* g_lat   = (const float*)d_in[5];
    const float* b_lat   = (const float*)d_in[6];
    const float* Wq      = (const float*)d_in[7];
    const float* Wkv     = (const float*)d_in[8];
    const float* Wo      = (const float*)d_in[9];
    const float* g_ff    = (const float*)d_in[10];
    const float* b_ff    = (const float*)d_in[11];
    const float* W1      = (const float*)d_in[12];
    const float* W2      = (const float*)d_in[13];
    const float* g_out   = (const float*)d_in[14];
    const float* b_out   = (const float*)d_in[15];

    char* p = (char*)d_ws;
    auto alloc = [&](size_t bytes) { char* r = p; p += (bytes + 255) & ~(size_t)255; return r; };
    bf16*  xhat = (bf16*)alloc((size_t)MROWS_ * D_ * 2);          // 67 MB
    float* lat  = (float*)alloc((size_t)2048 * D_ * 4);           // 8 MB
    bf16*  lnl  = (bf16*)alloc((size_t)2048 * D_ * 2);            // 4 MB
    bf16*  qb   = (bf16*)alloc((size_t)2048 * INNER_ * 2);        // 2 MB
    bf16*  KVb  = (bf16*)alloc((size_t)KVROWS_ * D_ * 2);         // 71 MB
    bf16*  vt   = (bf16*)alloc((size_t)ZB_ * DH_ * NKV_ * 2);     // 36 MB
    bf16*  ob   = (bf16*)alloc((size_t)2048 * INNER_ * 2);        // 2 MB
    bf16*  Bcat = (bf16*)alloc((size_t)1536 * D_ * 2);            // 3 MB (WqT rows 0-511 | WkvT rows 512-1535)
    bf16*  WkvTg= (bf16*)alloc((size_t)D_ * D_ * 2);
    bf16*  WoT  = (bf16*)alloc((size_t)D_ * INNER_ * 2);
    bf16*  W1T  = (bf16*)alloc((size_t)FF_ * D_ * 2);
    bf16*  W2T  = (bf16*)alloc((size_t)D_ * FF_ * 2);
    float* bkv  = (float*)alloc(1024 * 4);
    float* ffp  = (float*)alloc((size_t)4 * 2048 * D_ * 4);       // 32 MB
    bf16*  ffh  = vt;            // alias: vt dead once attn done

    xhat_k<<<MROWS_, 256, 0, stream>>>(x, fe, xhat);
    latinit_k<<<2048, 256, 0, stream>>>(latents, lat);

    for (int l = 0; l < L_; l++) {
        const float* gm = g_media + (size_t)l * D_;
        const float* bm = b_media + (size_t)l * D_;
        const float* gl = g_lat + (size_t)l * D_;
        const float* bl = b_lat + (size_t)l * D_;
        const float* gf = g_ff + (size_t)l * D_;
        const float* bf_ = b_ff + (size_t)l * D_;
        const float* wq = Wq + (size_t)l * D_ * INNER_;
        const float* wkv = Wkv + (size_t)l * D_ * 2 * INNER_;
        const float* wo = Wo + (size_t)l * INNER_ * D_;
        const float* w1 = W1 + (size_t)l * D_ * FF_;
        const float* w2 = W2 + (size_t)l * FF_ * D_;

        ln_k<0><<<2048, 256, 0, stream>>>(lat, gl, bl, lnl);
        wprep_k<<<11264, 256, 0, stream>>>(wq, wkv, wo, w1, w2, gm,
                                           Bcat, Bcat + (size_t)512 * D_, WkvTg, WoT, W1T, W2T);
        hipMemsetAsync(bkv, 0, 1024 * 4, stream);
        bias_k<<<dim3(4, 8), 256, 0, stream>>>(bm, wkv, bkv);

        // KV x-part: xhat @ WkvTg + bkv  -> KV rows bt*1088 + [0,1024)   [8-phase 256²]
        gemm256<0, 1, 1><<<dim3(128, 4), 512, 0, stream>>>(
            xhat, D_, WkvTg, D_, KVb, 2 * INNER_, D_, 1.0f, bkv);
        // merged: q = (lnl @ WqT)*scale  and  KV lat rows = lnl @ WkvT
        gemm128<0, 3, 0><<<dim3(16, 12), 256, 0, stream>>>(
            lnl, D_, Bcat, D_, qb, 0, D_, 0.125f, nullptr, 0, KVb);

        vtrans_k<<<dim3(34, 2, ZB_), 256, 0, stream>>>(KVb, vt);

        // fused attention -> ob
        attn_k<<<ZB_, 256, 0, stream>>>(qb, KVb, vt, ob);

        // lat += o @ WoT
        gemm128<2, 0, 0><<<dim3(16, 8), 256, 0, stream>>>(
            ob, INNER_, WoT, INNER_, lat, D_, INNER_, 1.0f, nullptr, 0, nullptr);

        // FF: ffh = gelu(LN(lat) @ W1T)   [8-phase 256²]
        ln_k<0><<<2048, 256, 0, stream>>>(lat, gf, bf_, lnl);
        gemm256<3, 0, 0><<<dim3(8, 16), 512, 0, stream>>>(
            lnl, D_, W1T, D_, ffh, FF_, D_, 1.0f, nullptr);
        gemm128<4, 0, 0><<<dim3(16, 8, 4), 256, 0, stream>>>(
            ffh, FF_, W2T, FF_, ffp, D_, FF_, 1.0f, nullptr, (long long)2048 * D_, nullptr);
        ffadd4_k<<<2048, 256, 0, stream>>>(lat, ffp, (long long)2048 * D_);
    }

    ln_k<1><<<2048, 256, 0, stream>>>(lat, g_out, b_out, (float*)d_out);
}

// Round 5
// 1582.698 us; speedup vs baseline: 1.7446x; 1.0718x over previous
//
#include <hip/hip_runtime.h>
#include <math.h>

// ---- problem constants ----
#define D_      1024
#define DH_     64
#define H_      8
#define INNER_  512
#define L_      6
#define NL_     64
#define FF_     4096
#define B_      4
#define T_      8
#define FV_     1024          // F*V
#define BT_     32            // B*T
#define MROWS_  32768         // BT*FV
#define NKV_    1088          // FV + NL
#define KVROWS_ 34816         // BT*NKV
#define ZB_     256           // BT*H

typedef __bf16 bf16;
typedef __bf16 bf16x8 __attribute__((ext_vector_type(8)));
typedef __bf16 bf16x4 __attribute__((ext_vector_type(4)));
typedef float  f32x4  __attribute__((ext_vector_type(4)));

#define BARRIER() { asm volatile("" ::: "memory"); __builtin_amdgcn_s_barrier(); asm volatile("" ::: "memory"); }

// ---- helpers ----
__device__ __forceinline__ void gload_lds16(const bf16* g, bf16* l) {
    __builtin_amdgcn_global_load_lds(
        (const __attribute__((address_space(1))) unsigned int*)g,
        (__attribute__((address_space(3))) unsigned int*)l, 16, 0, 0);
}

__device__ __forceinline__ float wred_sum(float v) {
#pragma unroll
    for (int o = 32; o > 0; o >>= 1) v += __shfl_xor(v, o, 64);
    return v;
}

__device__ __forceinline__ float gelu_f(float x) {
    return 0.5f * x * (1.0f + erff(x * 0.70710678118654752440f));
}

// ---- xhat: LN-normalize (x + frame_embs[t]) once, no affine, bf16 out ----
__global__ __launch_bounds__(256) void xhat_k(const float* __restrict__ x,
                                              const float* __restrict__ fe,
                                              bf16* __restrict__ xhat) {
    __shared__ float red[8];
    int row = blockIdx.x;                // bt*FV + fv
    int t = (row >> 10) & 7;
    const float* xr = x + (size_t)row * D_;
    const float* fr_ = fe + (size_t)t * D_;
    int tid = threadIdx.x, c = tid * 4;
    float4 v = *(const float4*)(xr + c);
    float4 f = *(const float4*)(fr_ + c);
    v.x += f.x; v.y += f.y; v.z += f.z; v.w += f.w;
    float s = v.x + v.y + v.z + v.w;
    float ss = v.x * v.x + v.y * v.y + v.z * v.z + v.w * v.w;
    s = wred_sum(s); ss = wred_sum(ss);
    if ((tid & 63) == 0) { red[tid >> 6] = s; red[4 + (tid >> 6)] = ss; }
    __syncthreads();
    s = red[0] + red[1] + red[2] + red[3];
    ss = red[4] + red[5] + red[6] + red[7];
    float mean = s * (1.0f / D_);
    float rstd = rsqrtf(ss * (1.0f / D_) - mean * mean + 1e-5f);
    bf16x4 o;
    o[0] = (bf16)((v.x - mean) * rstd);
    o[1] = (bf16)((v.y - mean) * rstd);
    o[2] = (bf16)((v.z - mean) * rstd);
    o[3] = (bf16)((v.w - mean) * rstd);
    *(bf16x4*)(xhat + (size_t)row * D_ + c) = o;
}

// ---- lat init ----
__global__ __launch_bounds__(256) void latinit_k(const float* __restrict__ latents,
                                                 float* __restrict__ lat) {
    int row = blockIdx.x;
    int i = row & 63;
    int c = threadIdx.x * 4;
    float4 v = *(const float4*)(latents + (size_t)i * D_ + c);
    *(float4*)(lat + (size_t)row * D_ + c) = v;
}

// ---- row LayerNorm with affine: fp32 in, bf16 out ----
template<int OUTF>
__global__ __launch_bounds__(256) void ln_k(const float* __restrict__ in,
                                            const float* __restrict__ g,
                                            const float* __restrict__ b,
                                            void* __restrict__ out) {
    __shared__ float red[8];
    int row = blockIdx.x;
    const float* x = in + (size_t)row * D_;
    int tid = threadIdx.x, c = tid * 4;
    float4 v = *(const float4*)(x + c);
    float s = v.x + v.y + v.z + v.w;
    float ss = v.x * v.x + v.y * v.y + v.z * v.z + v.w * v.w;
    s = wred_sum(s); ss = wred_sum(ss);
    if ((tid & 63) == 0) { red[tid >> 6] = s; red[4 + (tid >> 6)] = ss; }
    __syncthreads();
    s = red[0] + red[1] + red[2] + red[3];
    ss = red[4] + red[5] + red[6] + red[7];
    float mean = s * (1.0f / D_);
    float rstd = rsqrtf(ss * (1.0f / D_) - mean * mean + 1e-5f);
    float4 gv = *(const float4*)(g + c);
    float4 bv = *(const float4*)(b + c);
    float o0 = (v.x - mean) * rstd * gv.x + bv.x;
    float o1 = (v.y - mean) * rstd * gv.y + bv.y;
    float o2 = (v.z - mean) * rstd * gv.z + bv.z;
    float o3 = (v.w - mean) * rstd * gv.w + bv.w;
    if (OUTF) {
        *(float4*)((float*)out + (size_t)row * D_ + c) = make_float4(o0, o1, o2, o3);
    } else {
        bf16x4 o; o[0] = (bf16)o0; o[1] = (bf16)o1; o[2] = (bf16)o2; o[3] = (bf16)o3;
        *(bf16x4*)((bf16*)out + (size_t)row * D_ + c) = o;
    }
}

// ---- accln: lat += sum of NP partials; LN(lat) -> out. OUTF 0: bf16 lnl; 1: fp32 out ----
template<int NP, int OUTF>
__global__ __launch_bounds__(256) void accln_k(float* __restrict__ lat,
                                               const float* __restrict__ p, long long s,
                                               const float* __restrict__ g,
                                               const float* __restrict__ b,
                                               void* __restrict__ out) {
    __shared__ float red[8];
    int row = blockIdx.x;
    int tid = threadIdx.x, c = tid * 4;
    float* lr = lat + (size_t)row * D_;
    float4 a = *(const float4*)(lr + c);
#pragma unroll
    for (int w = 0; w < NP; w++) {
        float4 x = *(const float4*)(p + (size_t)w * s + (size_t)row * D_ + c);
        a.x += x.x; a.y += x.y; a.z += x.z; a.w += x.w;
    }
    if (!OUTF) *(float4*)(lr + c) = a;
    float sm = a.x + a.y + a.z + a.w;
    float ss = a.x * a.x + a.y * a.y + a.z * a.z + a.w * a.w;
    sm = wred_sum(sm); ss = wred_sum(ss);
    if ((tid & 63) == 0) { red[tid >> 6] = sm; red[4 + (tid >> 6)] = ss; }
    __syncthreads();
    sm = red[0] + red[1] + red[2] + red[3];
    ss = red[4] + red[5] + red[6] + red[7];
    float mean = sm * (1.0f / D_);
    float rstd = rsqrtf(ss * (1.0f / D_) - mean * mean + 1e-5f);
    float4 gv = *(const float4*)(g + c);
    float4 bv = *(const float4*)(b + c);
    float o0 = (a.x - mean) * rstd * gv.x + bv.x;
    float o1 = (a.y - mean) * rstd * gv.y + bv.y;
    float o2 = (a.z - mean) * rstd * gv.z + bv.z;
    float o3 = (a.w - mean) * rstd * gv.w + bv.w;
    if (OUTF) {
        *(float4*)((float*)out + (size_t)row * D_ + c) = make_float4(o0, o1, o2, o3);
    } else {
        bf16x4 o; o[0] = (bf16)o0; o[1] = (bf16)o1; o[2] = (bf16)o2; o[3] = (bf16)o3;
        *(bf16x4*)((bf16*)out + (size_t)row * D_ + c) = o;
    }
}

// ---- fused weight prep: transpose fp32->bf16, one launch per layer ----
__device__ __forceinline__ void wt_tile(const float* __restrict__ in, int R, int C,
                                        bf16* __restrict__ out, int bx, int by,
                                        const float* __restrict__ sc) {
    __shared__ float t[32][33];
    int c0 = bx * 32, r0 = by * 32;
    int tx = threadIdx.x & 31, ty = threadIdx.x >> 5;
#pragma unroll
    for (int i = 0; i < 4; i++)
        t[ty + i * 8][tx] = in[(size_t)(r0 + ty + i * 8) * C + c0 + tx];
    __syncthreads();
    float scale = sc ? sc[r0 + tx] : 1.0f;
#pragma unroll
    for (int i = 0; i < 4; i++)
        out[(size_t)(c0 + ty + i * 8) * R + r0 + tx] = (bf16)(t[tx][ty + i * 8] * scale);
}

__global__ __launch_bounds__(256) void wprep_k(const float* __restrict__ wq,
                                               const float* __restrict__ wkv,
                                               const float* __restrict__ wo,
                                               const float* __restrict__ w1,
                                               const float* __restrict__ w2,
                                               const float* __restrict__ gm,
                                               bf16* __restrict__ BcatQ,   // rows 0..511
                                               bf16* __restrict__ BcatKV,  // rows 512..1535
                                               bf16* __restrict__ WkvTg,
                                               bf16* __restrict__ WoT,
                                               bf16* __restrict__ W1T,
                                               bf16* __restrict__ W2T) {
    int id = blockIdx.x;
    if (id < 512)            wt_tile(wq, D_, INNER_, BcatQ, id & 15, id >> 4, nullptr);
    else if (id < 1536)  { int i = id - 512;  wt_tile(wkv, D_, 2 * INNER_, BcatKV, i & 31, i >> 5, nullptr); }
    else if (id < 2560)  { int i = id - 1536; wt_tile(wkv, D_, 2 * INNER_, WkvTg, i & 31, i >> 5, gm); }
    else if (id < 3072)  { int i = id - 2560; wt_tile(wo, INNER_, D_, WoT, i & 31, i >> 5, nullptr); }
    else if (id < 7168)  { int i = id - 3072; wt_tile(w1, D_, FF_, W1T, i & 127, i >> 7, nullptr); }
    else                 { int i = id - 7168; wt_tile(w2, FF_, D_, W2T, i & 31, i >> 5, nullptr); }
}

// ---- bkv[n] = sum_k bm[k] * wkv[k][n] (single pass, no atomics) ----
__global__ __launch_bounds__(256) void bias_k(const float* __restrict__ bm,
                                              const float* __restrict__ wkv,
                                              float* __restrict__ bkv) {
    int n = blockIdx.x * 256 + threadIdx.x;
    float s = 0.0f;
    for (int k = 0; k < D_; k++) s += bm[k] * wkv[(size_t)k * (2 * INNER_) + n];
    bkv[n] = s;
}

// ======== KV GEMM: 256x256 8-phase pipelined NT (T2+T3+T4+T5) ========
// A=xhat (32768 x 1024), B=WkvTg (1024 x 1024). Epilogue splits columns:
//   cb<512  -> K part into KVb (ld 512), row = bt*1088 + j, +bias
//   cb>=512 -> V part TRANSPOSED into vt[(bt*8+h)*64+dh][j], +bias
__global__ __launch_bounds__(512, 1) void gemm_kv(const bf16* __restrict__ Ag,
                                                  const bf16* __restrict__ Bg,
                                                  bf16* __restrict__ KVb,
                                                  bf16* __restrict__ vt,
                                                  const float* __restrict__ bias) {
    __shared__ bf16 lds[2][32768];   // [buf][Alo 0 | Ahi 8192 | Blo 16384 | Bhi 24576]
    const int lda = D_, ldb = D_;
    const int tid = threadIdx.x;
    const int w = tid >> 6, lane = tid & 63;
    const int wm = w >> 2, wn = w & 3;
    const size_t m0 = (size_t)blockIdx.x * 256;
    const size_t n0 = (size_t)blockIdx.y * 256;
    const int nt = 16;   // K=1024, BK=64

    const int p0 = (w * 2) * 64 + lane, p1 = p0 + 64;
    const int sr0 = p0 >> 3, sk0 = ((p0 & 7) ^ (sr0 & 7)) * 8;
    const int sr1 = p1 >> 3, sk1 = ((p1 & 7) ^ (sr1 & 7)) * 8;
    const int scw0 = (w * 2) * 512, scw1 = scw0 + 512;

    auto STAGE = [&](const bf16* g, int ld, size_t row0, int k0, bf16* bufb, int rb) {
        gload_lds16(g + (row0 + sr0) * (size_t)ld + k0 + sk0, bufb + rb + scw0);
        gload_lds16(g + (row0 + sr1) * (size_t)ld + k0 + sk1, bufb + rb + scw1);
    };

    const int fr = lane & 15;
    const int pK0 = (((lane >> 4)) ^ (fr & 7)) * 8;
    const int pK1 = ((4 + (lane >> 4)) ^ (fr & 7)) * 8;
    const size_t aoff = (size_t)(wm * 128 + fr) * 64;
    const size_t boff = 16384 + (size_t)(wn * 64 + fr) * 64;

    f32x4 acc[8][4];
#pragma unroll
    for (int i = 0; i < 8; i++)
#pragma unroll
        for (int j = 0; j < 4; j++)
#pragma unroll
            for (int r = 0; r < 4; r++) acc[i][j][r] = 0.0f;

    STAGE(Bg, ldb, n0,       0, lds[0], 16384);
    STAGE(Bg, ldb, n0 + 128, 0, lds[0], 24576);
    STAGE(Ag, lda, m0,       0, lds[0], 0);
    STAGE(Ag, lda, m0 + 128, 0, lds[0], 8192);
    STAGE(Bg, ldb, n0,       64, lds[1], 16384);
    STAGE(Bg, ldb, n0 + 128, 64, lds[1], 24576);
    STAGE(Ag, lda, m0,       64, lds[1], 0);
    asm volatile("s_waitcnt vmcnt(6)");
    BARRIER();

    for (int t = 0; t < nt; ++t) {
        const bf16* lb = lds[t & 1];
        bf16* lbw = lds[t & 1];
        bf16* lbn = lds[(t + 1) & 1];
        const int kt1 = (t + 1) << 6, kt2 = (t + 2) << 6;
        bf16x8 bfr[4][2];

        {
#pragma unroll
            for (int j = 0; j < 4; j++) {
                bfr[j][0] = *(const bf16x8*)(lb + boff + j * 1024 + pK0);
                bfr[j][1] = *(const bf16x8*)(lb + boff + j * 1024 + pK1);
            }
            bf16x8 a00 = *(const bf16x8*)(lb + aoff + 0 * 1024 + pK0);
            bf16x8 a01 = *(const bf16x8*)(lb + aoff + 0 * 1024 + pK1);
            bf16x8 a10 = *(const bf16x8*)(lb + aoff + 1 * 1024 + pK0);
            bf16x8 a11 = *(const bf16x8*)(lb + aoff + 1 * 1024 + pK1);
            if (t + 1 < nt) STAGE(Ag, lda, m0 + 128, kt1, lbn, 8192);
            BARRIER();
            asm volatile("s_waitcnt lgkmcnt(0)");
            __builtin_amdgcn_s_setprio(1);
#pragma unroll
            for (int j = 0; j < 4; j++) {
                acc[0][j] = __builtin_amdgcn_mfma_f32_16x16x32_bf16(a00, bfr[j][0], acc[0][j], 0, 0, 0);
                acc[0][j] = __builtin_amdgcn_mfma_f32_16x16x32_bf16(a01, bfr[j][1], acc[0][j], 0, 0, 0);
                acc[1][j] = __builtin_amdgcn_mfma_f32_16x16x32_bf16(a10, bfr[j][0], acc[1][j], 0, 0, 0);
                acc[1][j] = __builtin_amdgcn_mfma_f32_16x16x32_bf16(a11, bfr[j][1], acc[1][j], 0, 0, 0);
            }
            __builtin_amdgcn_s_setprio(0);
            BARRIER();
        }
        {
            bf16x8 a00 = *(const bf16x8*)(lb + aoff + 2 * 1024 + pK0);
            bf16x8 a01 = *(const bf16x8*)(lb + aoff + 2 * 1024 + pK1);
            bf16x8 a10 = *(const bf16x8*)(lb + aoff + 3 * 1024 + pK0);
            bf16x8 a11 = *(const bf16x8*)(lb + aoff + 3 * 1024 + pK1);
            if (t + 2 < nt) STAGE(Bg, ldb, n0, kt2, lbw, 16384);
            BARRIER();
            asm volatile("s_waitcnt lgkmcnt(0)");
            __builtin_amdgcn_s_setprio(1);
#pragma unroll
            for (int j = 0; j < 4; j++) {
                acc[2][j] = __builtin_amdgcn_mfma_f32_16x16x32_bf16(a00, bfr[j][0], acc[2][j], 0, 0, 0);
                acc[2][j] = __builtin_amdgcn_mfma_f32_16x16x32_bf16(a01, bfr[j][1], acc[2][j], 0, 0, 0);
                acc[3][j] = __builtin_amdgcn_mfma_f32_16x16x32_bf16(a10, bfr[j][0], acc[3][j], 0, 0, 0);
                acc[3][j] = __builtin_amdgcn_mfma_f32_16x16x32_bf16(a11, bfr[j][1], acc[3][j], 0, 0, 0);
            }
            __builtin_amdgcn_s_setprio(0);
            BARRIER();
        }
        {
            bf16x8 a00 = *(const bf16x8*)(lb + aoff + 4 * 1024 + pK0);
            bf16x8 a01 = *(const bf16x8*)(lb + aoff + 4 * 1024 + pK1);
            bf16x8 a10 = *(const bf16x8*)(lb + aoff + 5 * 1024 + pK0);
            bf16x8 a11 = *(const bf16x8*)(lb + aoff + 5 * 1024 + pK1);
            if (t + 2 < nt) STAGE(Bg, ldb, n0 + 128, kt2, lbw, 24576);
            BARRIER();
            asm volatile("s_waitcnt lgkmcnt(0)");
            __builtin_amdgcn_s_setprio(1);
#pragma unroll
            for (int j = 0; j < 4; j++) {
                acc[4][j] = __builtin_amdgcn_mfma_f32_16x16x32_bf16(a00, bfr[j][0], acc[4][j], 0, 0, 0);
                acc[4][j] = __builtin_amdgcn_mfma_f32_16x16x32_bf16(a01, bfr[j][1], acc[4][j], 0, 0, 0);
                acc[5][j] = __builtin_amdgcn_mfma_f32_16x16x32_bf16(a10, bfr[j][0], acc[5][j], 0, 0, 0);
                acc[5][j] = __builtin_amdgcn_mfma_f32_16x16x32_bf16(a11, bfr[j][1], acc[5][j], 0, 0, 0);
            }
            __builtin_amdgcn_s_setprio(0);
            BARRIER();
        }
        {
            bf16x8 a00 = *(const bf16x8*)(lb + aoff + 6 * 1024 + pK0);
            bf16x8 a01 = *(const bf16x8*)(lb + aoff + 6 * 1024 + pK1);
            bf16x8 a10 = *(const bf16x8*)(lb + aoff + 7 * 1024 + pK0);
            bf16x8 a11 = *(const bf16x8*)(lb + aoff + 7 * 1024 + pK1);
            if (t + 2 < nt) STAGE(Ag, lda, m0, kt2, lbw, 0);
            BARRIER();
            asm volatile("s_waitcnt lgkmcnt(0)");
            __builtin_amdgcn_s_setprio(1);
#pragma unroll
            for (int j = 0; j < 4; j++) {
                acc[6][j] = __builtin_amdgcn_mfma_f32_16x16x32_bf16(a00, bfr[j][0], acc[6][j], 0, 0, 0);
                acc[6][j] = __builtin_amdgcn_mfma_f32_16x16x32_bf16(a01, bfr[j][1], acc[6][j], 0, 0, 0);
                acc[7][j] = __builtin_amdgcn_mfma_f32_16x16x32_bf16(a10, bfr[j][0], acc[7][j], 0, 0, 0);
                acc[7][j] = __builtin_amdgcn_mfma_f32_16x16x32_bf16(a11, bfr[j][1], acc[7][j], 0, 0, 0);
            }
            __builtin_amdgcn_s_setprio(0);
            if (t < nt - 2)       { asm volatile("s_waitcnt vmcnt(6)"); }
            else if (t == nt - 2) { asm volatile("s_waitcnt vmcnt(0)"); }
            BARRIER();
        }
    }

    // epilogue: K -> KVb (ld 512), V -> vt transposed
    const int fq = (lane >> 4) * 4;
#pragma unroll
    for (int i = 0; i < 8; i++)
#pragma unroll
        for (int j = 0; j < 4; j++) {
            size_t cb = n0 + wn * 64 + j * 16 + fr;
            float bv = bias[cb];
            size_t mb = m0 + wm * 128 + i * 16 + fq;
            if (cb < 512) {
#pragma unroll
                for (int r = 0; r < 4; r++) {
                    size_t m = mb + r;
                    size_t rb = m + ((m >> 10) << 6);
                    KVb[rb * 512 + cb] = (bf16)(acc[i][j][r] + bv);
                }
            } else {
                int hh = ((int)cb - 512) >> 6, dh = ((int)cb - 512) & 63;
                size_t bt = mb >> 10, jl = mb & 1023;
                bf16x4 v4;
#pragma unroll
                for (int r = 0; r < 4; r++) v4[r] = (bf16)(acc[i][j][r] + bv);
                *(bf16x4*)(vt + ((bt * 8 + hh) * 64 + dh) * (size_t)NKV_ + jl) = v4;
            }
        }
}

// ---- 128x128 NT GEMM (swizzled LDS) ----
// MODE 3: bf16 gelu. 4: fp32 store (split-K partial, czs stride).
// CMAP 3: cb<512 -> qb*scale; 512<=cb<1024 -> KVb K-part (ld 512, lat rows);
//         cb>=1024 -> vt transposed (lat rows).
template<int MODE, int CMAP>
__global__ __launch_bounds__(256) void gemm128(const bf16* __restrict__ A, int lda,
                                               const bf16* __restrict__ Bw, int ldb,
                                               void* __restrict__ C, int ldc,
                                               int K, float scale,
                                               long long czs, void* __restrict__ C2,
                                               void* __restrict__ C3) {
    __shared__ bf16 As[128 * 32];
    __shared__ bf16 Bs[128 * 32];
    const int tid = threadIdx.x;
    const int wave = tid >> 6;
    const int lane = tid & 63;
    const size_t m0 = (size_t)blockIdx.x * 128;
    const size_t n0 = (size_t)blockIdx.y * 128;
    const int wm = (wave >> 1) * 64;
    const int wn = (wave & 1) * 64;

    const int klen = K / gridDim.z;
    const int koff = blockIdx.z * klen;

    const int r0 = tid >> 2;
    const int c0 = ((tid & 3) ^ ((tid >> 3) & 3)) * 8;
    const bf16* ga0 = A + (m0 + r0) * lda + c0 + koff;
    const bf16* ga1 = A + (m0 + r0 + 64) * lda + c0 + koff;
    const bf16* gb0 = Bw + (n0 + r0) * ldb + c0 + koff;
    const bf16* gb1 = Bw + (n0 + r0 + 64) * ldb + c0 + koff;
    bf16* la0 = As + wave * 512;
    bf16* la1 = As + 2048 + wave * 512;
    bf16* lb0 = Bs + wave * 512;
    bf16* lb1 = Bs + 2048 + wave * 512;

    f32x4 acc[4][4];
#pragma unroll
    for (int i = 0; i < 4; i++)
#pragma unroll
        for (int j = 0; j < 4; j++)
#pragma unroll
            for (int r = 0; r < 4; r++) acc[i][j][r] = 0.0f;

    const int fr = lane & 15;
    const int q = lane >> 4;
    const int sw = (q ^ ((fr >> 1) & 3)) * 8;

    for (int kt = 0; kt < klen; kt += 32) {
        gload_lds16(ga0 + kt, la0);
        gload_lds16(ga1 + kt, la1);
        gload_lds16(gb0 + kt, lb0);
        gload_lds16(gb1 + kt, lb1);
        __syncthreads();
        bf16x8 af[4], bfv[4];
#pragma unroll
        for (int i = 0; i < 4; i++) {
            af[i]  = *(const bf16x8*)(As + (wm + i * 16 + fr) * 32 + sw);
            bfv[i] = *(const bf16x8*)(Bs + (wn + i * 16 + fr) * 32 + sw);
        }
#pragma unroll
        for (int i = 0; i < 4; i++)
#pragma unroll
            for (int j = 0; j < 4; j++)
                acc[i][j] = __builtin_amdgcn_mfma_f32_16x16x32_bf16(af[i], bfv[j], acc[i][j], 0, 0, 0);
        __syncthreads();
    }

    const int fq = (lane >> 4) * 4;
#pragma unroll
    for (int i = 0; i < 4; i++)
#pragma unroll
        for (int j = 0; j < 4; j++) {
            size_t cb = n0 + wn + j * 16 + fr;
            size_t mb = m0 + wm + i * 16 + fq;
            if (CMAP == 3) {
                if (cb < 512) {
#pragma unroll
                    for (int r = 0; r < 4; r++)
                        ((bf16*)C)[(mb + r) * 512 + cb] = (bf16)(acc[i][j][r] * scale);
                } else if (cb < 1024) {
#pragma unroll
                    for (int r = 0; r < 4; r++) {
                        size_t m = mb + r;
                        size_t rb = (m >> 6) * (size_t)NKV_ + 1024 + (m & 63);
                        ((bf16*)C2)[rb * 512 + (cb - 512)] = (bf16)acc[i][j][r];
                    }
                } else {
                    int hh = ((int)cb - 1024) >> 6, dh = ((int)cb - 1024) & 63;
                    size_t bt = mb >> 6, jl = 1024 + (mb & 63);
                    bf16x4 v4;
#pragma unroll
                    for (int r = 0; r < 4; r++) v4[r] = (bf16)acc[i][j][r];
                    *(bf16x4*)((bf16*)C3 + ((bt * 8 + hh) * 64 + dh) * (size_t)NKV_ + jl) = v4;
                }
            } else {
#pragma unroll
                for (int r = 0; r < 4; r++) {
                    float v = acc[i][j][r];
                    if (MODE == 4) {
                        ((float*)C + blockIdx.z * czs)[(mb + r) * ldc + cb] = v;
                    } else {
                        if (MODE == 3) v = gelu_f(v);
                        ((bf16*)C)[(mb + r) * ldc + cb] = (bf16)v;
                    }
                }
            }
        }
}

// ======== fused attention: QK^T + online softmax + PV, one block per z ========
__global__ __launch_bounds__(256, 2) void attn_k(const bf16* __restrict__ qb,
                                                 const bf16* __restrict__ KVb,
                                                 const bf16* __restrict__ vt,
                                                 bf16* __restrict__ ob) {
    __shared__ float comb[4][64 * 66];
    __shared__ float sc[4][64];
    __shared__ float mw[4][64], lw[4][64];
    const int z = blockIdx.x, bt = z >> 3, h = z & 7;
    const int tid = threadIdx.x, w = tid >> 6, lane = tid & 63;
    const int fr = lane & 15, g = lane >> 4;
    const bf16* Qz = qb + (size_t)(bt * 64) * INNER_ + h * DH_;
    const bf16* Kz = KVb + (size_t)bt * NKV_ * 512 + h * DH_;   // K rows, ld 512
    const bf16* Vz = vt + (size_t)z * (DH_ * NKV_);
    bf16* Pw = (bf16*)(&comb[w][0]);

    bf16x8 qf[4][2];
#pragma unroll
    for (int nj = 0; nj < 4; nj++)
#pragma unroll
        for (int ks = 0; ks < 2; ks++)
            qf[nj][ks] = *(const bf16x8*)(Qz + (size_t)(fr + 16 * nj) * INNER_ + g * 8 + ks * 32);

    f32x4 acc_o[4][4];
#pragma unroll
    for (int i = 0; i < 4; i++)
#pragma unroll
        for (int j = 0; j < 4; j++)
#pragma unroll
            for (int r = 0; r < 4; r++) acc_o[i][j][r] = 0.0f;
    float m_reg[4] = {-INFINITY, -INFINITY, -INFINITY, -INFINITY};
    float l_reg[4] = {0.0f, 0.0f, 0.0f, 0.0f};

    const int nch = (w == 0) ? 5 : 4;
    for (int ci = 0; ci < nch; ci++) {
        const int kc0 = (w + ci * 4) * 64;
        f32x4 s[4][4];
#pragma unroll
        for (int i = 0; i < 4; i++)
#pragma unroll
            for (int j = 0; j < 4; j++)
#pragma unroll
                for (int r = 0; r < 4; r++) s[i][j][r] = 0.0f;
#pragma unroll
        for (int ks = 0; ks < 2; ks++) {
            bf16x8 kf[4];
#pragma unroll
            for (int mi = 0; mi < 4; mi++)
                kf[mi] = *(const bf16x8*)(Kz + (size_t)(kc0 + fr + 16 * mi) * 512 + g * 8 + ks * 32);
#pragma unroll
            for (int mi = 0; mi < 4; mi++)
#pragma unroll
                for (int nj = 0; nj < 4; nj++)
                    s[mi][nj] = __builtin_amdgcn_mfma_f32_16x16x32_bf16(kf[mi], qf[nj][ks], s[mi][nj], 0, 0, 0);
        }
        float pmax[4];
#pragma unroll
        for (int nj = 0; nj < 4; nj++) {
            float mx = s[0][nj][0];
#pragma unroll
            for (int mi = 0; mi < 4; mi++)
#pragma unroll
                for (int r = 0; r < 4; r++) mx = fmaxf(mx, s[mi][nj][r]);
            mx = fmaxf(mx, __shfl_xor(mx, 16, 64));
            mx = fmaxf(mx, __shfl_xor(mx, 32, 64));
            pmax[nj] = mx;
        }
        bool grew = (pmax[0] > m_reg[0]) || (pmax[1] > m_reg[1]) ||
                    (pmax[2] > m_reg[2]) || (pmax[3] > m_reg[3]);
        if (__any(grew ? 1 : 0)) {
            float so[4];
#pragma unroll
            for (int nj = 0; nj < 4; nj++) {
                float mn = fmaxf(m_reg[nj], pmax[nj]);
                so[nj] = __expf(m_reg[nj] - mn);
                m_reg[nj] = mn;
                l_reg[nj] *= so[nj];
            }
            if (g == 0) {
#pragma unroll
                for (int nj = 0; nj < 4; nj++) sc[w][fr + 16 * nj] = so[nj];
            }
            asm volatile("s_waitcnt lgkmcnt(0)" ::: "memory");
#pragma unroll
            for (int mi = 0; mi < 4; mi++)
#pragma unroll
                for (int r = 0; r < 4; r++) {
                    float sq = sc[w][16 * mi + 4 * g + r];
#pragma unroll
                    for (int jd = 0; jd < 4; jd++) acc_o[mi][jd][r] *= sq;
                }
        }
        float psum[4] = {0.0f, 0.0f, 0.0f, 0.0f};
#pragma unroll
        for (int mi = 0; mi < 4; mi++)
#pragma unroll
            for (int nj = 0; nj < 4; nj++) {
                bf16x4 pb4;
#pragma unroll
                for (int r = 0; r < 4; r++) {
                    float pv = __expf(s[mi][nj][r] - m_reg[nj]);
                    psum[nj] += pv;
                    pb4[r] = (bf16)pv;
                }
                *(bf16x4*)(Pw + (size_t)(fr + 16 * nj) * 72 + 16 * mi + 4 * g) = pb4;
            }
#pragma unroll
        for (int nj = 0; nj < 4; nj++) {
            float ps = psum[nj];
            ps += __shfl_xor(ps, 16, 64);
            ps += __shfl_xor(ps, 32, 64);
            l_reg[nj] += ps;
        }
        asm volatile("s_waitcnt lgkmcnt(0)" ::: "memory");
#pragma unroll
        for (int ks = 0; ks < 2; ks++) {
            bf16x8 af[4], vf[4];
#pragma unroll
            for (int mi = 0; mi < 4; mi++)
                af[mi] = *(const bf16x8*)(Pw + (size_t)(fr + 16 * mi) * 72 + g * 8 + ks * 32);
#pragma unroll
            for (int jd = 0; jd < 4; jd++)
                vf[jd] = *(const bf16x8*)(Vz + (size_t)(fr + 16 * jd) * NKV_ + kc0 + g * 8 + ks * 32);
#pragma unroll
            for (int mi = 0; mi < 4; mi++)
#pragma unroll
                for (int jd = 0; jd < 4; jd++)
                    acc_o[mi][jd] = __builtin_amdgcn_mfma_f32_16x16x32_bf16(af[mi], vf[jd], acc_o[mi][jd], 0, 0, 0);
        }
    }

    if (g == 0) {
#pragma unroll
        for (int nj = 0; nj < 4; nj++) {
            mw[w][fr + 16 * nj] = m_reg[nj];
            lw[w][fr + 16 * nj] = l_reg[nj];
        }
    }
    asm volatile("s_waitcnt lgkmcnt(0)" ::: "memory");
#pragma unroll
    for (int mi = 0; mi < 4; mi++)
#pragma unroll
        for (int jd = 0; jd < 4; jd++)
#pragma unroll
            for (int r = 0; r < 4; r++)
                comb[w][(16 * mi + 4 * g + r) * 66 + fr + 16 * jd] = acc_o[mi][jd][r];
    __syncthreads();
    {
        int q = tid >> 2, d0 = (tid & 3) * 16;
        float M = fmaxf(fmaxf(mw[0][q], mw[1][q]), fmaxf(mw[2][q], mw[3][q]));
        float al[4], l = 0.0f;
#pragma unroll
        for (int ww = 0; ww < 4; ww++) { al[ww] = __expf(mw[ww][q] - M); l += al[ww] * lw[ww][q]; }
        float inv = 1.0f / l;
        bf16 outv[16];
#pragma unroll
        for (int dd = 0; dd < 16; dd++) {
            float o = 0.0f;
#pragma unroll
            for (int ww = 0; ww < 4; ww++) o += comb[ww][q * 66 + d0 + dd] * al[ww];
            outv[dd] = (bf16)(o * inv);
        }
        bf16* dst = ob + (size_t)(bt * 64 + q) * INNER_ + h * 64 + d0;
        *(bf16x8*)dst = *(bf16x8*)outv;
        *(bf16x8*)(dst + 8) = *(bf16x8*)(outv + 8);
    }
}

// ---- host side ----
extern "C" void kernel_launch(void* const* d_in, const int* in_sizes, int n_in,
                              void* d_out, int out_size, void* d_ws, size_t ws_size,
                              hipStream_t stream) {
    const float* x       = (const float*)d_in[0];
    const float* latents = (const float*)d_in[1];
    const float* fe      = (const float*)d_in[2];
    const float* g_media = (const float*)d_in[3];
    const float* b_media = (const float*)d_in[4];
    const float* g_lat   = (const float*)d_in[5];
    const float* b_lat   = (const float*)d_in[6];
    const float* Wq      = (const float*)d_in[7];
    const float* Wkv     = (const float*)d_in[8];
    const float* Wo      = (const float*)d_in[9];
    const float* g_ff    = (const float*)d_in[10];
    const float* b_ff    = (const float*)d_in[11];
    const float* W1      = (const float*)d_in[12];
    const float* W2      = (const float*)d_in[13];
    const float* g_out   = (const float*)d_in[14];
    const float* b_out   = (const float*)d_in[15];

    char* p = (char*)d_ws;
    auto alloc = [&](size_t bytes) { char* r = p; p += (bytes + 255) & ~(size_t)255; return r; };
    bf16*  xhat = (bf16*)alloc((size_t)MROWS_ * D_ * 2);          // 67 MB
    float* lat  = (float*)alloc((size_t)2048 * D_ * 4);           // 8 MB
    bf16*  lnl  = (bf16*)alloc((size_t)2048 * D_ * 2);            // 4 MB
    bf16*  qb   = (bf16*)alloc((size_t)2048 * INNER_ * 2);        // 2 MB
    bf16*  KVb  = (bf16*)alloc((size_t)KVROWS_ * 512 * 2);        // 36 MB (K-part only, ld 512)
    bf16*  vt   = (bf16*)alloc((size_t)ZB_ * DH_ * NKV_ * 2);     // 36 MB
    bf16*  ob   = (bf16*)alloc((size_t)2048 * INNER_ * 2);        // 2 MB
    bf16*  Bcat = (bf16*)alloc((size_t)1536 * D_ * 2);            // 3 MB
    bf16*  WkvTg= (bf16*)alloc((size_t)D_ * D_ * 2);
    bf16*  WoT  = (bf16*)alloc((size_t)D_ * INNER_ * 2);
    bf16*  W1T  = (bf16*)alloc((size_t)FF_ * D_ * 2);
    bf16*  W2T  = (bf16*)alloc((size_t)D_ * FF_ * 2);
    float* bkv  = (float*)alloc(1024 * 4);
    float* ffp  = (float*)alloc((size_t)4 * 2048 * D_ * 4);       // 32 MB
    bf16*  ffh  = vt;            // alias: vt dead once attn done (16.8 MB <= 35.7 MB)

    xhat_k<<<MROWS_, 256, 0, stream>>>(x, fe, xhat);
    latinit_k<<<2048, 256, 0, stream>>>(latents, lat);
    ln_k<0><<<2048, 256, 0, stream>>>(lat, g_lat, b_lat, lnl);   // layer-0 latent LN

    const long long PS = (long long)2048 * D_;

    for (int l = 0; l < L_; l++) {
        const float* gm = g_media + (size_t)l * D_;
        const float* bm = b_media + (size_t)l * D_;
        const float* gf = g_ff + (size_t)l * D_;
        const float* bf_ = b_ff + (size_t)l * D_;
        const float* wq = Wq + (size_t)l * D_ * INNER_;
        const float* wkv = Wkv + (size_t)l * D_ * 2 * INNER_;
        const float* wo = Wo + (size_t)l * INNER_ * D_;
        const float* w1 = W1 + (size_t)l * D_ * FF_;
        const float* w2 = W2 + (size_t)l * FF_ * D_;

        wprep_k<<<11264, 256, 0, stream>>>(wq, wkv, wo, w1, w2, gm,
                                           Bcat, Bcat + (size_t)512 * D_, WkvTg, WoT, W1T, W2T);
        bias_k<<<4, 256, 0, stream>>>(bm, wkv, bkv);

        // KV x-part: K -> KVb, V -> vt (transposed), +bkv
        gemm_kv<<<dim3(128, 4), 512, 0, stream>>>(xhat, WkvTg, KVb, vt, bkv);
        // merged: q = (lnl@WqT)*scale; KV lat rows: K -> KVb, V -> vt
        gemm128<0, 3><<<dim3(16, 12), 256, 0, stream>>>(
            lnl, D_, Bcat, D_, qb, 0, D_, 0.125f, 0, KVb, vt);

        // fused attention -> ob
        attn_k<<<ZB_, 256, 0, stream>>>(qb, KVb, vt, ob);

        // Wo split-K 2 -> fp32 partials
        gemm128<4, 0><<<dim3(16, 8, 2), 256, 0, stream>>>(
            ob, INNER_, WoT, INNER_, ffp, D_, INNER_, 1.0f, PS, nullptr, nullptr);
        // lat += partials; lnl = LN(lat; gf,bf)
        accln_k<2, 0><<<2048, 256, 0, stream>>>(lat, ffp, PS, gf, bf_, lnl);

        // FF1: ffh = gelu(lnl @ W1T)
        gemm128<3, 0><<<dim3(16, 32), 256, 0, stream>>>(
            lnl, D_, W1T, D_, ffh, FF_, D_, 1.0f, 0, nullptr, nullptr);
        // FF2 split-K 4 -> fp32 partials
        gemm128<4, 0><<<dim3(16, 8, 4), 256, 0, stream>>>(
            ffh, FF_, W2T, FF_, ffp, D_, FF_, 1.0f, PS, nullptr, nullptr);
        // lat += partials; next-layer latent LN (or final LN -> d_out)
        if (l < L_ - 1) {
            accln_k<4, 0><<<2048, 256, 0, stream>>>(lat, ffp, PS,
                g_lat + (size_t)(l + 1) * D_, b_lat + (size_t)(l + 1) * D_, lnl);
        } else {
            accln_k<4, 1><<<2048, 256, 0, stream>>>(lat, ffp, PS, g_out, b_out, (float*)d_out);
        }
    }
}

// Round 6
// 1323.360 us; speedup vs baseline: 2.0865x; 1.1960x over previous
//
#include <hip/hip_runtime.h>
#include <math.h>

// ---- problem constants ----
#define D_      1024
#define DH_     64
#define H_      8
#define INNER_  512
#define L_      6
#define NL_     64
#define FF_     4096
#define B_      4
#define T_      8
#define FV_     1024          // F*V
#define BT_     32            // B*T
#define MROWS_  32768         // BT*FV
#define NKV_    1088          // FV + NL
#define KVROWS_ 34816         // BT*NKV
#define ZB_     256           // BT*H

typedef __bf16 bf16;
typedef __bf16 bf16x8 __attribute__((ext_vector_type(8)));
typedef __bf16 bf16x4 __attribute__((ext_vector_type(4)));
typedef float  f32x4  __attribute__((ext_vector_type(4)));

#define BARRIER() { asm volatile("" ::: "memory"); __builtin_amdgcn_s_barrier(); asm volatile("" ::: "memory"); }

// ---- helpers ----
__device__ __forceinline__ void gload_lds16(const bf16* g, bf16* l) {
    __builtin_amdgcn_global_load_lds(
        (const __attribute__((address_space(1))) unsigned int*)g,
        (__attribute__((address_space(3))) unsigned int*)l, 16, 0, 0);
}

__device__ __forceinline__ float wred_sum(float v) {
#pragma unroll
    for (int o = 32; o > 0; o >>= 1) v += __shfl_xor(v, o, 64);
    return v;
}

__device__ __forceinline__ float gelu_f(float x) {
    return 0.5f * x * (1.0f + erff(x * 0.70710678118654752440f));
}

// ---- xhat: LN-normalize (x + frame_embs[t]) once, no affine, bf16 out ----
__global__ __launch_bounds__(256) void xhat_k(const float* __restrict__ x,
                                              const float* __restrict__ fe,
                                              bf16* __restrict__ xhat) {
    __shared__ float red[8];
    int row = blockIdx.x;                // bt*FV + fv
    int t = (row >> 10) & 7;
    const float* xr = x + (size_t)row * D_;
    const float* fr_ = fe + (size_t)t * D_;
    int tid = threadIdx.x, c = tid * 4;
    float4 v = *(const float4*)(xr + c);
    float4 f = *(const float4*)(fr_ + c);
    v.x += f.x; v.y += f.y; v.z += f.z; v.w += f.w;
    float s = v.x + v.y + v.z + v.w;
    float ss = v.x * v.x + v.y * v.y + v.z * v.z + v.w * v.w;
    s = wred_sum(s); ss = wred_sum(ss);
    if ((tid & 63) == 0) { red[tid >> 6] = s; red[4 + (tid >> 6)] = ss; }
    __syncthreads();
    s = red[0] + red[1] + red[2] + red[3];
    ss = red[4] + red[5] + red[6] + red[7];
    float mean = s * (1.0f / D_);
    float rstd = rsqrtf(ss * (1.0f / D_) - mean * mean + 1e-5f);
    bf16x4 o;
    o[0] = (bf16)((v.x - mean) * rstd);
    o[1] = (bf16)((v.y - mean) * rstd);
    o[2] = (bf16)((v.z - mean) * rstd);
    o[3] = (bf16)((v.w - mean) * rstd);
    *(bf16x4*)(xhat + (size_t)row * D_ + c) = o;
}

// ---- lat init ----
__global__ __launch_bounds__(256) void latinit_k(const float* __restrict__ latents,
                                                 float* __restrict__ lat) {
    int row = blockIdx.x;
    int i = row & 63;
    int c = threadIdx.x * 4;
    float4 v = *(const float4*)(latents + (size_t)i * D_ + c);
    *(float4*)(lat + (size_t)row * D_ + c) = v;
}

// ---- row LayerNorm with affine: fp32 in, bf16 out ----
template<int OUTF>
__global__ __launch_bounds__(256) void ln_k(const float* __restrict__ in,
                                            const float* __restrict__ g,
                                            const float* __restrict__ b,
                                            void* __restrict__ out) {
    __shared__ float red[8];
    int row = blockIdx.x;
    const float* x = in + (size_t)row * D_;
    int tid = threadIdx.x, c = tid * 4;
    float4 v = *(const float4*)(x + c);
    float s = v.x + v.y + v.z + v.w;
    float ss = v.x * v.x + v.y * v.y + v.z * v.z + v.w * v.w;
    s = wred_sum(s); ss = wred_sum(ss);
    if ((tid & 63) == 0) { red[tid >> 6] = s; red[4 + (tid >> 6)] = ss; }
    __syncthreads();
    s = red[0] + red[1] + red[2] + red[3];
    ss = red[4] + red[5] + red[6] + red[7];
    float mean = s * (1.0f / D_);
    float rstd = rsqrtf(ss * (1.0f / D_) - mean * mean + 1e-5f);
    float4 gv = *(const float4*)(g + c);
    float4 bv = *(const float4*)(b + c);
    float o0 = (v.x - mean) * rstd * gv.x + bv.x;
    float o1 = (v.y - mean) * rstd * gv.y + bv.y;
    float o2 = (v.z - mean) * rstd * gv.z + bv.z;
    float o3 = (v.w - mean) * rstd * gv.w + bv.w;
    if (OUTF) {
        *(float4*)((float*)out + (size_t)row * D_ + c) = make_float4(o0, o1, o2, o3);
    } else {
        bf16x4 o; o[0] = (bf16)o0; o[1] = (bf16)o1; o[2] = (bf16)o2; o[3] = (bf16)o3;
        *(bf16x4*)((bf16*)out + (size_t)row * D_ + c) = o;
    }
}

// ---- accln: lat += sum of NP partials; LN(lat) -> out. OUTF 0: bf16 lnl; 1: fp32 out ----
template<int NP, int OUTF>
__global__ __launch_bounds__(256) void accln_k(float* __restrict__ lat,
                                               const float* __restrict__ p, long long s,
                                               const float* __restrict__ g,
                                               const float* __restrict__ b,
                                               void* __restrict__ out) {
    __shared__ float red[8];
    int row = blockIdx.x;
    int tid = threadIdx.x, c = tid * 4;
    float* lr = lat + (size_t)row * D_;
    float4 a = *(const float4*)(lr + c);
#pragma unroll
    for (int w = 0; w < NP; w++) {
        float4 x = *(const float4*)(p + (size_t)w * s + (size_t)row * D_ + c);
        a.x += x.x; a.y += x.y; a.z += x.z; a.w += x.w;
    }
    if (!OUTF) *(float4*)(lr + c) = a;
    float sm = a.x + a.y + a.z + a.w;
    float ss = a.x * a.x + a.y * a.y + a.z * a.z + a.w * a.w;
    sm = wred_sum(sm); ss = wred_sum(ss);
    if ((tid & 63) == 0) { red[tid >> 6] = sm; red[4 + (tid >> 6)] = ss; }
    __syncthreads();
    sm = red[0] + red[1] + red[2] + red[3];
    ss = red[4] + red[5] + red[6] + red[7];
    float mean = sm * (1.0f / D_);
    float rstd = rsqrtf(ss * (1.0f / D_) - mean * mean + 1e-5f);
    float4 gv = *(const float4*)(g + c);
    float4 bv = *(const float4*)(b + c);
    float o0 = (a.x - mean) * rstd * gv.x + bv.x;
    float o1 = (a.y - mean) * rstd * gv.y + bv.y;
    float o2 = (a.z - mean) * rstd * gv.z + bv.z;
    float o3 = (a.w - mean) * rstd * gv.w + bv.w;
    if (OUTF) {
        *(float4*)((float*)out + (size_t)row * D_ + c) = make_float4(o0, o1, o2, o3);
    } else {
        bf16x4 o; o[0] = (bf16)o0; o[1] = (bf16)o1; o[2] = (bf16)o2; o[3] = (bf16)o3;
        *(bf16x4*)((bf16*)out + (size_t)row * D_ + c) = o;
    }
}

// ---- fused weight prep: transpose fp32->bf16, one launch per layer ----
__device__ __forceinline__ void wt_tile(const float* __restrict__ in, int R, int C,
                                        bf16* __restrict__ out, int bx, int by,
                                        const float* __restrict__ sc) {
    __shared__ float t[32][33];
    int c0 = bx * 32, r0 = by * 32;
    int tx = threadIdx.x & 31, ty = threadIdx.x >> 5;
#pragma unroll
    for (int i = 0; i < 4; i++)
        t[ty + i * 8][tx] = in[(size_t)(r0 + ty + i * 8) * C + c0 + tx];
    __syncthreads();
    float scale = sc ? sc[r0 + tx] : 1.0f;
#pragma unroll
    for (int i = 0; i < 4; i++)
        out[(size_t)(c0 + ty + i * 8) * R + r0 + tx] = (bf16)(t[tx][ty + i * 8] * scale);
}

__global__ __launch_bounds__(256) void wprep_k(const float* __restrict__ wq,
                                               const float* __restrict__ wkv,
                                               const float* __restrict__ wo,
                                               const float* __restrict__ w1,
                                               const float* __restrict__ w2,
                                               const float* __restrict__ gm,
                                               bf16* __restrict__ BcatQ,   // rows 0..511
                                               bf16* __restrict__ BcatKV,  // rows 512..1535
                                               bf16* __restrict__ WkvTg,
                                               bf16* __restrict__ WoT,
                                               bf16* __restrict__ W1T,
                                               bf16* __restrict__ W2T) {
    int id = blockIdx.x;
    if (id < 512)            wt_tile(wq, D_, INNER_, BcatQ, id & 15, id >> 4, nullptr);
    else if (id < 1536)  { int i = id - 512;  wt_tile(wkv, D_, 2 * INNER_, BcatKV, i & 31, i >> 5, nullptr); }
    else if (id < 2560)  { int i = id - 1536; wt_tile(wkv, D_, 2 * INNER_, WkvTg, i & 31, i >> 5, gm); }
    else if (id < 3072)  { int i = id - 2560; wt_tile(wo, INNER_, D_, WoT, i & 31, i >> 5, nullptr); }
    else if (id < 7168)  { int i = id - 3072; wt_tile(w1, D_, FF_, W1T, i & 127, i >> 7, nullptr); }
    else                 { int i = id - 7168; wt_tile(w2, FF_, D_, W2T, i & 31, i >> 5, nullptr); }
}

// ---- bkv[n] += sum_{k chunk} bm[k] * wkv[k][n] (atomic partials, 128 blocks) ----
__global__ __launch_bounds__(256) void bias_k(const float* __restrict__ bm,
                                              const float* __restrict__ wkv,
                                              float* __restrict__ bkv) {
    int n = blockIdx.x * 256 + threadIdx.x;
    int k0 = blockIdx.y * 32;
    float s = 0.0f;
#pragma unroll
    for (int k = k0; k < k0 + 32; k++) s += bm[k] * wkv[(size_t)k * (2 * INNER_) + n];
    atomicAdd(&bkv[n], s);
}

// ======== KV GEMM: 256x256 8-phase pipelined NT (T2+T3+T4+T5) ========
// A=xhat (32768 x 1024), B=WkvTg (1024 x 1024). Epilogue splits columns:
//   cb<512  -> K part into KVb (ld 512), row = bt*1088 + j, +bias
//   cb>=512 -> V part TRANSPOSED into vt[(bt*8+h)*64+dh][j], +bias
__global__ __launch_bounds__(512, 1) void gemm_kv(const bf16* __restrict__ Ag,
                                                  const bf16* __restrict__ Bg,
                                                  bf16* __restrict__ KVb,
                                                  bf16* __restrict__ vt,
                                                  const float* __restrict__ bias) {
    __shared__ bf16 lds[2][32768];   // [buf][Alo 0 | Ahi 8192 | Blo 16384 | Bhi 24576]
    const int lda = D_, ldb = D_;
    const int tid = threadIdx.x;
    const int w = tid >> 6, lane = tid & 63;
    const int wm = w >> 2, wn = w & 3;
    const size_t m0 = (size_t)blockIdx.x * 256;
    const size_t n0 = (size_t)blockIdx.y * 256;
    const int nt = 16;   // K=1024, BK=64

    const int p0 = (w * 2) * 64 + lane, p1 = p0 + 64;
    const int sr0 = p0 >> 3, sk0 = ((p0 & 7) ^ (sr0 & 7)) * 8;
    const int sr1 = p1 >> 3, sk1 = ((p1 & 7) ^ (sr1 & 7)) * 8;
    const int scw0 = (w * 2) * 512, scw1 = scw0 + 512;

    auto STAGE = [&](const bf16* g, int ld, size_t row0, int k0, bf16* bufb, int rb) {
        gload_lds16(g + (row0 + sr0) * (size_t)ld + k0 + sk0, bufb + rb + scw0);
        gload_lds16(g + (row0 + sr1) * (size_t)ld + k0 + sk1, bufb + rb + scw1);
    };

    const int fr = lane & 15;
    const int pK0 = (((lane >> 4)) ^ (fr & 7)) * 8;
    const int pK1 = ((4 + (lane >> 4)) ^ (fr & 7)) * 8;
    const size_t aoff = (size_t)(wm * 128 + fr) * 64;
    const size_t boff = 16384 + (size_t)(wn * 64 + fr) * 64;

    f32x4 acc[8][4];
#pragma unroll
    for (int i = 0; i < 8; i++)
#pragma unroll
        for (int j = 0; j < 4; j++)
#pragma unroll
            for (int r = 0; r < 4; r++) acc[i][j][r] = 0.0f;

    STAGE(Bg, ldb, n0,       0, lds[0], 16384);
    STAGE(Bg, ldb, n0 + 128, 0, lds[0], 24576);
    STAGE(Ag, lda, m0,       0, lds[0], 0);
    STAGE(Ag, lda, m0 + 128, 0, lds[0], 8192);
    STAGE(Bg, ldb, n0,       64, lds[1], 16384);
    STAGE(Bg, ldb, n0 + 128, 64, lds[1], 24576);
    STAGE(Ag, lda, m0,       64, lds[1], 0);
    asm volatile("s_waitcnt vmcnt(6)");
    BARRIER();

    for (int t = 0; t < nt; ++t) {
        const bf16* lb = lds[t & 1];
        bf16* lbw = lds[t & 1];
        bf16* lbn = lds[(t + 1) & 1];
        const int kt1 = (t + 1) << 6, kt2 = (t + 2) << 6;
        bf16x8 bfr[4][2];

        {
#pragma unroll
            for (int j = 0; j < 4; j++) {
                bfr[j][0] = *(const bf16x8*)(lb + boff + j * 1024 + pK0);
                bfr[j][1] = *(const bf16x8*)(lb + boff + j * 1024 + pK1);
            }
            bf16x8 a00 = *(const bf16x8*)(lb + aoff + 0 * 1024 + pK0);
            bf16x8 a01 = *(const bf16x8*)(lb + aoff + 0 * 1024 + pK1);
            bf16x8 a10 = *(const bf16x8*)(lb + aoff + 1 * 1024 + pK0);
            bf16x8 a11 = *(const bf16x8*)(lb + aoff + 1 * 1024 + pK1);
            if (t + 1 < nt) STAGE(Ag, lda, m0 + 128, kt1, lbn, 8192);
            BARRIER();
            asm volatile("s_waitcnt lgkmcnt(0)");
            __builtin_amdgcn_s_setprio(1);
#pragma unroll
            for (int j = 0; j < 4; j++) {
                acc[0][j] = __builtin_amdgcn_mfma_f32_16x16x32_bf16(a00, bfr[j][0], acc[0][j], 0, 0, 0);
                acc[0][j] = __builtin_amdgcn_mfma_f32_16x16x32_bf16(a01, bfr[j][1], acc[0][j], 0, 0, 0);
                acc[1][j] = __builtin_amdgcn_mfma_f32_16x16x32_bf16(a10, bfr[j][0], acc[1][j], 0, 0, 0);
                acc[1][j] = __builtin_amdgcn_mfma_f32_16x16x32_bf16(a11, bfr[j][1], acc[1][j], 0, 0, 0);
            }
            __builtin_amdgcn_s_setprio(0);
            BARRIER();
        }
        {
            bf16x8 a00 = *(const bf16x8*)(lb + aoff + 2 * 1024 + pK0);
            bf16x8 a01 = *(const bf16x8*)(lb + aoff + 2 * 1024 + pK1);
            bf16x8 a10 = *(const bf16x8*)(lb + aoff + 3 * 1024 + pK0);
            bf16x8 a11 = *(const bf16x8*)(lb + aoff + 3 * 1024 + pK1);
            if (t + 2 < nt) STAGE(Bg, ldb, n0, kt2, lbw, 16384);
            BARRIER();
            asm volatile("s_waitcnt lgkmcnt(0)");
            __builtin_amdgcn_s_setprio(1);
#pragma unroll
            for (int j = 0; j < 4; j++) {
                acc[2][j] = __builtin_amdgcn_mfma_f32_16x16x32_bf16(a00, bfr[j][0], acc[2][j], 0, 0, 0);
                acc[2][j] = __builtin_amdgcn_mfma_f32_16x16x32_bf16(a01, bfr[j][1], acc[2][j], 0, 0, 0);
                acc[3][j] = __builtin_amdgcn_mfma_f32_16x16x32_bf16(a10, bfr[j][0], acc[3][j], 0, 0, 0);
                acc[3][j] = __builtin_amdgcn_mfma_f32_16x16x32_bf16(a11, bfr[j][1], acc[3][j], 0, 0, 0);
            }
            __builtin_amdgcn_s_setprio(0);
            BARRIER();
        }
        {
            bf16x8 a00 = *(const bf16x8*)(lb + aoff + 4 * 1024 + pK0);
            bf16x8 a01 = *(const bf16x8*)(lb + aoff + 4 * 1024 + pK1);
            bf16x8 a10 = *(const bf16x8*)(lb + aoff + 5 * 1024 + pK0);
            bf16x8 a11 = *(const bf16x8*)(lb + aoff + 5 * 1024 + pK1);
            if (t + 2 < nt) STAGE(Bg, ldb, n0 + 128, kt2, lbw, 24576);
            BARRIER();
            asm volatile("s_waitcnt lgkmcnt(0)");
            __builtin_amdgcn_s_setprio(1);
#pragma unroll
            for (int j = 0; j < 4; j++) {
                acc[4][j] = __builtin_amdgcn_mfma_f32_16x16x32_bf16(a00, bfr[j][0], acc[4][j], 0, 0, 0);
                acc[4][j] = __builtin_amdgcn_mfma_f32_16x16x32_bf16(a01, bfr[j][1], acc[4][j], 0, 0, 0);
                acc[5][j] = __builtin_amdgcn_mfma_f32_16x16x32_bf16(a10, bfr[j][0], acc[5][j], 0, 0, 0);
                acc[5][j] = __builtin_amdgcn_mfma_f32_16x16x32_bf16(a11, bfr[j][1], acc[5][j], 0, 0, 0);
            }
            __builtin_amdgcn_s_setprio(0);
            BARRIER();
        }
        {
            bf16x8 a00 = *(const bf16x8*)(lb + aoff + 6 * 1024 + pK0);
            bf16x8 a01 = *(const bf16x8*)(lb + aoff + 6 * 1024 + pK1);
            bf16x8 a10 = *(const bf16x8*)(lb + aoff + 7 * 1024 + pK0);
            bf16x8 a11 = *(const bf16x8*)(lb + aoff + 7 * 1024 + pK1);
            if (t + 2 < nt) STAGE(Ag, lda, m0, kt2, lbw, 0);
            BARRIER();
            asm volatile("s_waitcnt lgkmcnt(0)");
            __builtin_amdgcn_s_setprio(1);
#pragma unroll
            for (int j = 0; j < 4; j++) {
                acc[6][j] = __builtin_amdgcn_mfma_f32_16x16x32_bf16(a00, bfr[j][0], acc[6][j], 0, 0, 0);
                acc[6][j] = __builtin_amdgcn_mfma_f32_16x16x32_bf16(a01, bfr[j][1], acc[6][j], 0, 0, 0);
                acc[7][j] = __builtin_amdgcn_mfma_f32_16x16x32_bf16(a10, bfr[j][0], acc[7][j], 0, 0, 0);
                acc[7][j] = __builtin_amdgcn_mfma_f32_16x16x32_bf16(a11, bfr[j][1], acc[7][j], 0, 0, 0);
            }
            __builtin_amdgcn_s_setprio(0);
            if (t < nt - 2)       { asm volatile("s_waitcnt vmcnt(6)"); }
            else if (t == nt - 2) { asm volatile("s_waitcnt vmcnt(0)"); }
            BARRIER();
        }
    }

    // epilogue: K -> KVb (ld 512), V -> vt transposed
    const int fq = (lane >> 4) * 4;
#pragma unroll
    for (int i = 0; i < 8; i++)
#pragma unroll
        for (int j = 0; j < 4; j++) {
            size_t cb = n0 + wn * 64 + j * 16 + fr;
            float bv = bias[cb];
            size_t mb = m0 + wm * 128 + i * 16 + fq;
            if (cb < 512) {
#pragma unroll
                for (int r = 0; r < 4; r++) {
                    size_t m = mb + r;
                    size_t rb = m + ((m >> 10) << 6);
                    KVb[rb * 512 + cb] = (bf16)(acc[i][j][r] + bv);
                }
            } else {
                int hh = ((int)cb - 512) >> 6, dh = ((int)cb - 512) & 63;
                size_t bt = mb >> 10, jl = mb & 1023;
                bf16x4 v4;
#pragma unroll
                for (int r = 0; r < 4; r++) v4[r] = (bf16)(acc[i][j][r] + bv);
                *(bf16x4*)(vt + ((bt * 8 + hh) * 64 + dh) * (size_t)NKV_ + jl) = v4;
            }
        }
}

// ======== FF GEMM: 128x256 4-phase pipelined NT (full-GPU grids) ========
// 8 waves (2M x 4N), per-wave 64x64. LDS 96KiB dbuf: A 128x64 | B 256x64.
// 3 STAGE units/tile (A, Blo, Bhi); counted vmcnt(4) (5 STAGEs=10 loads out).
// MODE 3: bf16 gelu out. MODE 4: fp32 split-K partial (czs stride).
template<int MODE>
__global__ __launch_bounds__(512, 1) void gemm_ff(const bf16* __restrict__ Ag, int lda,
                                                  const bf16* __restrict__ Bg, int ldb,
                                                  void* __restrict__ C, int ldc,
                                                  int K, long long czs) {
    __shared__ bf16 lds[2][24576];   // [buf][A 0..8191 | B 8192..24575]
    const int tid = threadIdx.x;
    const int w = tid >> 6, lane = tid & 63;
    const int wm = w >> 2, wn = w & 3;
    const size_t m0 = (size_t)blockIdx.x * 128;
    const size_t n0 = (size_t)blockIdx.y * 256;
    const int klen = K / gridDim.z;
    const int koff = blockIdx.z * klen;
    const int nt = klen >> 6;

    const int p0 = (w * 2) * 64 + lane, p1 = p0 + 64;
    const int sr0 = p0 >> 3, sk0 = ((p0 & 7) ^ (sr0 & 7)) * 8;
    const int sr1 = p1 >> 3, sk1 = ((p1 & 7) ^ (sr1 & 7)) * 8;
    const int scw0 = (w * 2) * 512, scw1 = scw0 + 512;

    auto STAGE = [&](const bf16* g, int ld, size_t row0, int k0, bf16* bufb, int rb) {
        gload_lds16(g + (row0 + sr0) * (size_t)ld + k0 + sk0, bufb + rb + scw0);
        gload_lds16(g + (row0 + sr1) * (size_t)ld + k0 + sk1, bufb + rb + scw1);
    };

    const int fr = lane & 15;
    const int pK0 = (((lane >> 4)) ^ (fr & 7)) * 8;
    const int pK1 = ((4 + (lane >> 4)) ^ (fr & 7)) * 8;
    const size_t aoff = (size_t)(wm * 64 + fr) * 64;
    const size_t boff = 8192 + (size_t)(wn * 64 + fr) * 64;

    f32x4 acc[4][4];
#pragma unroll
    for (int i = 0; i < 4; i++)
#pragma unroll
        for (int j = 0; j < 4; j++)
#pragma unroll
            for (int r = 0; r < 4; r++) acc[i][j][r] = 0.0f;

    // prologue: tile0 {A,Blo,Bhi} + tile1 {Blo,Bhi}
    STAGE(Ag, lda, m0,       koff,      lds[0], 0);
    STAGE(Bg, ldb, n0,       koff,      lds[0], 8192);
    STAGE(Bg, ldb, n0 + 128, koff,      lds[0], 16384);
    STAGE(Bg, ldb, n0,       koff + 64, lds[1], 8192);
    STAGE(Bg, ldb, n0 + 128, koff + 64, lds[1], 16384);
    asm volatile("s_waitcnt vmcnt(4)");
    BARRIER();

    for (int t = 0; t < nt; ++t) {
        const bf16* lb = lds[t & 1];
        bf16* lbw = lds[t & 1];
        bf16* lbn = lds[(t + 1) & 1];
        const int kt1 = koff + ((t + 1) << 6), kt2 = koff + ((t + 2) << 6);
        bf16x8 bfr[4][2];

        // ph0: B frags + A row 0; stage A(t+1) -> other buf
        {
#pragma unroll
            for (int j = 0; j < 4; j++) {
                bfr[j][0] = *(const bf16x8*)(lb + boff + j * 1024 + pK0);
                bfr[j][1] = *(const bf16x8*)(lb + boff + j * 1024 + pK1);
            }
            bf16x8 a0 = *(const bf16x8*)(lb + aoff + 0 * 1024 + pK0);
            bf16x8 a1 = *(const bf16x8*)(lb + aoff + 0 * 1024 + pK1);
            if (t + 1 < nt) STAGE(Ag, lda, m0, kt1, lbn, 0);
            BARRIER();
            asm volatile("s_waitcnt lgkmcnt(0)");
            __builtin_amdgcn_s_setprio(1);
#pragma unroll
            for (int j = 0; j < 4; j++) {
                acc[0][j] = __builtin_amdgcn_mfma_f32_16x16x32_bf16(a0, bfr[j][0], acc[0][j], 0, 0, 0);
                acc[0][j] = __builtin_amdgcn_mfma_f32_16x16x32_bf16(a1, bfr[j][1], acc[0][j], 0, 0, 0);
            }
            __builtin_amdgcn_s_setprio(0);
            BARRIER();
        }
        // ph1: A row 1; stage Blo(t+2) -> current buf (B consumed at ph0)
        {
            bf16x8 a0 = *(const bf16x8*)(lb + aoff + 1 * 1024 + pK0);
            bf16x8 a1 = *(const bf16x8*)(lb + aoff + 1 * 1024 + pK1);
            if (t + 2 < nt) STAGE(Bg, ldb, n0, kt2, lbw, 8192);
            BARRIER();
            asm volatile("s_waitcnt lgkmcnt(0)");
            __builtin_amdgcn_s_setprio(1);
#pragma unroll
            for (int j = 0; j < 4; j++) {
                acc[1][j] = __builtin_amdgcn_mfma_f32_16x16x32_bf16(a0, bfr[j][0], acc[1][j], 0, 0, 0);
                acc[1][j] = __builtin_amdgcn_mfma_f32_16x16x32_bf16(a1, bfr[j][1], acc[1][j], 0, 0, 0);
            }
            __builtin_amdgcn_s_setprio(0);
            BARRIER();
        }
        // ph2: A row 2; stage Bhi(t+2)
        {
            bf16x8 a0 = *(const bf16x8*)(lb + aoff + 2 * 1024 + pK0);
            bf16x8 a1 = *(const bf16x8*)(lb + aoff + 2 * 1024 + pK1);
            if (t + 2 < nt) STAGE(Bg, ldb, n0 + 128, kt2, lbw, 16384);
            BARRIER();
            asm volatile("s_waitcnt lgkmcnt(0)");
            __builtin_amdgcn_s_setprio(1);
#pragma unroll
            for (int j = 0; j < 4; j++) {
                acc[2][j] = __builtin_amdgcn_mfma_f32_16x16x32_bf16(a0, bfr[j][0], acc[2][j], 0, 0, 0);
                acc[2][j] = __builtin_amdgcn_mfma_f32_16x16x32_bf16(a1, bfr[j][1], acc[2][j], 0, 0, 0);
            }
            __builtin_amdgcn_s_setprio(0);
            BARRIER();
        }
        // ph3: A row 3; tile-end counted vmcnt
        {
            bf16x8 a0 = *(const bf16x8*)(lb + aoff + 3 * 1024 + pK0);
            bf16x8 a1 = *(const bf16x8*)(lb + aoff + 3 * 1024 + pK1);
            BARRIER();
            asm volatile("s_waitcnt lgkmcnt(0)");
            __builtin_amdgcn_s_setprio(1);
#pragma unroll
            for (int j = 0; j < 4; j++) {
                acc[3][j] = __builtin_amdgcn_mfma_f32_16x16x32_bf16(a0, bfr[j][0], acc[3][j], 0, 0, 0);
                acc[3][j] = __builtin_amdgcn_mfma_f32_16x16x32_bf16(a1, bfr[j][1], acc[3][j], 0, 0, 0);
            }
            __builtin_amdgcn_s_setprio(0);
            if (t < nt - 2)       { asm volatile("s_waitcnt vmcnt(4)"); }
            else if (t == nt - 2) { asm volatile("s_waitcnt vmcnt(0)"); }
            BARRIER();
        }
    }

    const int fq = (lane >> 4) * 4;
#pragma unroll
    for (int i = 0; i < 4; i++)
#pragma unroll
        for (int j = 0; j < 4; j++) {
            size_t cb = n0 + wn * 64 + j * 16 + fr;
            size_t mb = m0 + wm * 64 + i * 16 + fq;
#pragma unroll
            for (int r = 0; r < 4; r++) {
                float v = acc[i][j][r];
                if (MODE == 4) {
                    ((float*)C + blockIdx.z * czs)[(mb + r) * (size_t)ldc + cb] = v;
                } else {
                    ((bf16*)C)[(mb + r) * (size_t)ldc + cb] = (bf16)gelu_f(v);
                }
            }
        }
}

// ---- 128x128 NT GEMM (swizzled LDS) ----
// MODE 4: fp32 store (split-K partial, czs stride).
// CMAP 3: cb<512 -> qb*scale; 512<=cb<1024 -> KVb K-part (ld 512, lat rows);
//         cb>=1024 -> vt transposed (lat rows).
template<int MODE, int CMAP>
__global__ __launch_bounds__(256) void gemm128(const bf16* __restrict__ A, int lda,
                                               const bf16* __restrict__ Bw, int ldb,
                                               void* __restrict__ C, int ldc,
                                               int K, float scale,
                                               long long czs, void* __restrict__ C2,
                                               void* __restrict__ C3) {
    __shared__ bf16 As[128 * 32];
    __shared__ bf16 Bs[128 * 32];
    const int tid = threadIdx.x;
    const int wave = tid >> 6;
    const int lane = tid & 63;
    const size_t m0 = (size_t)blockIdx.x * 128;
    const size_t n0 = (size_t)blockIdx.y * 128;
    const int wm = (wave >> 1) * 64;
    const int wn = (wave & 1) * 64;

    const int klen = K / gridDim.z;
    const int koff = blockIdx.z * klen;

    const int r0 = tid >> 2;
    const int c0 = ((tid & 3) ^ ((tid >> 3) & 3)) * 8;
    const bf16* ga0 = A + (m0 + r0) * lda + c0 + koff;
    const bf16* ga1 = A + (m0 + r0 + 64) * lda + c0 + koff;
    const bf16* gb0 = Bw + (n0 + r0) * ldb + c0 + koff;
    const bf16* gb1 = Bw + (n0 + r0 + 64) * ldb + c0 + koff;
    bf16* la0 = As + wave * 512;
    bf16* la1 = As + 2048 + wave * 512;
    bf16* lb0 = Bs + wave * 512;
    bf16* lb1 = Bs + 2048 + wave * 512;

    f32x4 acc[4][4];
#pragma unroll
    for (int i = 0; i < 4; i++)
#pragma unroll
        for (int j = 0; j < 4; j++)
#pragma unroll
            for (int r = 0; r < 4; r++) acc[i][j][r] = 0.0f;

    const int fr = lane & 15;
    const int q = lane >> 4;
    const int sw = (q ^ ((fr >> 1) & 3)) * 8;

    for (int kt = 0; kt < klen; kt += 32) {
        gload_lds16(ga0 + kt, la0);
        gload_lds16(ga1 + kt, la1);
        gload_lds16(gb0 + kt, lb0);
        gload_lds16(gb1 + kt, lb1);
        __syncthreads();
        bf16x8 af[4], bfv[4];
#pragma unroll
        for (int i = 0; i < 4; i++) {
            af[i]  = *(const bf16x8*)(As + (wm + i * 16 + fr) * 32 + sw);
            bfv[i] = *(const bf16x8*)(Bs + (wn + i * 16 + fr) * 32 + sw);
        }
#pragma unroll
        for (int i = 0; i < 4; i++)
#pragma unroll
            for (int j = 0; j < 4; j++)
                acc[i][j] = __builtin_amdgcn_mfma_f32_16x16x32_bf16(af[i], bfv[j], acc[i][j], 0, 0, 0);
        __syncthreads();
    }

    const int fq = (lane >> 4) * 4;
#pragma unroll
    for (int i = 0; i < 4; i++)
#pragma unroll
        for (int j = 0; j < 4; j++) {
            size_t cb = n0 + wn + j * 16 + fr;
            size_t mb = m0 + wm + i * 16 + fq;
            if (CMAP == 3) {
                if (cb < 512) {
#pragma unroll
                    for (int r = 0; r < 4; r++)
                        ((bf16*)C)[(mb + r) * 512 + cb] = (bf16)(acc[i][j][r] * scale);
                } else if (cb < 1024) {
#pragma unroll
                    for (int r = 0; r < 4; r++) {
                        size_t m = mb + r;
                        size_t rb = (m >> 6) * (size_t)NKV_ + 1024 + (m & 63);
                        ((bf16*)C2)[rb * 512 + (cb - 512)] = (bf16)acc[i][j][r];
                    }
                } else {
                    int hh = ((int)cb - 1024) >> 6, dh = ((int)cb - 1024) & 63;
                    size_t bt = mb >> 6, jl = 1024 + (mb & 63);
                    bf16x4 v4;
#pragma unroll
                    for (int r = 0; r < 4; r++) v4[r] = (bf16)acc[i][j][r];
                    *(bf16x4*)((bf16*)C3 + ((bt * 8 + hh) * 64 + dh) * (size_t)NKV_ + jl) = v4;
                }
            } else {
#pragma unroll
                for (int r = 0; r < 4; r++) {
                    float v = acc[i][j][r];
                    if (MODE == 4) {
                        ((float*)C + blockIdx.z * czs)[(mb + r) * ldc + cb] = v;
                    } else {
                        ((bf16*)C)[(mb + r) * ldc + cb] = (bf16)v;
                    }
                }
            }
        }
}

// ======== fused attention: QK^T + online softmax + PV, one block per z ========
__global__ __launch_bounds__(256, 2) void attn_k(const bf16* __restrict__ qb,
                                                 const bf16* __restrict__ KVb,
                                                 const bf16* __restrict__ vt,
                                                 bf16* __restrict__ ob) {
    __shared__ float comb[4][64 * 66];
    __shared__ float sc[4][64];
    __shared__ float mw[4][64], lw[4][64];
    const int z = blockIdx.x, bt = z >> 3, h = z & 7;
    const int tid = threadIdx.x, w = tid >> 6, lane = tid & 63;
    const int fr = lane & 15, g = lane >> 4;
    const bf16* Qz = qb + (size_t)(bt * 64) * INNER_ + h * DH_;
    const bf16* Kz = KVb + (size_t)bt * NKV_ * 512 + h * DH_;   // K rows, ld 512
    const bf16* Vz = vt + (size_t)z * (DH_ * NKV_);
    bf16* Pw = (bf16*)(&comb[w][0]);

    bf16x8 qf[4][2];
#pragma unroll
    for (int nj = 0; nj < 4; nj++)
#pragma unroll
        for (int ks = 0; ks < 2; ks++)
            qf[nj][ks] = *(const bf16x8*)(Qz + (size_t)(fr + 16 * nj) * INNER_ + g * 8 + ks * 32);

    f32x4 acc_o[4][4];
#pragma unroll
    for (int i = 0; i < 4; i++)
#pragma unroll
        for (int j = 0; j < 4; j++)
#pragma unroll
            for (int r = 0; r < 4; r++) acc_o[i][j][r] = 0.0f;
    float m_reg[4] = {-INFINITY, -INFINITY, -INFINITY, -INFINITY};
    float l_reg[4] = {0.0f, 0.0f, 0.0f, 0.0f};

    const int nch = (w == 0) ? 5 : 4;
    for (int ci = 0; ci < nch; ci++) {
        const int kc0 = (w + ci * 4) * 64;
        f32x4 s[4][4];
#pragma unroll
        for (int i = 0; i < 4; i++)
#pragma unroll
            for (int j = 0; j < 4; j++)
#pragma unroll
                for (int r = 0; r < 4; r++) s[i][j][r] = 0.0f;
#pragma unroll
        for (int ks = 0; ks < 2; ks++) {
            bf16x8 kf[4];
#pragma unroll
            for (int mi = 0; mi < 4; mi++)
                kf[mi] = *(const bf16x8*)(Kz + (size_t)(kc0 + fr + 16 * mi) * 512 + g * 8 + ks * 32);
#pragma unroll
            for (int mi = 0; mi < 4; mi++)
#pragma unroll
                for (int nj = 0; nj < 4; nj++)
                    s[mi][nj] = __builtin_amdgcn_mfma_f32_16x16x32_bf16(kf[mi], qf[nj][ks], s[mi][nj], 0, 0, 0);
        }
        float pmax[4];
#pragma unroll
        for (int nj = 0; nj < 4; nj++) {
            float mx = s[0][nj][0];
#pragma unroll
            for (int mi = 0; mi < 4; mi++)
#pragma unroll
                for (int r = 0; r < 4; r++) mx = fmaxf(mx, s[mi][nj][r]);
            mx = fmaxf(mx, __shfl_xor(mx, 16, 64));
            mx = fmaxf(mx, __shfl_xor(mx, 32, 64));
            pmax[nj] = mx;
        }
        bool grew = (pmax[0] > m_reg[0]) || (pmax[1] > m_reg[1]) ||
                    (pmax[2] > m_reg[2]) || (pmax[3] > m_reg[3]);
        if (__any(grew ? 1 : 0)) {
            float so[4];
#pragma unroll
            for (int nj = 0; nj < 4; nj++) {
                float mn = fmaxf(m_reg[nj], pmax[nj]);
                so[nj] = __expf(m_reg[nj] - mn);
                m_reg[nj] = mn;
                l_reg[nj] *= so[nj];
            }
            if (g == 0) {
#pragma unroll
                for (int nj = 0; nj < 4; nj++) sc[w][fr + 16 * nj] = so[nj];
            }
            asm volatile("s_waitcnt lgkmcnt(0)" ::: "memory");
#pragma unroll
            for (int mi = 0; mi < 4; mi++)
#pragma unroll
                for (int r = 0; r < 4; r++) {
                    float sq = sc[w][16 * mi + 4 * g + r];
#pragma unroll
                    for (int jd = 0; jd < 4; jd++) acc_o[mi][jd][r] *= sq;
                }
        }
        float psum[4] = {0.0f, 0.0f, 0.0f, 0.0f};
#pragma unroll
        for (int mi = 0; mi < 4; mi++)
#pragma unroll
            for (int nj = 0; nj < 4; nj++) {
                bf16x4 pb4;
#pragma unroll
                for (int r = 0; r < 4; r++) {
                    float pv = __expf(s[mi][nj][r] - m_reg[nj]);
                    psum[nj] += pv;
                    pb4[r] = (bf16)pv;
                }
                *(bf16x4*)(Pw + (size_t)(fr + 16 * nj) * 72 + 16 * mi + 4 * g) = pb4;
            }
#pragma unroll
        for (int nj = 0; nj < 4; nj++) {
            float ps = psum[nj];
            ps += __shfl_xor(ps, 16, 64);
            ps += __shfl_xor(ps, 32, 64);
            l_reg[nj] += ps;
        }
        asm volatile("s_waitcnt lgkmcnt(0)" ::: "memory");
#pragma unroll
        for (int ks = 0; ks < 2; ks++) {
            bf16x8 af[4], vf[4];
#pragma unroll
            for (int mi = 0; mi < 4; mi++)
                af[mi] = *(const bf16x8*)(Pw + (size_t)(fr + 16 * mi) * 72 + g * 8 + ks * 32);
#pragma unroll
            for (int jd = 0; jd < 4; jd++)
                vf[jd] = *(const bf16x8*)(Vz + (size_t)(fr + 16 * jd) * NKV_ + kc0 + g * 8 + ks * 32);
#pragma unroll
            for (int mi = 0; mi < 4; mi++)
#pragma unroll
                for (int jd = 0; jd < 4; jd++)
                    acc_o[mi][jd] = __builtin_amdgcn_mfma_f32_16x16x32_bf16(af[mi], vf[jd], acc_o[mi][jd], 0, 0, 0);
        }
    }

    if (g == 0) {
#pragma unroll
        for (int nj = 0; nj < 4; nj++) {
            mw[w][fr + 16 * nj] = m_reg[nj];
            lw[w][fr + 16 * nj] = l_reg[nj];
        }
    }
    asm volatile("s_waitcnt lgkmcnt(0)" ::: "memory");
#pragma unroll
    for (int mi = 0; mi < 4; mi++)
#pragma unroll
        for (int jd = 0; jd < 4; jd++)
#pragma unroll
            for (int r = 0; r < 4; r++)
                comb[w][(16 * mi + 4 * g + r) * 66 + fr + 16 * jd] = acc_o[mi][jd][r];
    __syncthreads();
    {
        int q = tid >> 2, d0 = (tid & 3) * 16;
        float M = fmaxf(fmaxf(mw[0][q], mw[1][q]), fmaxf(mw[2][q], mw[3][q]));
        float al[4], l = 0.0f;
#pragma unroll
        for (int ww = 0; ww < 4; ww++) { al[ww] = __expf(mw[ww][q] - M); l += al[ww] * lw[ww][q]; }
        float inv = 1.0f / l;
        bf16 outv[16];
#pragma unroll
        for (int dd = 0; dd < 16; dd++) {
            float o = 0.0f;
#pragma unroll
            for (int ww = 0; ww < 4; ww++) o += comb[ww][q * 66 + d0 + dd] * al[ww];
            outv[dd] = (bf16)(o * inv);
        }
        bf16* dst = ob + (size_t)(bt * 64 + q) * INNER_ + h * 64 + d0;
        *(bf16x8*)dst = *(bf16x8*)outv;
        *(bf16x8*)(dst + 8) = *(bf16x8*)(outv + 8);
    }
}

// ---- host side ----
extern "C" void kernel_launch(void* const* d_in, const int* in_sizes, int n_in,
                              void* d_out, int out_size, void* d_ws, size_t ws_size,
                              hipStream_t stream) {
    const float* x       = (const float*)d_in[0];
    const float* latents = (const float*)d_in[1];
    const float* fe      = (const float*)d_in[2];
    const float* g_media = (const float*)d_in[3];
    const float* b_media = (const float*)d_in[4];
    const float* g_lat   = (const float*)d_in[5];
    const float* b_lat   = (const float*)d_in[6];
    const float* Wq      = (const float*)d_in[7];
    const float* Wkv     = (const float*)d_in[8];
    const float* Wo      = (const float*)d_in[9];
    const float* g_ff    = (const float*)d_in[10];
    const float* b_ff    = (const float*)d_in[11];
    const float* W1      = (const float*)d_in[12];
    const float* W2      = (const float*)d_in[13];
    const float* g_out   = (const float*)d_in[14];
    const float* b_out   = (const float*)d_in[15];

    char* p = (char*)d_ws;
    auto alloc = [&](size_t bytes) { char* r = p; p += (bytes + 255) & ~(size_t)255; return r; };
    bf16*  xhat = (bf16*)alloc((size_t)MROWS_ * D_ * 2);          // 67 MB
    float* lat  = (float*)alloc((size_t)2048 * D_ * 4);           // 8 MB
    bf16*  lnl  = (bf16*)alloc((size_t)2048 * D_ * 2);            // 4 MB
    bf16*  qb   = (bf16*)alloc((size_t)2048 * INNER_ * 2);        // 2 MB
    bf16*  KVb  = (bf16*)alloc((size_t)KVROWS_ * 512 * 2);        // 36 MB (K-part only, ld 512)
    bf16*  vt   = (bf16*)alloc((size_t)ZB_ * DH_ * NKV_ * 2);     // 36 MB
    bf16*  ob   = (bf16*)alloc((size_t)2048 * INNER_ * 2);        // 2 MB
    bf16*  Bcat = (bf16*)alloc((size_t)1536 * D_ * 2);            // 3 MB
    bf16*  WkvTg= (bf16*)alloc((size_t)D_ * D_ * 2);
    bf16*  WoT  = (bf16*)alloc((size_t)D_ * INNER_ * 2);
    bf16*  W1T  = (bf16*)alloc((size_t)FF_ * D_ * 2);
    bf16*  W2T  = (bf16*)alloc((size_t)D_ * FF_ * 2);
    float* bkv  = (float*)alloc(1024 * 4);
    float* ffp  = (float*)alloc((size_t)4 * 2048 * D_ * 4);       // 32 MB
    bf16*  ffh  = vt;            // alias: vt dead once attn done (16.8 MB <= 35.7 MB)

    xhat_k<<<MROWS_, 256, 0, stream>>>(x, fe, xhat);
    latinit_k<<<2048, 256, 0, stream>>>(latents, lat);
    ln_k<0><<<2048, 256, 0, stream>>>(lat, g_lat, b_lat, lnl);   // layer-0 latent LN

    const long long PS = (long long)2048 * D_;

    for (int l = 0; l < L_; l++) {
        const float* gm = g_media + (size_t)l * D_;
        const float* bm = b_media + (size_t)l * D_;
        const float* gf = g_ff + (size_t)l * D_;
        const float* bf_ = b_ff + (size_t)l * D_;
        const float* wq = Wq + (size_t)l * D_ * INNER_;
        const float* wkv = Wkv + (size_t)l * D_ * 2 * INNER_;
        const float* wo = Wo + (size_t)l * INNER_ * D_;
        const float* w1 = W1 + (size_t)l * D_ * FF_;
        const float* w2 = W2 + (size_t)l * FF_ * D_;

        wprep_k<<<11264, 256, 0, stream>>>(wq, wkv, wo, w1, w2, gm,
                                           Bcat, Bcat + (size_t)512 * D_, WkvTg, WoT, W1T, W2T);
        hipMemsetAsync(bkv, 0, 1024 * 4, stream);
        bias_k<<<dim3(4, 32), 256, 0, stream>>>(bm, wkv, bkv);

        // KV x-part: K -> KVb, V -> vt (transposed), +bkv
        gemm_kv<<<dim3(128, 4), 512, 0, stream>>>(xhat, WkvTg, KVb, vt, bkv);
        // merged: q = (lnl@WqT)*scale; KV lat rows: K -> KVb, V -> vt
        gemm128<0, 3><<<dim3(16, 12), 256, 0, stream>>>(
            lnl, D_, Bcat, D_, qb, 0, D_, 0.125f, 0, KVb, vt);

        // fused attention -> ob
        attn_k<<<ZB_, 256, 0, stream>>>(qb, KVb, vt, ob);

        // Wo split-K 2 -> fp32 partials
        gemm128<4, 0><<<dim3(16, 8, 2), 256, 0, stream>>>(
            ob, INNER_, WoT, INNER_, ffp, D_, INNER_, 1.0f, PS, nullptr, nullptr);
        // lat += partials; lnl = LN(lat; gf,bf)
        accln_k<2, 0><<<2048, 256, 0, stream>>>(lat, ffp, PS, gf, bf_, lnl);

        // FF1: ffh = gelu(lnl @ W1T)   [4-phase 128x256, full GPU]
        gemm_ff<3><<<dim3(16, 16), 512, 0, stream>>>(
            lnl, D_, W1T, D_, ffh, FF_, D_, 0);
        // FF2 split-K 4 -> fp32 partials   [4-phase 128x256, full GPU]
        gemm_ff<4><<<dim3(16, 4, 4), 512, 0, stream>>>(
            ffh, FF_, W2T, FF_, ffp, D_, FF_, PS);
        // lat += partials; next-layer latent LN (or final LN -> d_out)
        if (l < L_ - 1) {
            accln_k<4, 0><<<2048, 256, 0, stream>>>(lat, ffp, PS,
                g_lat + (size_t)(l + 1) * D_, b_lat + (size_t)(l + 1) * D_, lnl);
        } else {
            accln_k<4, 1><<<2048, 256, 0, stream>>>(lat, ffp, PS, g_out, b_out, (float*)d_out);
        }
    }
}